// Round 14
// baseline (468.277 us; speedup 1.0000x reference)
//
#include <hip/hip_runtime.h>
#include <hip/hip_bf16.h>
#include <math.h>

static constexpr int NN  = 50000;   // nodes
static constexpr int NE  = 800000;  // edges
static constexpr int DIM = 128;
static constexpr int NG  = 512;     // graphs
static constexpr int NBLK = (NN + 255) / 256;  // 196 scan blocks / buckets

typedef __attribute__((ext_vector_type(8))) short bf16x8;
typedef __attribute__((ext_vector_type(4))) float f32x4;

__device__ __forceinline__ float sigm(float x) {
    return __builtin_amdgcn_rcpf(1.0f + __expf(-x));
}
__device__ __forceinline__ float ftanh(float x) {
    x = fminf(fmaxf(x, -15.f), 15.f);
    float t = __expf(2.f * x);
    return (t - 1.f) * __builtin_amdgcn_rcpf(t + 1.f);
}
__device__ __forceinline__ float b2f(ushort u) { return __uint_as_float(((unsigned)u) << 16); }
__device__ __forceinline__ ushort f2b(float f) {
    __hip_bfloat16 h = __float2bfloat16(f);
    return *reinterpret_cast<ushort*>(&h);
}
__device__ __forceinline__ bf16x8 ldb8(const ushort* p) {
    return *reinterpret_cast<const bf16x8*>(p);
}

// ---------------- mega-prep: all weight conversions + init in one kernel ----------------
__global__ __launch_bounds__(256) void k_prep(const float* __restrict__ lin0_W,
                                              const float* __restrict__ gin_W1,
                                              const float* __restrict__ gin_W2,
                                              const float* __restrict__ gru_Wih,
                                              const float* __restrict__ gru_Whh,
                                              const float* __restrict__ gru_bih,
                                              const float* __restrict__ gru_bhh,
                                              const float* __restrict__ lstm_Wih,
                                              const float* __restrict__ lstm_Whh,
                                              const float* __restrict__ lstm_bih,
                                              const float* __restrict__ lstm_bhh,
                                              const int* __restrict__ batch,
                                              ushort* __restrict__ wlin0,
                                              ushort* __restrict__ wg1,
                                              ushort* __restrict__ wg2,
                                              ushort* __restrict__ wihb,
                                              ushort* __restrict__ whhb,
                                              ushort* __restrict__ wrz,
                                              float* __restrict__ brz,
                                              float* __restrict__ wltr,
                                              float* __restrict__ bl,
                                              int* __restrict__ deg,
                                              int* __restrict__ gstart,
                                              float* __restrict__ zf) {
    const int S0 = 16384, S1 = S0 + 16384, S2 = S1 + 16384;
    const int S3 = S2 + 49152, S4 = S3 + 49152, S5 = S4 + 65536;
    const int S6 = S5 + 256, S7 = S6 + 196608, S8 = S7 + 512;
    const int S9 = S8 + (NN + 1), S10 = S9 + (NG + 1), S11 = S10 + 262144;
    int i = blockIdx.x * 256 + threadIdx.x;
    if (i < S0) { wlin0[i] = f2b(lin0_W[i]); }
    else if (i < S1) { int j = i - S0; wg1[j] = f2b(gin_W1[j]); }
    else if (i < S2) { int j = i - S1; wg2[j] = f2b(gin_W2[j]); }
    else if (i < S3) { int j = i - S2; wihb[j] = f2b(gru_Wih[j]); }
    else if (i < S4) { int j = i - S3; whhb[j] = f2b(gru_Whh[j]); }
    else if (i < S5) {
        int j = i - S4; int col = j >> 8, k = j & 255;
        int row = (col >> 7) * 128 + (col & 127);
        wrz[j] = f2b((k < 128) ? gru_Whh[row * 128 + k] : gru_Wih[row * 128 + (k - 128)]);
    }
    else if (i < S6) { int j = i - S5; brz[j] = gru_bih[j] + gru_bhh[j]; }
    else if (i < S7) {
        int j = i - S6; int k = j / 512, col = j % 512;
        wltr[j] = (k < 256) ? lstm_Wih[(size_t)col * 256 + k]
                            : lstm_Whh[(size_t)col * 128 + (k - 256)];
    }
    else if (i < S8) { int j = i - S7; bl[j] = lstm_bih[j] + lstm_bhh[j]; }
    else if (i < S9) { deg[i - S8] = 0; }
    else if (i < S10) {
        int g = i - S9;
        int lo = 0, hi = NN;
        while (lo < hi) { int mid = (lo + hi) >> 1; if (batch[mid] < g) lo = mid + 1; else hi = mid; }
        gstart[g] = lo;
    }
    else if (i < S11) { zf[i - S10] = 0.f; }
}
static constexpr int PREP_TOTAL = 16384 * 3 + 49152 * 2 + 65536 + 256 + 196608 + 512 + (NN + 1) + (NG + 1) + 262144;

__global__ void k_count(const int* __restrict__ dst, int* __restrict__ deg, int e) {
    int i = blockIdx.x * blockDim.x + threadIdx.x;
    if (i < e) atomicAdd(&deg[dst[i]], 1);
}

// ---------------- parallel 3-phase exclusive scan of deg -> rowptr (+ bucket cursors) ----------------
__global__ __launch_bounds__(256) void k_scan_blk(const int* __restrict__ deg,
                                                  int* __restrict__ part,
                                                  int* __restrict__ blksum) {
    __shared__ int s[256];
    int b = blockIdx.x, t = threadIdx.x;
    int i = b * 256 + t;
    int v = (i < NN) ? deg[i] : 0;
    s[t] = v;
    __syncthreads();
    #pragma unroll
    for (int off = 1; off < 256; off <<= 1) {
        int x = (t >= off) ? s[t - off] : 0;
        __syncthreads();
        s[t] += x;
        __syncthreads();
    }
    if (i < NN) part[i] = s[t] - v;
    if (t == 255) blksum[b] = s[255];
}
__global__ __launch_bounds__(256) void k_scan_top(const int* __restrict__ blksum,
                                                  int* __restrict__ blkoff) {
    __shared__ int s[256];
    int t = threadIdx.x;
    int v = (t < NBLK) ? blksum[t] : 0;
    s[t] = v;
    __syncthreads();
    #pragma unroll
    for (int off = 1; off < 256; off <<= 1) {
        int x = (t >= off) ? s[t - off] : 0;
        __syncthreads();
        s[t] += x;
        __syncthreads();
    }
    if (t < NBLK) blkoff[t] = s[t] - v;
    if (t == NBLK - 1) blkoff[NBLK] = s[t];
}
__global__ __launch_bounds__(256) void k_scan_add(const int* __restrict__ part,
                                                  const int* __restrict__ blkoff,
                                                  int* __restrict__ rowptr,
                                                  int* __restrict__ bcur) {
    int b = blockIdx.x, t = threadIdx.x;
    int i = b * 256 + t;
    if (i < NN) {
        int r = part[i] + blkoff[b];
        rowptr[i] = r;
        if ((i & 255) == 0) bcur[i >> 8] = r;
    }
    if (b == 0 && t == 0) rowptr[NN] = blkoff[NBLK];
}

// ---------------- bucketed CSR fill ----------------
__global__ __launch_bounds__(256) void k_bucket(const int* __restrict__ src,
                                                const int* __restrict__ dst,
                                                int* __restrict__ bcur,
                                                int2* __restrict__ pairs, int e) {
    __shared__ int lcnt[256];
    __shared__ int lbase[256];
    int tid = threadIdx.x;
    lcnt[tid] = 0;
    __syncthreads();
    int base = blockIdx.x * 4096;
    #pragma unroll
    for (int k = 0; k < 16; ++k) {
        int e0 = base + k * 256 + tid;
        if (e0 < e) atomicAdd(&lcnt[dst[e0] >> 8], 1);
    }
    __syncthreads();
    int cnt = lcnt[tid];
    if (cnt > 0) lbase[tid] = atomicAdd(&bcur[tid], cnt);
    __syncthreads();
    lcnt[tid] = 0;
    __syncthreads();
    #pragma unroll
    for (int k = 0; k < 16; ++k) {
        int e0 = base + k * 256 + tid;
        if (e0 < e) {
            int d = dst[e0];
            int b = d >> 8;
            int off = atomicAdd(&lcnt[b], 1);
            pairs[lbase[b] + off] = make_int2(src[e0], d);
        }
    }
}
__global__ __launch_bounds__(256) void k_fillbkt(const int2* __restrict__ pairs,
                                                 const int* __restrict__ rowptr,
                                                 int* __restrict__ csr) {
    __shared__ int lcur[256];
    int b = blockIdx.x, tid = threadIdx.x;
    int w0 = b << 8;
    int w1 = min(w0 + 256, NN);
    if (w0 + tid < w1) lcur[tid] = rowptr[w0 + tid];
    __syncthreads();
    int r0 = rowptr[w0], r1 = rowptr[w1];
    for (int i = r0 + tid; i < r1; i += 256) {
        int2 p = pairs[i];
        int pos = atomicAdd(&lcur[p.y - w0], 1);
        csr[pos] = p.x;
    }
}

// z[i] = h[i] + sum h[nbr]
__global__ __launch_bounds__(256) void k_aggr8(const ushort* __restrict__ AB,
                                               const int* __restrict__ rowptr,
                                               const int* __restrict__ csr,
                                               ushort* __restrict__ Z) {
    int node = blockIdx.x * 4 + (threadIdx.x >> 6);
    if (node >= NN) return;
    int lane = threadIdx.x & 63;
    const unsigned* base = (const unsigned*)AB;
    unsigned u = base[(size_t)node * 64 + lane];
    float s0a = b2f(u & 0xffff), s0b = b2f(u >> 16);
    float s1a = 0.f, s1b = 0.f, s2a = 0.f, s2b = 0.f, s3a = 0.f, s3b = 0.f;
    float s4a = 0.f, s4b = 0.f, s5a = 0.f, s5b = 0.f, s6a = 0.f, s6b = 0.f, s7a = 0.f, s7b = 0.f;
    int p = rowptr[node], p1 = rowptr[node + 1];
    for (; p + 8 <= p1; p += 8) {
        unsigned v0 = base[(size_t)csr[p + 0] * 64 + lane];
        unsigned v1 = base[(size_t)csr[p + 1] * 64 + lane];
        unsigned v2 = base[(size_t)csr[p + 2] * 64 + lane];
        unsigned v3 = base[(size_t)csr[p + 3] * 64 + lane];
        unsigned v4 = base[(size_t)csr[p + 4] * 64 + lane];
        unsigned v5 = base[(size_t)csr[p + 5] * 64 + lane];
        unsigned v6 = base[(size_t)csr[p + 6] * 64 + lane];
        unsigned v7 = base[(size_t)csr[p + 7] * 64 + lane];
        s0a += b2f(v0 & 0xffff); s0b += b2f(v0 >> 16);
        s1a += b2f(v1 & 0xffff); s1b += b2f(v1 >> 16);
        s2a += b2f(v2 & 0xffff); s2b += b2f(v2 >> 16);
        s3a += b2f(v3 & 0xffff); s3b += b2f(v3 >> 16);
        s4a += b2f(v4 & 0xffff); s4b += b2f(v4 >> 16);
        s5a += b2f(v5 & 0xffff); s5b += b2f(v5 >> 16);
        s6a += b2f(v6 & 0xffff); s6b += b2f(v6 >> 16);
        s7a += b2f(v7 & 0xffff); s7b += b2f(v7 >> 16);
    }
    for (; p < p1; ++p) {
        unsigned v = base[(size_t)csr[p] * 64 + lane];
        s0a += b2f(v & 0xffff); s0b += b2f(v >> 16);
    }
    s0a += (s1a + s2a) + (s3a + s4a) + (s5a + s6a) + s7a;
    s0b += (s1b + s2b) + (s3b + s4b) + (s5b + s6b) + s7b;
    unsigned o = ((unsigned)f2b(s0b) << 16) | (unsigned)f2b(s0a);
    ((unsigned*)(Z + (size_t)node * 128))[lane] = o;
}

// lin0: h = relu(x @ W^T + b), fp32 A; writes AB [NN,128] bf16
__global__ __launch_bounds__(256) void k_lin0(const float* __restrict__ X,
                                              const ushort* __restrict__ W,
                                              const float* __restrict__ bias,
                                              ushort* __restrict__ AB, int n) {
    int lane = threadIdx.x & 63, wave = threadIdx.x >> 6;
    int c0 = lane & 15, kg = (lane >> 4) * 8;
    int tb0 = wave * 32;
    bf16x8 B[2][4];
    #pragma unroll
    for (int t = 0; t < 2; ++t)
        #pragma unroll
        for (int kk = 0; kk < 4; ++kk)
            B[t][kk] = ldb8(W + (size_t)(tb0 + t * 16 + c0) * 128 + kk * 32 + kg);

    for (int m0 = blockIdx.x * 64; m0 < n; m0 += gridDim.x * 64) {
        f32x4 acc[4][2];
        #pragma unroll
        for (int m = 0; m < 4; ++m) { acc[m][0] = {0,0,0,0}; acc[m][1] = {0,0,0,0}; }
        #pragma unroll
        for (int kk = 0; kk < 4; ++kk) {
            #pragma unroll
            for (int m = 0; m < 4; ++m) {
                int ar = min(m0 + m * 16 + c0, n - 1);
                const float* a = X + (size_t)ar * 128 + kk * 32 + kg;
                float4 x0 = *reinterpret_cast<const float4*>(a);
                float4 x1 = *reinterpret_cast<const float4*>(a + 4);
                bf16x8 af;
                af[0] = (short)f2b(x0.x); af[1] = (short)f2b(x0.y);
                af[2] = (short)f2b(x0.z); af[3] = (short)f2b(x0.w);
                af[4] = (short)f2b(x1.x); af[5] = (short)f2b(x1.y);
                af[6] = (short)f2b(x1.z); af[7] = (short)f2b(x1.w);
                acc[m][0] = __builtin_amdgcn_mfma_f32_16x16x32_bf16(af, B[0][kk], acc[m][0], 0, 0, 0);
                acc[m][1] = __builtin_amdgcn_mfma_f32_16x16x32_bf16(af, B[1][kk], acc[m][1], 0, 0, 0);
            }
        }
        #pragma unroll
        for (int m = 0; m < 4; ++m) {
            int rbase = m0 + m * 16 + ((lane >> 4) << 2);
            #pragma unroll
            for (int t = 0; t < 2; ++t) {
                int col = tb0 + t * 16 + c0;
                float bv = bias[col];
                #pragma unroll
                for (int j = 0; j < 4; ++j) {
                    int row = rbase + j;
                    if (row < n) {
                        float v = fmaxf(acc[m][t][j] + bv, 0.f);
                        AB[(size_t)row * 128 + col] = f2b(v);
                    }
                }
            }
        }
    }
}

// ---------------- GIN MLP: m = relu(relu(z@W1+b1)@W2+b2) -> mt ----------------
__global__ __launch_bounds__(512) void k_ginmlp3(const ushort* __restrict__ Zt,
                                                 const ushort* __restrict__ W1,
                                                 const float* __restrict__ b1,
                                                 const ushort* __restrict__ W2,
                                                 const float* __restrict__ b2,
                                                 ushort* __restrict__ mt, int n) {
    __shared__ ushort Z_lds[32 * 136];
    __shared__ ushort M_lds[32 * 136];
    int tid = threadIdx.x;
    int lane = tid & 63, wave = tid >> 6;
    int c0 = lane & 15, kg = (lane >> 4) * 8;
    int colw = wave * 16 + c0;
    int rj = (lane >> 4) << 2;
    int srow = tid >> 4, scol = (tid & 15) * 8;

    bf16x8 B1[4], B2[4];
    #pragma unroll
    for (int kk = 0; kk < 4; ++kk) {
        B1[kk] = ldb8(W1 + (size_t)colw * 128 + kk * 32 + kg);
        B2[kk] = ldb8(W2 + (size_t)colw * 128 + kk * 32 + kg);
    }
    float bv1 = b1[colw], bv2 = b2[colw];

    for (int m0 = blockIdx.x * 32; m0 < n; m0 += gridDim.x * 32) {
        int gr = min(m0 + srow, n - 1);
        *reinterpret_cast<bf16x8*>(&Z_lds[srow * 136 + scol]) = ldb8(Zt + (size_t)gr * 128 + scol);
        __syncthreads();
        {
            f32x4 a[2] = {{0,0,0,0},{0,0,0,0}};
            #pragma unroll
            for (int kk = 0; kk < 4; ++kk) {
                bf16x8 f0 = *reinterpret_cast<const bf16x8*>(&Z_lds[c0 * 136 + kk * 32 + kg]);
                bf16x8 f1 = *reinterpret_cast<const bf16x8*>(&Z_lds[(16 + c0) * 136 + kk * 32 + kg]);
                a[0] = __builtin_amdgcn_mfma_f32_16x16x32_bf16(f0, B1[kk], a[0], 0, 0, 0);
                a[1] = __builtin_amdgcn_mfma_f32_16x16x32_bf16(f1, B1[kk], a[1], 0, 0, 0);
            }
            #pragma unroll
            for (int m = 0; m < 2; ++m)
                #pragma unroll
                for (int j = 0; j < 4; ++j)
                    M_lds[(m * 16 + rj + j) * 136 + colw] = f2b(fmaxf(a[m][j] + bv1, 0.f));
        }
        __syncthreads();
        {
            f32x4 a[2] = {{0,0,0,0},{0,0,0,0}};
            #pragma unroll
            for (int kk = 0; kk < 4; ++kk) {
                bf16x8 f0 = *reinterpret_cast<const bf16x8*>(&M_lds[c0 * 136 + kk * 32 + kg]);
                bf16x8 f1 = *reinterpret_cast<const bf16x8*>(&M_lds[(16 + c0) * 136 + kk * 32 + kg]);
                a[0] = __builtin_amdgcn_mfma_f32_16x16x32_bf16(f0, B2[kk], a[0], 0, 0, 0);
                a[1] = __builtin_amdgcn_mfma_f32_16x16x32_bf16(f1, B2[kk], a[1], 0, 0, 0);
            }
            #pragma unroll
            for (int m = 0; m < 2; ++m)
                #pragma unroll
                for (int j = 0; j < 4; ++j) {
                    int grow = m0 + m * 16 + rj + j;
                    if (grow < n)
                        mt[(size_t)grow * 128 + colw] = f2b(fmaxf(a[m][j] + bv2, 0.f));
                }
        }
        __syncthreads();
    }
}

// ---------------- GRU: rz (K=256) + n-gate + combine ----------------
template<bool WRITEH>
__global__ __launch_bounds__(512) void k_gru3b(const ushort* __restrict__ ABin,
                                               const ushort* __restrict__ mt,
                                               const ushort* __restrict__ wrz,
                                               const float* __restrict__ brz,
                                               const ushort* __restrict__ Wn,
                                               const ushort* __restrict__ Un,
                                               const float* __restrict__ bin,
                                               const float* __restrict__ bhn,
                                               float* __restrict__ Hf,
                                               ushort* __restrict__ ABout, int n) {
    __shared__ ushort A_lds[32 * 264];   // [h | m]
    __shared__ ushort rz_lds[32 * 264];
    int tid = threadIdx.x;
    int lane = tid & 63, wave = tid >> 6;
    int c0 = lane & 15, kg = (lane >> 4) * 8;
    int colw = wave * 16 + c0;
    int rj = (lane >> 4) << 2;
    int srow = tid >> 4, scol = (tid & 15) * 8;

    bf16x8 Brz[2][8];
    #pragma unroll
    for (int tt = 0; tt < 2; ++tt)
        #pragma unroll
        for (int kk = 0; kk < 8; ++kk)
            Brz[tt][kk] = ldb8(wrz + (size_t)(wave * 32 + tt * 16 + c0) * 256 + kk * 32 + kg);
    bf16x8 Bn[4], Bu[4];
    #pragma unroll
    for (int kk = 0; kk < 4; ++kk) {
        Bn[kk] = ldb8(Wn + (size_t)colw * 128 + kk * 32 + kg);
        Bu[kk] = ldb8(Un + (size_t)colw * 128 + kk * 32 + kg);
    }
    float biN = bin[colw], bhN = bhn[colw];
    float brz0 = brz[wave * 32 + c0], brz1 = brz[wave * 32 + 16 + c0];

    for (int m0 = blockIdx.x * 32; m0 < n; m0 += gridDim.x * 32) {
        int gr = min(m0 + srow, n - 1);
        *reinterpret_cast<bf16x8*>(&A_lds[srow * 264 + scol]) = ldb8(ABin + (size_t)gr * 128 + scol);
        *reinterpret_cast<bf16x8*>(&A_lds[srow * 264 + 128 + scol]) = ldb8(mt + (size_t)gr * 128 + scol);
        __syncthreads();
        {
            f32x4 acc[2][2];
            acc[0][0] = {0,0,0,0}; acc[0][1] = {0,0,0,0};
            acc[1][0] = {0,0,0,0}; acc[1][1] = {0,0,0,0};
            #pragma unroll
            for (int kk = 0; kk < 8; ++kk) {
                bf16x8 f0 = *reinterpret_cast<const bf16x8*>(&A_lds[c0 * 264 + kk * 32 + kg]);
                bf16x8 f1 = *reinterpret_cast<const bf16x8*>(&A_lds[(16 + c0) * 264 + kk * 32 + kg]);
                acc[0][0] = __builtin_amdgcn_mfma_f32_16x16x32_bf16(f0, Brz[0][kk], acc[0][0], 0, 0, 0);
                acc[0][1] = __builtin_amdgcn_mfma_f32_16x16x32_bf16(f0, Brz[1][kk], acc[0][1], 0, 0, 0);
                acc[1][0] = __builtin_amdgcn_mfma_f32_16x16x32_bf16(f1, Brz[0][kk], acc[1][0], 0, 0, 0);
                acc[1][1] = __builtin_amdgcn_mfma_f32_16x16x32_bf16(f1, Brz[1][kk], acc[1][1], 0, 0, 0);
            }
            #pragma unroll
            for (int m = 0; m < 2; ++m)
                #pragma unroll
                for (int tt = 0; tt < 2; ++tt)
                    #pragma unroll
                    for (int j = 0; j < 4; ++j) {
                        int row = m * 16 + rj + j;
                        int col2 = wave * 32 + tt * 16 + c0;
                        rz_lds[row * 264 + col2] = f2b(sigm(acc[m][tt][j] + (tt ? brz1 : brz0)));
                    }
        }
        __syncthreads();
        {
            f32x4 an[2] = {{0,0,0,0},{0,0,0,0}};
            f32x4 au[2] = {{0,0,0,0},{0,0,0,0}};
            #pragma unroll
            for (int kk = 0; kk < 4; ++kk) {
                bf16x8 am0 = *reinterpret_cast<const bf16x8*>(&A_lds[c0 * 264 + 128 + kk * 32 + kg]);
                bf16x8 ah0 = *reinterpret_cast<const bf16x8*>(&A_lds[c0 * 264 + kk * 32 + kg]);
                bf16x8 am1 = *reinterpret_cast<const bf16x8*>(&A_lds[(16 + c0) * 264 + 128 + kk * 32 + kg]);
                bf16x8 ah1 = *reinterpret_cast<const bf16x8*>(&A_lds[(16 + c0) * 264 + kk * 32 + kg]);
                an[0] = __builtin_amdgcn_mfma_f32_16x16x32_bf16(am0, Bn[kk], an[0], 0, 0, 0);
                au[0] = __builtin_amdgcn_mfma_f32_16x16x32_bf16(ah0, Bu[kk], au[0], 0, 0, 0);
                an[1] = __builtin_amdgcn_mfma_f32_16x16x32_bf16(am1, Bn[kk], an[1], 0, 0, 0);
                au[1] = __builtin_amdgcn_mfma_f32_16x16x32_bf16(ah1, Bu[kk], au[1], 0, 0, 0);
            }
            #pragma unroll
            for (int m = 0; m < 2; ++m)
                #pragma unroll
                for (int j = 0; j < 4; ++j) {
                    int row = m * 16 + rj + j;
                    int grow = m0 + row;
                    if (grow < n) {
                        float r    = b2f(rz_lds[row * 264 + colw]);
                        float zt   = b2f(rz_lds[row * 264 + 128 + colw]);
                        float hold = b2f(A_lds[row * 264 + colw]);
                        float nn = ftanh(an[m][j] + biN + r * (au[m][j] + bhN));
                        float hn = (1.f - zt) * nn + zt * hold;
                        ABout[(size_t)grow * 128 + colw] = f2b(hn);
                        if (WRITEH) Hf[(size_t)grow * 128 + colw] = hn;
                    }
                }
        }
        __syncthreads();
    }
}

// ---------------- fused Set2Set step: LSTM cell + online-softmax attention pool ----------------
__global__ __launch_bounds__(512) void k_s2s(const ushort* __restrict__ AB,
                                             const float* __restrict__ Wt,
                                             const float* __restrict__ bl,
                                             const int* __restrict__ gstart,
                                             const float* __restrict__ qstar,
                                             float* __restrict__ hl,
                                             float* __restrict__ cl,
                                             float* __restrict__ qout) {
    int g = blockIdx.x, tid = threadIdx.x, lane = tid & 63, wave = tid >> 6;
    __shared__ float qh[384];
    __shared__ float gbuf[512];
    __shared__ float q[128];
    __shared__ float wm[8];
    __shared__ float sw[8];
    __shared__ float rv[8][128];
    if (tid < 256) qh[tid] = qstar[(size_t)g * 256 + tid];
    else if (tid < 384) qh[tid] = hl[(size_t)g * 128 + (tid - 256)];
    __syncthreads();
    float acc = bl[tid];
    #pragma unroll 8
    for (int k = 0; k < 384; ++k)
        acc += Wt[(size_t)k * 512 + tid] * qh[k];
    gbuf[tid] = acc;
    __syncthreads();
    if (tid < 128) {
        float iv = sigm(gbuf[tid]);
        float fv = sigm(gbuf[128 + tid]);
        float gv = ftanh(gbuf[256 + tid]);
        float ov = sigm(gbuf[384 + tid]);
        float cn = fv * cl[(size_t)g * 128 + tid] + iv * gv;
        cl[(size_t)g * 128 + tid] = cn;
        float hn = ov * ftanh(cn);
        hl[(size_t)g * 128 + tid] = hn;
        q[tid] = hn;
    }
    __syncthreads();
    int s = gstart[g], e = gstart[g + 1];
    float q0 = q[2 * lane], q1 = q[2 * lane + 1];
    float mx = -1e30f, sumw = 0.f, a0 = 0.f, a1 = 0.f;
    for (int node = s + wave; node < e; node += 8) {
        unsigned u = ((const unsigned*)AB)[(size_t)node * 64 + lane];
        float v0 = b2f(u & 0xffff), v1 = b2f(u >> 16);
        float p = v0 * q0 + v1 * q1;
        #pragma unroll
        for (int off = 1; off < 64; off <<= 1) p += __shfl_xor(p, off);
        float nm = fmaxf(mx, p);
        float corr = __expf(mx - nm);
        float wgt = __expf(p - nm);
        sumw = sumw * corr + wgt;
        a0 = a0 * corr + wgt * v0;
        a1 = a1 * corr + wgt * v1;
        mx = nm;
    }
    if (lane == 0) wm[wave] = mx;
    __syncthreads();
    float gm = fmaxf(fmaxf(fmaxf(wm[0], wm[1]), fmaxf(wm[2], wm[3])),
                     fmaxf(fmaxf(wm[4], wm[5]), fmaxf(wm[6], wm[7])));
    float cw = __expf(mx - gm);
    rv[wave][2 * lane] = a0 * cw;
    rv[wave][2 * lane + 1] = a1 * cw;
    if (lane == 0) sw[wave] = sumw * cw;
    __syncthreads();
    if (tid < 128) {
        float r = 0.f, d = 1e-16f;
        #pragma unroll
        for (int wv = 0; wv < 8; ++wv) r += rv[wv][tid];
        #pragma unroll
        for (int wv = 0; wv < 8; ++wv) d += sw[wv];
        qout[(size_t)g * 256 + tid] = q[tid];
        qout[(size_t)g * 256 + 128 + tid] = r / d;
    }
}

// ---------------- launch ----------------
extern "C" void kernel_launch(void* const* d_in, const int* in_sizes, int n_in,
                              void* d_out, int out_size, void* d_ws, size_t ws_size,
                              hipStream_t stream) {
    const float* x        = (const float*)d_in[0];
    const int*   ei       = (const int*)d_in[1];
    const int*   batch    = (const int*)d_in[2];
    const float* lin0_W   = (const float*)d_in[3];
    const float* lin0_b   = (const float*)d_in[4];
    const float* gin_W1   = (const float*)d_in[5];
    const float* gin_b1   = (const float*)d_in[6];
    const float* gin_W2   = (const float*)d_in[7];
    const float* gin_b2   = (const float*)d_in[8];
    const float* gru_Wih  = (const float*)d_in[9];
    const float* gru_Whh  = (const float*)d_in[10];
    const float* gru_bih  = (const float*)d_in[11];
    const float* gru_bhh  = (const float*)d_in[12];
    const float* lstm_Wih = (const float*)d_in[13];
    const float* lstm_Whh = (const float*)d_in[14];
    const float* lstm_bih = (const float*)d_in[15];
    const float* lstm_bhh = (const float*)d_in[16];

    float* qstar_out = (float*)d_out;                         // [NG, 256]
    float* h         = (float*)d_out + (size_t)NG * 2 * DIM;  // [NN, 128] fp32 == `out`

    char* w = (char*)d_ws;
    ushort* AB0   = (ushort*)w; w += (size_t)NN * 128 * 2;   // ping (h only)
    ushort* AB1   = (ushort*)w; w += (size_t)NN * 128 * 2;   // pong (h only)
    ushort* zt    = (ushort*)w; w += (size_t)NN * 128 * 2;   // aggr out
    ushort* mt    = (ushort*)w; w += (size_t)NN * 128 * 2;   // GIN MLP out
    ushort* wlin0 = (ushort*)w; w += 16384 * 2;
    ushort* wg1   = (ushort*)w; w += 16384 * 2;
    ushort* wg2   = (ushort*)w; w += 16384 * 2;
    ushort* wihb  = (ushort*)w; w += 49152 * 2;
    ushort* whhb  = (ushort*)w; w += 49152 * 2;
    ushort* wrz   = (ushort*)w; w += 65536 * 2;
    float* brz    = (float*)w;  w += 256 * 4;
    float* wltr   = (float*)w;  w += (size_t)512 * 384 * 4;  // LSTM W transposed
    float* bl     = (float*)w;  w += 512 * 4;
    float* qstar  = (float*)w;  w += (size_t)NG * 2 * DIM * 4;  // contiguous with hl, cl
    float* hl     = (float*)w;  w += (size_t)NG * DIM * 4;
    float* cl     = (float*)w;  w += (size_t)NG * DIM * 4;
    int* deg      = (int*)w;    w += (size_t)(NN + 1) * 4;
    int* rowptr   = (int*)w;    w += (size_t)(NN + 1) * 4;
    int* bcur     = (int*)w;    w += 256 * 4;
    int* csr_src  = (int*)w;    w += (size_t)NE * 4;
    int2* pairs   = (int2*)w;   w += (size_t)NE * 8;
    int* gstart   = (int*)w;    w += (size_t)(NG + 1) * 4;
    int* part     = (int*)w;    w += (size_t)NN * 4;
    int* blksum   = (int*)w;    w += (size_t)(NBLK + 1) * 4;
    int* blkoff   = (int*)w;    w += (size_t)(NBLK + 1) * 4;

    const int* src = ei;
    const int* dst = ei + NE;

    // one mega-prep
    k_prep<<<(PREP_TOTAL + 255) / 256, 256, 0, stream>>>(
        lin0_W, gin_W1, gin_W2, gru_Wih, gru_Whh, gru_bih, gru_bhh,
        lstm_Wih, lstm_Whh, lstm_bih, lstm_bhh, batch,
        wlin0, wg1, wg2, wihb, whhb, wrz, brz, wltr, bl, deg, gstart, qstar);

    // CSR build
    k_count<<<(NE + 255) / 256, 256, 0, stream>>>(dst, deg, NE);
    k_scan_blk<<<NBLK, 256, 0, stream>>>(deg, part, blksum);
    k_scan_top<<<1, 256, 0, stream>>>(blksum, blkoff);
    k_scan_add<<<NBLK, 256, 0, stream>>>(part, blkoff, rowptr, bcur);
    k_bucket<<<(NE + 4095) / 4096, 256, 0, stream>>>(src, dst, bcur, pairs, NE);
    k_fillbkt<<<NBLK, 256, 0, stream>>>(pairs, rowptr, csr_src);

    // lin0 -> AB0
    k_lin0<<<782, 256, 0, stream>>>(x, wlin0, lin0_b, AB0, NN);

    // 3 GC layers, ping-pong AB buffers
    for (int t = 0; t < 3; ++t) {
        ushort* ABc = (t & 1) ? AB1 : AB0;
        ushort* ABn = (t & 1) ? AB0 : AB1;
        k_aggr8<<<(NN + 3) / 4, 256, 0, stream>>>(ABc, rowptr, csr_src, zt);
        k_ginmlp3<<<782, 512, 0, stream>>>(zt, wg1, gin_b1, wg2, gin_b2, mt, NN);
        if (t < 2)
            k_gru3b<false><<<782, 512, 0, stream>>>(ABc, mt, wrz, brz,
                                                    wihb + 256 * 128, whhb + 256 * 128,
                                                    gru_bih + 256, gru_bhh + 256, h, ABn, NN);
        else
            k_gru3b<true><<<782, 512, 0, stream>>>(ABc, mt, wrz, brz,
                                                   wihb + 256 * 128, whhb + 256 * 128,
                                                   gru_bih + 256, gru_bhh + 256, h, ABn, NN);
    }
    // final bf16 h lives in AB1 (t=2 wrote ABn=AB1)
    const ushort* ABfin = AB1;

    // Set2Set (fused LSTM + attention per step)
    for (int st = 0; st < 3; ++st)
        k_s2s<<<NG, 512, 0, stream>>>(ABfin, wltr, bl, gstart, qstar, hl, cl,
                                      (st == 2) ? qstar_out : qstar);
}

// Round 15
// 422.765 us; speedup vs baseline: 1.1077x; 1.1077x over previous
//
#include <hip/hip_runtime.h>
#include <hip/hip_bf16.h>
#include <math.h>

static constexpr int NN  = 50000;   // nodes
static constexpr int NE  = 800000;  // edges
static constexpr int DIM = 128;
static constexpr int NG  = 512;     // graphs
static constexpr int NBLK = (NN + 255) / 256;  // 196 scan blocks / buckets

typedef __attribute__((ext_vector_type(8))) short bf16x8;
typedef __attribute__((ext_vector_type(4))) float f32x4;

__device__ __forceinline__ float sigm(float x) {
    return __builtin_amdgcn_rcpf(1.0f + __expf(-x));
}
__device__ __forceinline__ float ftanh(float x) {
    x = fminf(fmaxf(x, -15.f), 15.f);
    float t = __expf(2.f * x);
    return (t - 1.f) * __builtin_amdgcn_rcpf(t + 1.f);
}
__device__ __forceinline__ float b2f(ushort u) { return __uint_as_float(((unsigned)u) << 16); }
__device__ __forceinline__ ushort f2b(float f) {
    __hip_bfloat16 h = __float2bfloat16(f);
    return *reinterpret_cast<ushort*>(&h);
}
__device__ __forceinline__ bf16x8 ldb8(const ushort* p) {
    return *reinterpret_cast<const bf16x8*>(p);
}

// ---------------- mega-prep: all weight conversions + init in one kernel ----------------
__global__ __launch_bounds__(256) void k_prep(const float* __restrict__ lin0_W,
                                              const float* __restrict__ gin_W1,
                                              const float* __restrict__ gin_W2,
                                              const float* __restrict__ gru_Wih,
                                              const float* __restrict__ gru_Whh,
                                              const float* __restrict__ gru_bih,
                                              const float* __restrict__ gru_bhh,
                                              const float* __restrict__ lstm_Wih,
                                              const float* __restrict__ lstm_Whh,
                                              const float* __restrict__ lstm_bih,
                                              const float* __restrict__ lstm_bhh,
                                              const int* __restrict__ batch,
                                              ushort* __restrict__ wlin0,
                                              ushort* __restrict__ wg1,
                                              ushort* __restrict__ wg2,
                                              ushort* __restrict__ wihb,
                                              ushort* __restrict__ whhb,
                                              ushort* __restrict__ wrz,
                                              float* __restrict__ brz,
                                              float* __restrict__ wltr,
                                              float* __restrict__ bl,
                                              int* __restrict__ deg,
                                              int* __restrict__ gstart,
                                              float* __restrict__ zf) {
    const int S0 = 16384, S1 = S0 + 16384, S2 = S1 + 16384;
    const int S3 = S2 + 49152, S4 = S3 + 49152, S5 = S4 + 65536;
    const int S6 = S5 + 256, S7 = S6 + 196608, S8 = S7 + 512;
    const int S9 = S8 + (NN + 1), S10 = S9 + (NG + 1), S11 = S10 + 262144;
    int i = blockIdx.x * 256 + threadIdx.x;
    if (i < S0) { wlin0[i] = f2b(lin0_W[i]); }
    else if (i < S1) { int j = i - S0; wg1[j] = f2b(gin_W1[j]); }
    else if (i < S2) { int j = i - S1; wg2[j] = f2b(gin_W2[j]); }
    else if (i < S3) { int j = i - S2; wihb[j] = f2b(gru_Wih[j]); }
    else if (i < S4) { int j = i - S3; whhb[j] = f2b(gru_Whh[j]); }
    else if (i < S5) {
        int j = i - S4; int col = j >> 8, k = j & 255;
        int row = (col >> 7) * 128 + (col & 127);
        wrz[j] = f2b((k < 128) ? gru_Whh[row * 128 + k] : gru_Wih[row * 128 + (k - 128)]);
    }
    else if (i < S6) { int j = i - S5; brz[j] = gru_bih[j] + gru_bhh[j]; }
    else if (i < S7) {
        int j = i - S6; int k = j / 512, col = j % 512;
        wltr[j] = (k < 256) ? lstm_Wih[(size_t)col * 256 + k]
                            : lstm_Whh[(size_t)col * 128 + (k - 256)];
    }
    else if (i < S8) { int j = i - S7; bl[j] = lstm_bih[j] + lstm_bhh[j]; }
    else if (i < S9) { deg[i - S8] = 0; }
    else if (i < S10) {
        int g = i - S9;
        int lo = 0, hi = NN;
        while (lo < hi) { int mid = (lo + hi) >> 1; if (batch[mid] < g) lo = mid + 1; else hi = mid; }
        gstart[g] = lo;
    }
    else if (i < S11) { zf[i - S10] = 0.f; }
}
static constexpr int PREP_TOTAL = 16384 * 3 + 49152 * 2 + 65536 + 256 + 196608 + 512 + (NN + 1) + (NG + 1) + 262144;

__global__ void k_count(const int* __restrict__ dst, int* __restrict__ deg, int e) {
    int i = blockIdx.x * blockDim.x + threadIdx.x;
    if (i < e) atomicAdd(&deg[dst[i]], 1);
}

// ---------------- parallel 3-phase exclusive scan of deg -> rowptr (+ bucket cursors) ----------------
__global__ __launch_bounds__(256) void k_scan_blk(const int* __restrict__ deg,
                                                  int* __restrict__ part,
                                                  int* __restrict__ blksum) {
    __shared__ int s[256];
    int b = blockIdx.x, t = threadIdx.x;
    int i = b * 256 + t;
    int v = (i < NN) ? deg[i] : 0;
    s[t] = v;
    __syncthreads();
    #pragma unroll
    for (int off = 1; off < 256; off <<= 1) {
        int x = (t >= off) ? s[t - off] : 0;
        __syncthreads();
        s[t] += x;
        __syncthreads();
    }
    if (i < NN) part[i] = s[t] - v;
    if (t == 255) blksum[b] = s[255];
}
__global__ __launch_bounds__(256) void k_scan_top(const int* __restrict__ blksum,
                                                  int* __restrict__ blkoff) {
    __shared__ int s[256];
    int t = threadIdx.x;
    int v = (t < NBLK) ? blksum[t] : 0;
    s[t] = v;
    __syncthreads();
    #pragma unroll
    for (int off = 1; off < 256; off <<= 1) {
        int x = (t >= off) ? s[t - off] : 0;
        __syncthreads();
        s[t] += x;
        __syncthreads();
    }
    if (t < NBLK) blkoff[t] = s[t] - v;
    if (t == NBLK - 1) blkoff[NBLK] = s[t];
}
__global__ __launch_bounds__(256) void k_scan_add(const int* __restrict__ part,
                                                  const int* __restrict__ blkoff,
                                                  int* __restrict__ rowptr,
                                                  int* __restrict__ bcur) {
    int b = blockIdx.x, t = threadIdx.x;
    int i = b * 256 + t;
    if (i < NN) {
        int r = part[i] + blkoff[b];
        rowptr[i] = r;
        if ((i & 255) == 0) bcur[i >> 8] = r;
    }
    if (b == 0 && t == 0) rowptr[NN] = blkoff[NBLK];
}

// ---------------- bucketed CSR fill ----------------
__global__ __launch_bounds__(256) void k_bucket(const int* __restrict__ src,
                                                const int* __restrict__ dst,
                                                int* __restrict__ bcur,
                                                int2* __restrict__ pairs, int e) {
    __shared__ int lcnt[256];
    __shared__ int lbase[256];
    int tid = threadIdx.x;
    lcnt[tid] = 0;
    __syncthreads();
    int base = blockIdx.x * 4096;
    #pragma unroll
    for (int k = 0; k < 16; ++k) {
        int e0 = base + k * 256 + tid;
        if (e0 < e) atomicAdd(&lcnt[dst[e0] >> 8], 1);
    }
    __syncthreads();
    int cnt = lcnt[tid];
    if (cnt > 0) lbase[tid] = atomicAdd(&bcur[tid], cnt);
    __syncthreads();
    lcnt[tid] = 0;
    __syncthreads();
    #pragma unroll
    for (int k = 0; k < 16; ++k) {
        int e0 = base + k * 256 + tid;
        if (e0 < e) {
            int d = dst[e0];
            int b = d >> 8;
            int off = atomicAdd(&lcnt[b], 1);
            pairs[lbase[b] + off] = make_int2(src[e0], d);
        }
    }
}
__global__ __launch_bounds__(256) void k_fillbkt(const int2* __restrict__ pairs,
                                                 const int* __restrict__ rowptr,
                                                 int* __restrict__ csr) {
    __shared__ int lcur[256];
    int b = blockIdx.x, tid = threadIdx.x;
    int w0 = b << 8;
    int w1 = min(w0 + 256, NN);
    if (w0 + tid < w1) lcur[tid] = rowptr[w0 + tid];
    __syncthreads();
    int r0 = rowptr[w0], r1 = rowptr[w1];
    for (int i = r0 + tid; i < r1; i += 256) {
        int2 p = pairs[i];
        int pos = atomicAdd(&lcur[p.y - w0], 1);
        csr[pos] = p.x;
    }
}

// z[i] = h[i] + sum h[nbr]
__global__ __launch_bounds__(256) void k_aggr8(const ushort* __restrict__ AB,
                                               const int* __restrict__ rowptr,
                                               const int* __restrict__ csr,
                                               ushort* __restrict__ Z) {
    int node = blockIdx.x * 4 + (threadIdx.x >> 6);
    if (node >= NN) return;
    int lane = threadIdx.x & 63;
    const unsigned* base = (const unsigned*)AB;
    unsigned u = base[(size_t)node * 64 + lane];
    float s0a = b2f(u & 0xffff), s0b = b2f(u >> 16);
    float s1a = 0.f, s1b = 0.f, s2a = 0.f, s2b = 0.f, s3a = 0.f, s3b = 0.f;
    float s4a = 0.f, s4b = 0.f, s5a = 0.f, s5b = 0.f, s6a = 0.f, s6b = 0.f, s7a = 0.f, s7b = 0.f;
    int p = rowptr[node], p1 = rowptr[node + 1];
    for (; p + 8 <= p1; p += 8) {
        unsigned v0 = base[(size_t)csr[p + 0] * 64 + lane];
        unsigned v1 = base[(size_t)csr[p + 1] * 64 + lane];
        unsigned v2 = base[(size_t)csr[p + 2] * 64 + lane];
        unsigned v3 = base[(size_t)csr[p + 3] * 64 + lane];
        unsigned v4 = base[(size_t)csr[p + 4] * 64 + lane];
        unsigned v5 = base[(size_t)csr[p + 5] * 64 + lane];
        unsigned v6 = base[(size_t)csr[p + 6] * 64 + lane];
        unsigned v7 = base[(size_t)csr[p + 7] * 64 + lane];
        s0a += b2f(v0 & 0xffff); s0b += b2f(v0 >> 16);
        s1a += b2f(v1 & 0xffff); s1b += b2f(v1 >> 16);
        s2a += b2f(v2 & 0xffff); s2b += b2f(v2 >> 16);
        s3a += b2f(v3 & 0xffff); s3b += b2f(v3 >> 16);
        s4a += b2f(v4 & 0xffff); s4b += b2f(v4 >> 16);
        s5a += b2f(v5 & 0xffff); s5b += b2f(v5 >> 16);
        s6a += b2f(v6 & 0xffff); s6b += b2f(v6 >> 16);
        s7a += b2f(v7 & 0xffff); s7b += b2f(v7 >> 16);
    }
    for (; p < p1; ++p) {
        unsigned v = base[(size_t)csr[p] * 64 + lane];
        s0a += b2f(v & 0xffff); s0b += b2f(v >> 16);
    }
    s0a += (s1a + s2a) + (s3a + s4a) + (s5a + s6a) + s7a;
    s0b += (s1b + s2b) + (s3b + s4b) + (s5b + s6b) + s7b;
    unsigned o = ((unsigned)f2b(s0b) << 16) | (unsigned)f2b(s0a);
    ((unsigned*)(Z + (size_t)node * 128))[lane] = o;
}

// lin0: h = relu(x @ W^T + b), fp32 A; writes AB [NN,128] bf16
__global__ __launch_bounds__(256) void k_lin0(const float* __restrict__ X,
                                              const ushort* __restrict__ W,
                                              const float* __restrict__ bias,
                                              ushort* __restrict__ AB, int n) {
    int lane = threadIdx.x & 63, wave = threadIdx.x >> 6;
    int c0 = lane & 15, kg = (lane >> 4) * 8;
    int tb0 = wave * 32;
    bf16x8 B[2][4];
    #pragma unroll
    for (int t = 0; t < 2; ++t)
        #pragma unroll
        for (int kk = 0; kk < 4; ++kk)
            B[t][kk] = ldb8(W + (size_t)(tb0 + t * 16 + c0) * 128 + kk * 32 + kg);

    for (int m0 = blockIdx.x * 64; m0 < n; m0 += gridDim.x * 64) {
        f32x4 acc[4][2];
        #pragma unroll
        for (int m = 0; m < 4; ++m) { acc[m][0] = {0,0,0,0}; acc[m][1] = {0,0,0,0}; }
        #pragma unroll
        for (int kk = 0; kk < 4; ++kk) {
            #pragma unroll
            for (int m = 0; m < 4; ++m) {
                int ar = min(m0 + m * 16 + c0, n - 1);
                const float* a = X + (size_t)ar * 128 + kk * 32 + kg;
                float4 x0 = *reinterpret_cast<const float4*>(a);
                float4 x1 = *reinterpret_cast<const float4*>(a + 4);
                bf16x8 af;
                af[0] = (short)f2b(x0.x); af[1] = (short)f2b(x0.y);
                af[2] = (short)f2b(x0.z); af[3] = (short)f2b(x0.w);
                af[4] = (short)f2b(x1.x); af[5] = (short)f2b(x1.y);
                af[6] = (short)f2b(x1.z); af[7] = (short)f2b(x1.w);
                acc[m][0] = __builtin_amdgcn_mfma_f32_16x16x32_bf16(af, B[0][kk], acc[m][0], 0, 0, 0);
                acc[m][1] = __builtin_amdgcn_mfma_f32_16x16x32_bf16(af, B[1][kk], acc[m][1], 0, 0, 0);
            }
        }
        #pragma unroll
        for (int m = 0; m < 4; ++m) {
            int rbase = m0 + m * 16 + ((lane >> 4) << 2);
            #pragma unroll
            for (int t = 0; t < 2; ++t) {
                int col = tb0 + t * 16 + c0;
                float bv = bias[col];
                #pragma unroll
                for (int j = 0; j < 4; ++j) {
                    int row = rbase + j;
                    if (row < n) {
                        float v = fmaxf(acc[m][t][j] + bv, 0.f);
                        AB[(size_t)row * 128 + col] = f2b(v);
                    }
                }
            }
        }
    }
}

// ---------------- GIN MLP with register-prefetch pipeline ----------------
__global__ __launch_bounds__(512) void k_ginmlp3(const ushort* __restrict__ Zt,
                                                 const ushort* __restrict__ W1,
                                                 const float* __restrict__ b1,
                                                 const ushort* __restrict__ W2,
                                                 const float* __restrict__ b2,
                                                 ushort* __restrict__ mt, int n) {
    __shared__ ushort Z_lds[32 * 136];
    __shared__ ushort M_lds[32 * 136];
    int tid = threadIdx.x;
    int lane = tid & 63, wave = tid >> 6;
    int c0 = lane & 15, kg = (lane >> 4) * 8;
    int colw = wave * 16 + c0;
    int rj = (lane >> 4) << 2;
    int srow = tid >> 4, scol = (tid & 15) * 8;
    const int stride = gridDim.x * 32;

    bf16x8 B1[4], B2[4];
    #pragma unroll
    for (int kk = 0; kk < 4; ++kk) {
        B1[kk] = ldb8(W1 + (size_t)colw * 128 + kk * 32 + kg);
        B2[kk] = ldb8(W2 + (size_t)colw * 128 + kk * 32 + kg);
    }
    float bv1 = b1[colw], bv2 = b2[colw];

    int m0 = blockIdx.x * 32;
    bf16x8 pz;
    if (m0 < n) pz = ldb8(Zt + (size_t)min(m0 + srow, n - 1) * 128 + scol);
    for (; m0 < n; m0 += stride) {
        *reinterpret_cast<bf16x8*>(&Z_lds[srow * 136 + scol]) = pz;
        __syncthreads();
        // issue next tile's prefetch (flies under the two MFMA phases)
        int mn = m0 + stride;
        if (mn < n) pz = ldb8(Zt + (size_t)min(mn + srow, n - 1) * 128 + scol);
        {
            f32x4 a[2] = {{0,0,0,0},{0,0,0,0}};
            #pragma unroll
            for (int kk = 0; kk < 4; ++kk) {
                bf16x8 f0 = *reinterpret_cast<const bf16x8*>(&Z_lds[c0 * 136 + kk * 32 + kg]);
                bf16x8 f1 = *reinterpret_cast<const bf16x8*>(&Z_lds[(16 + c0) * 136 + kk * 32 + kg]);
                a[0] = __builtin_amdgcn_mfma_f32_16x16x32_bf16(f0, B1[kk], a[0], 0, 0, 0);
                a[1] = __builtin_amdgcn_mfma_f32_16x16x32_bf16(f1, B1[kk], a[1], 0, 0, 0);
            }
            #pragma unroll
            for (int m = 0; m < 2; ++m)
                #pragma unroll
                for (int j = 0; j < 4; ++j)
                    M_lds[(m * 16 + rj + j) * 136 + colw] = f2b(fmaxf(a[m][j] + bv1, 0.f));
        }
        __syncthreads();
        {
            f32x4 a[2] = {{0,0,0,0},{0,0,0,0}};
            #pragma unroll
            for (int kk = 0; kk < 4; ++kk) {
                bf16x8 f0 = *reinterpret_cast<const bf16x8*>(&M_lds[c0 * 136 + kk * 32 + kg]);
                bf16x8 f1 = *reinterpret_cast<const bf16x8*>(&M_lds[(16 + c0) * 136 + kk * 32 + kg]);
                a[0] = __builtin_amdgcn_mfma_f32_16x16x32_bf16(f0, B2[kk], a[0], 0, 0, 0);
                a[1] = __builtin_amdgcn_mfma_f32_16x16x32_bf16(f1, B2[kk], a[1], 0, 0, 0);
            }
            #pragma unroll
            for (int m = 0; m < 2; ++m)
                #pragma unroll
                for (int j = 0; j < 4; ++j) {
                    int grow = m0 + m * 16 + rj + j;
                    if (grow < n)
                        mt[(size_t)grow * 128 + colw] = f2b(fmaxf(a[m][j] + bv2, 0.f));
                }
        }
        __syncthreads();
    }
}

// ---------------- GRU with register-prefetch pipeline ----------------
template<bool WRITEH>
__global__ __launch_bounds__(512) void k_gru3b(const ushort* __restrict__ ABin,
                                               const ushort* __restrict__ mt,
                                               const ushort* __restrict__ wrz,
                                               const float* __restrict__ brz,
                                               const ushort* __restrict__ Wn,
                                               const ushort* __restrict__ Un,
                                               const float* __restrict__ bin,
                                               const float* __restrict__ bhn,
                                               float* __restrict__ Hf,
                                               ushort* __restrict__ ABout, int n) {
    __shared__ ushort A_lds[32 * 264];   // [h | m]
    __shared__ ushort rz_lds[32 * 264];
    int tid = threadIdx.x;
    int lane = tid & 63, wave = tid >> 6;
    int c0 = lane & 15, kg = (lane >> 4) * 8;
    int colw = wave * 16 + c0;
    int rj = (lane >> 4) << 2;
    int srow = tid >> 4, scol = (tid & 15) * 8;
    const int stride = gridDim.x * 32;

    bf16x8 Brz[2][8];
    #pragma unroll
    for (int tt = 0; tt < 2; ++tt)
        #pragma unroll
        for (int kk = 0; kk < 8; ++kk)
            Brz[tt][kk] = ldb8(wrz + (size_t)(wave * 32 + tt * 16 + c0) * 256 + kk * 32 + kg);
    bf16x8 Bn[4], Bu[4];
    #pragma unroll
    for (int kk = 0; kk < 4; ++kk) {
        Bn[kk] = ldb8(Wn + (size_t)colw * 128 + kk * 32 + kg);
        Bu[kk] = ldb8(Un + (size_t)colw * 128 + kk * 32 + kg);
    }
    float biN = bin[colw], bhN = bhn[colw];
    float brz0 = brz[wave * 32 + c0], brz1 = brz[wave * 32 + 16 + c0];

    int m0 = blockIdx.x * 32;
    bf16x8 ph, pm;
    if (m0 < n) {
        int gr = min(m0 + srow, n - 1);
        ph = ldb8(ABin + (size_t)gr * 128 + scol);
        pm = ldb8(mt + (size_t)gr * 128 + scol);
    }
    for (; m0 < n; m0 += stride) {
        *reinterpret_cast<bf16x8*>(&A_lds[srow * 264 + scol]) = ph;
        *reinterpret_cast<bf16x8*>(&A_lds[srow * 264 + 128 + scol]) = pm;
        __syncthreads();
        // issue next tile's prefetch (flies under rz + ngate MFMA phases)
        int mn = m0 + stride;
        if (mn < n) {
            int gr = min(mn + srow, n - 1);
            ph = ldb8(ABin + (size_t)gr * 128 + scol);
            pm = ldb8(mt + (size_t)gr * 128 + scol);
        }
        {
            f32x4 acc[2][2];
            acc[0][0] = {0,0,0,0}; acc[0][1] = {0,0,0,0};
            acc[1][0] = {0,0,0,0}; acc[1][1] = {0,0,0,0};
            #pragma unroll
            for (int kk = 0; kk < 8; ++kk) {
                bf16x8 f0 = *reinterpret_cast<const bf16x8*>(&A_lds[c0 * 264 + kk * 32 + kg]);
                bf16x8 f1 = *reinterpret_cast<const bf16x8*>(&A_lds[(16 + c0) * 264 + kk * 32 + kg]);
                acc[0][0] = __builtin_amdgcn_mfma_f32_16x16x32_bf16(f0, Brz[0][kk], acc[0][0], 0, 0, 0);
                acc[0][1] = __builtin_amdgcn_mfma_f32_16x16x32_bf16(f0, Brz[1][kk], acc[0][1], 0, 0, 0);
                acc[1][0] = __builtin_amdgcn_mfma_f32_16x16x32_bf16(f1, Brz[0][kk], acc[1][0], 0, 0, 0);
                acc[1][1] = __builtin_amdgcn_mfma_f32_16x16x32_bf16(f1, Brz[1][kk], acc[1][1], 0, 0, 0);
            }
            #pragma unroll
            for (int m = 0; m < 2; ++m)
                #pragma unroll
                for (int tt = 0; tt < 2; ++tt)
                    #pragma unroll
                    for (int j = 0; j < 4; ++j) {
                        int row = m * 16 + rj + j;
                        int col2 = wave * 32 + tt * 16 + c0;
                        rz_lds[row * 264 + col2] = f2b(sigm(acc[m][tt][j] + (tt ? brz1 : brz0)));
                    }
        }
        __syncthreads();
        {
            f32x4 an[2] = {{0,0,0,0},{0,0,0,0}};
            f32x4 au[2] = {{0,0,0,0},{0,0,0,0}};
            #pragma unroll
            for (int kk = 0; kk < 4; ++kk) {
                bf16x8 am0 = *reinterpret_cast<const bf16x8*>(&A_lds[c0 * 264 + 128 + kk * 32 + kg]);
                bf16x8 ah0 = *reinterpret_cast<const bf16x8*>(&A_lds[c0 * 264 + kk * 32 + kg]);
                bf16x8 am1 = *reinterpret_cast<const bf16x8*>(&A_lds[(16 + c0) * 264 + 128 + kk * 32 + kg]);
                bf16x8 ah1 = *reinterpret_cast<const bf16x8*>(&A_lds[(16 + c0) * 264 + kk * 32 + kg]);
                an[0] = __builtin_amdgcn_mfma_f32_16x16x32_bf16(am0, Bn[kk], an[0], 0, 0, 0);
                au[0] = __builtin_amdgcn_mfma_f32_16x16x32_bf16(ah0, Bu[kk], au[0], 0, 0, 0);
                an[1] = __builtin_amdgcn_mfma_f32_16x16x32_bf16(am1, Bn[kk], an[1], 0, 0, 0);
                au[1] = __builtin_amdgcn_mfma_f32_16x16x32_bf16(ah1, Bu[kk], au[1], 0, 0, 0);
            }
            #pragma unroll
            for (int m = 0; m < 2; ++m)
                #pragma unroll
                for (int j = 0; j < 4; ++j) {
                    int row = m * 16 + rj + j;
                    int grow = m0 + row;
                    if (grow < n) {
                        float r    = b2f(rz_lds[row * 264 + colw]);
                        float zt   = b2f(rz_lds[row * 264 + 128 + colw]);
                        float hold = b2f(A_lds[row * 264 + colw]);
                        float nn = ftanh(an[m][j] + biN + r * (au[m][j] + bhN));
                        float hn = (1.f - zt) * nn + zt * hold;
                        ABout[(size_t)grow * 128 + colw] = f2b(hn);
                        if (WRITEH) Hf[(size_t)grow * 128 + colw] = hn;
                    }
                }
        }
        __syncthreads();
    }
}

// ---------------- fused Set2Set step: LSTM cell + online-softmax attention pool ----------------
__global__ __launch_bounds__(512) void k_s2s(const ushort* __restrict__ AB,
                                             const float* __restrict__ Wt,
                                             const float* __restrict__ bl,
                                             const int* __restrict__ gstart,
                                             const float* __restrict__ qstar,
                                             float* __restrict__ hl,
                                             float* __restrict__ cl,
                                             float* __restrict__ qout) {
    int g = blockIdx.x, tid = threadIdx.x, lane = tid & 63, wave = tid >> 6;
    __shared__ float qh[384];
    __shared__ float gbuf[512];
    __shared__ float q[128];
    __shared__ float wm[8];
    __shared__ float sw[8];
    __shared__ float rv[8][128];
    if (tid < 256) qh[tid] = qstar[(size_t)g * 256 + tid];
    else if (tid < 384) qh[tid] = hl[(size_t)g * 128 + (tid - 256)];
    __syncthreads();
    float acc = bl[tid];
    #pragma unroll 8
    for (int k = 0; k < 384; ++k)
        acc += Wt[(size_t)k * 512 + tid] * qh[k];
    gbuf[tid] = acc;
    __syncthreads();
    if (tid < 128) {
        float iv = sigm(gbuf[tid]);
        float fv = sigm(gbuf[128 + tid]);
        float gv = ftanh(gbuf[256 + tid]);
        float ov = sigm(gbuf[384 + tid]);
        float cn = fv * cl[(size_t)g * 128 + tid] + iv * gv;
        cl[(size_t)g * 128 + tid] = cn;
        float hn = ov * ftanh(cn);
        hl[(size_t)g * 128 + tid] = hn;
        q[tid] = hn;
    }
    __syncthreads();
    int s = gstart[g], e = gstart[g + 1];
    float q0 = q[2 * lane], q1 = q[2 * lane + 1];
    float mx = -1e30f, sumw = 0.f, a0 = 0.f, a1 = 0.f;
    for (int node = s + wave; node < e; node += 8) {
        unsigned u = ((const unsigned*)AB)[(size_t)node * 64 + lane];
        float v0 = b2f(u & 0xffff), v1 = b2f(u >> 16);
        float p = v0 * q0 + v1 * q1;
        #pragma unroll
        for (int off = 1; off < 64; off <<= 1) p += __shfl_xor(p, off);
        float nm = fmaxf(mx, p);
        float corr = __expf(mx - nm);
        float wgt = __expf(p - nm);
        sumw = sumw * corr + wgt;
        a0 = a0 * corr + wgt * v0;
        a1 = a1 * corr + wgt * v1;
        mx = nm;
    }
    if (lane == 0) wm[wave] = mx;
    __syncthreads();
    float gm = fmaxf(fmaxf(fmaxf(wm[0], wm[1]), fmaxf(wm[2], wm[3])),
                     fmaxf(fmaxf(wm[4], wm[5]), fmaxf(wm[6], wm[7])));
    float cw = __expf(mx - gm);
    rv[wave][2 * lane] = a0 * cw;
    rv[wave][2 * lane + 1] = a1 * cw;
    if (lane == 0) sw[wave] = sumw * cw;
    __syncthreads();
    if (tid < 128) {
        float r = 0.f, d = 1e-16f;
        #pragma unroll
        for (int wv = 0; wv < 8; ++wv) r += rv[wv][tid];
        #pragma unroll
        for (int wv = 0; wv < 8; ++wv) d += sw[wv];
        qout[(size_t)g * 256 + tid] = q[tid];
        qout[(size_t)g * 256 + 128 + tid] = r / d;
    }
}

// ---------------- launch ----------------
extern "C" void kernel_launch(void* const* d_in, const int* in_sizes, int n_in,
                              void* d_out, int out_size, void* d_ws, size_t ws_size,
                              hipStream_t stream) {
    const float* x        = (const float*)d_in[0];
    const int*   ei       = (const int*)d_in[1];
    const int*   batch    = (const int*)d_in[2];
    const float* lin0_W   = (const float*)d_in[3];
    const float* lin0_b   = (const float*)d_in[4];
    const float* gin_W1   = (const float*)d_in[5];
    const float* gin_b1   = (const float*)d_in[6];
    const float* gin_W2   = (const float*)d_in[7];
    const float* gin_b2   = (const float*)d_in[8];
    const float* gru_Wih  = (const float*)d_in[9];
    const float* gru_Whh  = (const float*)d_in[10];
    const float* gru_bih  = (const float*)d_in[11];
    const float* gru_bhh  = (const float*)d_in[12];
    const float* lstm_Wih = (const float*)d_in[13];
    const float* lstm_Whh = (const float*)d_in[14];
    const float* lstm_bih = (const float*)d_in[15];
    const float* lstm_bhh = (const float*)d_in[16];

    float* qstar_out = (float*)d_out;                         // [NG, 256]
    float* h         = (float*)d_out + (size_t)NG * 2 * DIM;  // [NN, 128] fp32 == `out`

    char* w = (char*)d_ws;
    ushort* AB0   = (ushort*)w; w += (size_t)NN * 128 * 2;   // ping (h only)
    ushort* AB1   = (ushort*)w; w += (size_t)NN * 128 * 2;   // pong (h only)
    ushort* zt    = (ushort*)w; w += (size_t)NN * 128 * 2;   // aggr out
    ushort* mt    = (ushort*)w; w += (size_t)NN * 128 * 2;   // GIN MLP out
    ushort* wlin0 = (ushort*)w; w += 16384 * 2;
    ushort* wg1   = (ushort*)w; w += 16384 * 2;
    ushort* wg2   = (ushort*)w; w += 16384 * 2;
    ushort* wihb  = (ushort*)w; w += 49152 * 2;
    ushort* whhb  = (ushort*)w; w += 49152 * 2;
    ushort* wrz   = (ushort*)w; w += 65536 * 2;
    float* brz    = (float*)w;  w += 256 * 4;
    float* wltr   = (float*)w;  w += (size_t)512 * 384 * 4;  // LSTM W transposed
    float* bl     = (float*)w;  w += 512 * 4;
    float* qstar  = (float*)w;  w += (size_t)NG * 2 * DIM * 4;  // contiguous with hl, cl
    float* hl     = (float*)w;  w += (size_t)NG * DIM * 4;
    float* cl     = (float*)w;  w += (size_t)NG * DIM * 4;
    int* deg      = (int*)w;    w += (size_t)(NN + 1) * 4;
    int* rowptr   = (int*)w;    w += (size_t)(NN + 1) * 4;
    int* bcur     = (int*)w;    w += 256 * 4;
    int* csr_src  = (int*)w;    w += (size_t)NE * 4;
    int2* pairs   = (int2*)w;   w += (size_t)NE * 8;
    int* gstart   = (int*)w;    w += (size_t)(NG + 1) * 4;
    int* part     = (int*)w;    w += (size_t)NN * 4;
    int* blksum   = (int*)w;    w += (size_t)(NBLK + 1) * 4;
    int* blkoff   = (int*)w;    w += (size_t)(NBLK + 1) * 4;

    const int* src = ei;
    const int* dst = ei + NE;

    // one mega-prep
    k_prep<<<(PREP_TOTAL + 255) / 256, 256, 0, stream>>>(
        lin0_W, gin_W1, gin_W2, gru_Wih, gru_Whh, gru_bih, gru_bhh,
        lstm_Wih, lstm_Whh, lstm_bih, lstm_bhh, batch,
        wlin0, wg1, wg2, wihb, whhb, wrz, brz, wltr, bl, deg, gstart, qstar);

    // CSR build
    k_count<<<(NE + 255) / 256, 256, 0, stream>>>(dst, deg, NE);
    k_scan_blk<<<NBLK, 256, 0, stream>>>(deg, part, blksum);
    k_scan_top<<<1, 256, 0, stream>>>(blksum, blkoff);
    k_scan_add<<<NBLK, 256, 0, stream>>>(part, blkoff, rowptr, bcur);
    k_bucket<<<(NE + 4095) / 4096, 256, 0, stream>>>(src, dst, bcur, pairs, NE);
    k_fillbkt<<<NBLK, 256, 0, stream>>>(pairs, rowptr, csr_src);

    // lin0 -> AB0
    k_lin0<<<782, 256, 0, stream>>>(x, wlin0, lin0_b, AB0, NN);

    // 3 GC layers, ping-pong AB buffers
    for (int t = 0; t < 3; ++t) {
        ushort* ABc = (t & 1) ? AB1 : AB0;
        ushort* ABn = (t & 1) ? AB0 : AB1;
        k_aggr8<<<(NN + 3) / 4, 256, 0, stream>>>(ABc, rowptr, csr_src, zt);
        k_ginmlp3<<<1024, 512, 0, stream>>>(zt, wg1, gin_b1, wg2, gin_b2, mt, NN);
        if (t < 2)
            k_gru3b<false><<<512, 512, 0, stream>>>(ABc, mt, wrz, brz,
                                                    wihb + 256 * 128, whhb + 256 * 128,
                                                    gru_bih + 256, gru_bhh + 256, h, ABn, NN);
        else
            k_gru3b<true><<<512, 512, 0, stream>>>(ABc, mt, wrz, brz,
                                                   wihb + 256 * 128, whhb + 256 * 128,
                                                   gru_bih + 256, gru_bhh + 256, h, ABn, NN);
    }
    // final bf16 h lives in AB1 (t=2 wrote ABn=AB1)
    const ushort* ABfin = AB1;

    // Set2Set (fused LSTM + attention per step)
    for (int st = 0; st < 3; ++st)
        k_s2s<<<NG, 512, 0, stream>>>(ABfin, wltr, bl, gstart, qstar, hl, cl,
                                      (st == 2) ? qstar_out : qstar);
}

// Round 16
// 408.518 us; speedup vs baseline: 1.1463x; 1.0349x over previous
//
#include <hip/hip_runtime.h>
#include <hip/hip_bf16.h>
#include <math.h>

static constexpr int NN  = 50000;   // nodes
static constexpr int NE  = 800000;  // edges
static constexpr int DIM = 128;
static constexpr int NG  = 512;     // graphs
static constexpr int NBLK = (NN + 255) / 256;  // 196 scan blocks / buckets

typedef __attribute__((ext_vector_type(8))) short bf16x8;
typedef __attribute__((ext_vector_type(4))) float f32x4;

__device__ __forceinline__ float sigm(float x) {
    return __builtin_amdgcn_rcpf(1.0f + __expf(-x));
}
__device__ __forceinline__ float ftanh(float x) {
    x = fminf(fmaxf(x, -15.f), 15.f);
    float t = __expf(2.f * x);
    return (t - 1.f) * __builtin_amdgcn_rcpf(t + 1.f);
}
__device__ __forceinline__ float b2f(ushort u) { return __uint_as_float(((unsigned)u) << 16); }
__device__ __forceinline__ ushort f2b(float f) {
    __hip_bfloat16 h = __float2bfloat16(f);
    return *reinterpret_cast<ushort*>(&h);
}
__device__ __forceinline__ bf16x8 ldb8(const ushort* p) {
    return *reinterpret_cast<const bf16x8*>(p);
}

// ---------------- mega-prep: all weight conversions + init in one kernel ----------------
__global__ __launch_bounds__(256) void k_prep(const float* __restrict__ lin0_W,
                                              const float* __restrict__ gin_W1,
                                              const float* __restrict__ gin_W2,
                                              const float* __restrict__ gru_Wih,
                                              const float* __restrict__ gru_Whh,
                                              const float* __restrict__ gru_bih,
                                              const float* __restrict__ gru_bhh,
                                              const float* __restrict__ lstm_Wih,
                                              const float* __restrict__ lstm_Whh,
                                              const float* __restrict__ lstm_bih,
                                              const float* __restrict__ lstm_bhh,
                                              const int* __restrict__ batch,
                                              ushort* __restrict__ wlin0,
                                              ushort* __restrict__ wg1,
                                              ushort* __restrict__ wg2,
                                              ushort* __restrict__ wihb,
                                              ushort* __restrict__ whhb,
                                              ushort* __restrict__ wrz,
                                              float* __restrict__ brz,
                                              float* __restrict__ wltr,
                                              float* __restrict__ bl,
                                              int* __restrict__ deg,
                                              int* __restrict__ gstart,
                                              float* __restrict__ zf) {
    const int S0 = 16384, S1 = S0 + 16384, S2 = S1 + 16384;
    const int S3 = S2 + 49152, S4 = S3 + 49152, S5 = S4 + 65536;
    const int S6 = S5 + 256, S7 = S6 + 196608, S8 = S7 + 512;
    const int S9 = S8 + (NN + 1), S10 = S9 + (NG + 1), S11 = S10 + 262144;
    int i = blockIdx.x * 256 + threadIdx.x;
    if (i < S0) { wlin0[i] = f2b(lin0_W[i]); }
    else if (i < S1) { int j = i - S0; wg1[j] = f2b(gin_W1[j]); }
    else if (i < S2) { int j = i - S1; wg2[j] = f2b(gin_W2[j]); }
    else if (i < S3) { int j = i - S2; wihb[j] = f2b(gru_Wih[j]); }
    else if (i < S4) { int j = i - S3; whhb[j] = f2b(gru_Whh[j]); }
    else if (i < S5) {
        int j = i - S4; int col = j >> 8, k = j & 255;
        int row = (col >> 7) * 128 + (col & 127);
        wrz[j] = f2b((k < 128) ? gru_Whh[row * 128 + k] : gru_Wih[row * 128 + (k - 128)]);
    }
    else if (i < S6) { int j = i - S5; brz[j] = gru_bih[j] + gru_bhh[j]; }
    else if (i < S7) {
        int j = i - S6; int k = j / 512, col = j % 512;
        wltr[j] = (k < 256) ? lstm_Wih[(size_t)col * 256 + k]
                            : lstm_Whh[(size_t)col * 128 + (k - 256)];
    }
    else if (i < S8) { int j = i - S7; bl[j] = lstm_bih[j] + lstm_bhh[j]; }
    else if (i < S9) { deg[i - S8] = 0; }
    else if (i < S10) {
        int g = i - S9;
        int lo = 0, hi = NN;
        while (lo < hi) { int mid = (lo + hi) >> 1; if (batch[mid] < g) lo = mid + 1; else hi = mid; }
        gstart[g] = lo;
    }
    else if (i < S11) { zf[i - S10] = 0.f; }
}
static constexpr int PREP_TOTAL = 16384 * 3 + 49152 * 2 + 65536 + 256 + 196608 + 512 + (NN + 1) + (NG + 1) + 262144;

__global__ void k_count(const int* __restrict__ dst, int* __restrict__ deg, int e) {
    int i = blockIdx.x * blockDim.x + threadIdx.x;
    if (i < e) atomicAdd(&deg[dst[i]], 1);
}

// ---------------- parallel 3-phase exclusive scan of deg -> rowptr (+ bucket cursors) ----------------
__global__ __launch_bounds__(256) void k_scan_blk(const int* __restrict__ deg,
                                                  int* __restrict__ part,
                                                  int* __restrict__ blksum) {
    __shared__ int s[256];
    int b = blockIdx.x, t = threadIdx.x;
    int i = b * 256 + t;
    int v = (i < NN) ? deg[i] : 0;
    s[t] = v;
    __syncthreads();
    #pragma unroll
    for (int off = 1; off < 256; off <<= 1) {
        int x = (t >= off) ? s[t - off] : 0;
        __syncthreads();
        s[t] += x;
        __syncthreads();
    }
    if (i < NN) part[i] = s[t] - v;
    if (t == 255) blksum[b] = s[255];
}
__global__ __launch_bounds__(256) void k_scan_top(const int* __restrict__ blksum,
                                                  int* __restrict__ blkoff) {
    __shared__ int s[256];
    int t = threadIdx.x;
    int v = (t < NBLK) ? blksum[t] : 0;
    s[t] = v;
    __syncthreads();
    #pragma unroll
    for (int off = 1; off < 256; off <<= 1) {
        int x = (t >= off) ? s[t - off] : 0;
        __syncthreads();
        s[t] += x;
        __syncthreads();
    }
    if (t < NBLK) blkoff[t] = s[t] - v;
    if (t == NBLK - 1) blkoff[NBLK] = s[t];
}
__global__ __launch_bounds__(256) void k_scan_add(const int* __restrict__ part,
                                                  const int* __restrict__ blkoff,
                                                  int* __restrict__ rowptr,
                                                  int* __restrict__ bcur) {
    int b = blockIdx.x, t = threadIdx.x;
    int i = b * 256 + t;
    if (i < NN) {
        int r = part[i] + blkoff[b];
        rowptr[i] = r;
        if ((i & 255) == 0) bcur[i >> 8] = r;
    }
    if (b == 0 && t == 0) rowptr[NN] = blkoff[NBLK];
}

// ---------------- bucketed CSR fill ----------------
__global__ __launch_bounds__(256) void k_bucket(const int* __restrict__ src,
                                                const int* __restrict__ dst,
                                                int* __restrict__ bcur,
                                                int2* __restrict__ pairs, int e) {
    __shared__ int lcnt[256];
    __shared__ int lbase[256];
    int tid = threadIdx.x;
    lcnt[tid] = 0;
    __syncthreads();
    int base = blockIdx.x * 4096;
    #pragma unroll
    for (int k = 0; k < 16; ++k) {
        int e0 = base + k * 256 + tid;
        if (e0 < e) atomicAdd(&lcnt[dst[e0] >> 8], 1);
    }
    __syncthreads();
    int cnt = lcnt[tid];
    if (cnt > 0) lbase[tid] = atomicAdd(&bcur[tid], cnt);
    __syncthreads();
    lcnt[tid] = 0;
    __syncthreads();
    #pragma unroll
    for (int k = 0; k < 16; ++k) {
        int e0 = base + k * 256 + tid;
        if (e0 < e) {
            int d = dst[e0];
            int b = d >> 8;
            int off = atomicAdd(&lcnt[b], 1);
            pairs[lbase[b] + off] = make_int2(src[e0], d);
        }
    }
}
__global__ __launch_bounds__(256) void k_fillbkt(const int2* __restrict__ pairs,
                                                 const int* __restrict__ rowptr,
                                                 int* __restrict__ csr) {
    __shared__ int lcur[256];
    int b = blockIdx.x, tid = threadIdx.x;
    int w0 = b << 8;
    int w1 = min(w0 + 256, NN);
    if (w0 + tid < w1) lcur[tid] = rowptr[w0 + tid];
    __syncthreads();
    int r0 = rowptr[w0], r1 = rowptr[w1];
    for (int i = r0 + tid; i < r1; i += 256) {
        int2 p = pairs[i];
        int pos = atomicAdd(&lcur[p.y - w0], 1);
        csr[pos] = p.x;
    }
}

// z[i] = h[i] + sum h[nbr]
__global__ __launch_bounds__(256) void k_aggr8(const ushort* __restrict__ AB,
                                               const int* __restrict__ rowptr,
                                               const int* __restrict__ csr,
                                               ushort* __restrict__ Z) {
    int node = blockIdx.x * 4 + (threadIdx.x >> 6);
    if (node >= NN) return;
    int lane = threadIdx.x & 63;
    const unsigned* base = (const unsigned*)AB;
    unsigned u = base[(size_t)node * 64 + lane];
    float s0a = b2f(u & 0xffff), s0b = b2f(u >> 16);
    float s1a = 0.f, s1b = 0.f, s2a = 0.f, s2b = 0.f, s3a = 0.f, s3b = 0.f;
    float s4a = 0.f, s4b = 0.f, s5a = 0.f, s5b = 0.f, s6a = 0.f, s6b = 0.f, s7a = 0.f, s7b = 0.f;
    int p = rowptr[node], p1 = rowptr[node + 1];
    for (; p + 8 <= p1; p += 8) {
        unsigned v0 = base[(size_t)csr[p + 0] * 64 + lane];
        unsigned v1 = base[(size_t)csr[p + 1] * 64 + lane];
        unsigned v2 = base[(size_t)csr[p + 2] * 64 + lane];
        unsigned v3 = base[(size_t)csr[p + 3] * 64 + lane];
        unsigned v4 = base[(size_t)csr[p + 4] * 64 + lane];
        unsigned v5 = base[(size_t)csr[p + 5] * 64 + lane];
        unsigned v6 = base[(size_t)csr[p + 6] * 64 + lane];
        unsigned v7 = base[(size_t)csr[p + 7] * 64 + lane];
        s0a += b2f(v0 & 0xffff); s0b += b2f(v0 >> 16);
        s1a += b2f(v1 & 0xffff); s1b += b2f(v1 >> 16);
        s2a += b2f(v2 & 0xffff); s2b += b2f(v2 >> 16);
        s3a += b2f(v3 & 0xffff); s3b += b2f(v3 >> 16);
        s4a += b2f(v4 & 0xffff); s4b += b2f(v4 >> 16);
        s5a += b2f(v5 & 0xffff); s5b += b2f(v5 >> 16);
        s6a += b2f(v6 & 0xffff); s6b += b2f(v6 >> 16);
        s7a += b2f(v7 & 0xffff); s7b += b2f(v7 >> 16);
    }
    for (; p < p1; ++p) {
        unsigned v = base[(size_t)csr[p] * 64 + lane];
        s0a += b2f(v & 0xffff); s0b += b2f(v >> 16);
    }
    s0a += (s1a + s2a) + (s3a + s4a) + (s5a + s6a) + s7a;
    s0b += (s1b + s2b) + (s3b + s4b) + (s5b + s6b) + s7b;
    unsigned o = ((unsigned)f2b(s0b) << 16) | (unsigned)f2b(s0a);
    ((unsigned*)(Z + (size_t)node * 128))[lane] = o;
}

// lin0: h = relu(x @ W^T + b), fp32 A; writes AB [NN,128] bf16
__global__ __launch_bounds__(256) void k_lin0(const float* __restrict__ X,
                                              const ushort* __restrict__ W,
                                              const float* __restrict__ bias,
                                              ushort* __restrict__ AB, int n) {
    int lane = threadIdx.x & 63, wave = threadIdx.x >> 6;
    int c0 = lane & 15, kg = (lane >> 4) * 8;
    int tb0 = wave * 32;
    bf16x8 B[2][4];
    #pragma unroll
    for (int t = 0; t < 2; ++t)
        #pragma unroll
        for (int kk = 0; kk < 4; ++kk)
            B[t][kk] = ldb8(W + (size_t)(tb0 + t * 16 + c0) * 128 + kk * 32 + kg);

    for (int m0 = blockIdx.x * 64; m0 < n; m0 += gridDim.x * 64) {
        f32x4 acc[4][2];
        #pragma unroll
        for (int m = 0; m < 4; ++m) { acc[m][0] = {0,0,0,0}; acc[m][1] = {0,0,0,0}; }
        #pragma unroll
        for (int kk = 0; kk < 4; ++kk) {
            #pragma unroll
            for (int m = 0; m < 4; ++m) {
                int ar = min(m0 + m * 16 + c0, n - 1);
                const float* a = X + (size_t)ar * 128 + kk * 32 + kg;
                float4 x0 = *reinterpret_cast<const float4*>(a);
                float4 x1 = *reinterpret_cast<const float4*>(a + 4);
                bf16x8 af;
                af[0] = (short)f2b(x0.x); af[1] = (short)f2b(x0.y);
                af[2] = (short)f2b(x0.z); af[3] = (short)f2b(x0.w);
                af[4] = (short)f2b(x1.x); af[5] = (short)f2b(x1.y);
                af[6] = (short)f2b(x1.z); af[7] = (short)f2b(x1.w);
                acc[m][0] = __builtin_amdgcn_mfma_f32_16x16x32_bf16(af, B[0][kk], acc[m][0], 0, 0, 0);
                acc[m][1] = __builtin_amdgcn_mfma_f32_16x16x32_bf16(af, B[1][kk], acc[m][1], 0, 0, 0);
            }
        }
        #pragma unroll
        for (int m = 0; m < 4; ++m) {
            int rbase = m0 + m * 16 + ((lane >> 4) << 2);
            #pragma unroll
            for (int t = 0; t < 2; ++t) {
                int col = tb0 + t * 16 + c0;
                float bv = bias[col];
                #pragma unroll
                for (int j = 0; j < 4; ++j) {
                    int row = rbase + j;
                    if (row < n) {
                        float v = fmaxf(acc[m][t][j] + bv, 0.f);
                        AB[(size_t)row * 128 + col] = f2b(v);
                    }
                }
            }
        }
    }
}

// ---------------- GIN MLP with register-prefetch pipeline ----------------
__global__ __launch_bounds__(512) void k_ginmlp3(const ushort* __restrict__ Zt,
                                                 const ushort* __restrict__ W1,
                                                 const float* __restrict__ b1,
                                                 const ushort* __restrict__ W2,
                                                 const float* __restrict__ b2,
                                                 ushort* __restrict__ mt, int n) {
    __shared__ ushort Z_lds[32 * 136];
    __shared__ ushort M_lds[32 * 136];
    int tid = threadIdx.x;
    int lane = tid & 63, wave = tid >> 6;
    int c0 = lane & 15, kg = (lane >> 4) * 8;
    int colw = wave * 16 + c0;
    int rj = (lane >> 4) << 2;
    int srow = tid >> 4, scol = (tid & 15) * 8;
    const int stride = gridDim.x * 32;

    bf16x8 B1[4], B2[4];
    #pragma unroll
    for (int kk = 0; kk < 4; ++kk) {
        B1[kk] = ldb8(W1 + (size_t)colw * 128 + kk * 32 + kg);
        B2[kk] = ldb8(W2 + (size_t)colw * 128 + kk * 32 + kg);
    }
    float bv1 = b1[colw], bv2 = b2[colw];

    int m0 = blockIdx.x * 32;
    bf16x8 pz;
    if (m0 < n) pz = ldb8(Zt + (size_t)min(m0 + srow, n - 1) * 128 + scol);
    for (; m0 < n; m0 += stride) {
        *reinterpret_cast<bf16x8*>(&Z_lds[srow * 136 + scol]) = pz;
        __syncthreads();
        int mn = m0 + stride;
        if (mn < n) pz = ldb8(Zt + (size_t)min(mn + srow, n - 1) * 128 + scol);
        {
            f32x4 a[2] = {{0,0,0,0},{0,0,0,0}};
            #pragma unroll
            for (int kk = 0; kk < 4; ++kk) {
                bf16x8 f0 = *reinterpret_cast<const bf16x8*>(&Z_lds[c0 * 136 + kk * 32 + kg]);
                bf16x8 f1 = *reinterpret_cast<const bf16x8*>(&Z_lds[(16 + c0) * 136 + kk * 32 + kg]);
                a[0] = __builtin_amdgcn_mfma_f32_16x16x32_bf16(f0, B1[kk], a[0], 0, 0, 0);
                a[1] = __builtin_amdgcn_mfma_f32_16x16x32_bf16(f1, B1[kk], a[1], 0, 0, 0);
            }
            #pragma unroll
            for (int m = 0; m < 2; ++m)
                #pragma unroll
                for (int j = 0; j < 4; ++j)
                    M_lds[(m * 16 + rj + j) * 136 + colw] = f2b(fmaxf(a[m][j] + bv1, 0.f));
        }
        __syncthreads();
        {
            f32x4 a[2] = {{0,0,0,0},{0,0,0,0}};
            #pragma unroll
            for (int kk = 0; kk < 4; ++kk) {
                bf16x8 f0 = *reinterpret_cast<const bf16x8*>(&M_lds[c0 * 136 + kk * 32 + kg]);
                bf16x8 f1 = *reinterpret_cast<const bf16x8*>(&M_lds[(16 + c0) * 136 + kk * 32 + kg]);
                a[0] = __builtin_amdgcn_mfma_f32_16x16x32_bf16(f0, B2[kk], a[0], 0, 0, 0);
                a[1] = __builtin_amdgcn_mfma_f32_16x16x32_bf16(f1, B2[kk], a[1], 0, 0, 0);
            }
            #pragma unroll
            for (int m = 0; m < 2; ++m)
                #pragma unroll
                for (int j = 0; j < 4; ++j) {
                    int grow = m0 + m * 16 + rj + j;
                    if (grow < n)
                        mt[(size_t)grow * 128 + colw] = f2b(fmaxf(a[m][j] + bv2, 0.f));
                }
        }
        __syncthreads();
    }
}

// ---------------- GRU: rz + ngate fully in-register per wave (no rz_lds, 2 barriers/tile) ----------------
// Wave w owns output cols [16w, 16w+16). rz B-frags: r-cols [16w,16w+16), z-cols [128+16w,+16).
// MFMA C/D layout (col=lane&15, row=(lane>>4)*4+j) makes r/z land in the consuming thread.
template<bool WRITEH>
__global__ __launch_bounds__(512) void k_gru3b(const ushort* __restrict__ ABin,
                                               const ushort* __restrict__ mt,
                                               const ushort* __restrict__ wrz,
                                               const float* __restrict__ brz,
                                               const ushort* __restrict__ Wn,
                                               const ushort* __restrict__ Un,
                                               const float* __restrict__ bin,
                                               const float* __restrict__ bhn,
                                               float* __restrict__ Hf,
                                               ushort* __restrict__ ABout, int n) {
    __shared__ ushort A_lds[32 * 264];   // [h | m]
    int tid = threadIdx.x;
    int lane = tid & 63, wave = tid >> 6;
    int c0 = lane & 15, kg = (lane >> 4) * 8;
    int colw = wave * 16 + c0;
    int rj = (lane >> 4) << 2;
    int srow = tid >> 4, scol = (tid & 15) * 8;
    const int stride = gridDim.x * 32;

    // rz B-frags for this wave's own columns: tt=0 -> r (col base 16w), tt=1 -> z (col base 128+16w)
    bf16x8 Brz[2][8];
    #pragma unroll
    for (int kk = 0; kk < 8; ++kk) {
        Brz[0][kk] = ldb8(wrz + (size_t)(colw) * 256 + kk * 32 + kg);
        Brz[1][kk] = ldb8(wrz + (size_t)(128 + colw) * 256 + kk * 32 + kg);
    }
    bf16x8 Bn[4], Bu[4];
    #pragma unroll
    for (int kk = 0; kk < 4; ++kk) {
        Bn[kk] = ldb8(Wn + (size_t)colw * 128 + kk * 32 + kg);
        Bu[kk] = ldb8(Un + (size_t)colw * 128 + kk * 32 + kg);
    }
    float biN = bin[colw], bhN = bhn[colw];
    float brzR = brz[colw], brzZ = brz[128 + colw];

    int m0 = blockIdx.x * 32;
    bf16x8 ph, pm;
    if (m0 < n) {
        int gr = min(m0 + srow, n - 1);
        ph = ldb8(ABin + (size_t)gr * 128 + scol);
        pm = ldb8(mt + (size_t)gr * 128 + scol);
    }
    for (; m0 < n; m0 += stride) {
        *reinterpret_cast<bf16x8*>(&A_lds[srow * 264 + scol]) = ph;
        *reinterpret_cast<bf16x8*>(&A_lds[srow * 264 + 128 + scol]) = pm;
        __syncthreads();
        // prefetch next tile under the MFMA work
        int mn = m0 + stride;
        if (mn < n) {
            int gr = min(mn + srow, n - 1);
            ph = ldb8(ABin + (size_t)gr * 128 + scol);
            pm = ldb8(mt + (size_t)gr * 128 + scol);
        }
        // rz (K=256) + ngate (K=128 x2), all accs in registers
        f32x4 aR[2] = {{0,0,0,0},{0,0,0,0}};
        f32x4 aZ[2] = {{0,0,0,0},{0,0,0,0}};
        #pragma unroll
        for (int kk = 0; kk < 8; ++kk) {
            bf16x8 f0 = *reinterpret_cast<const bf16x8*>(&A_lds[c0 * 264 + kk * 32 + kg]);
            bf16x8 f1 = *reinterpret_cast<const bf16x8*>(&A_lds[(16 + c0) * 264 + kk * 32 + kg]);
            aR[0] = __builtin_amdgcn_mfma_f32_16x16x32_bf16(f0, Brz[0][kk], aR[0], 0, 0, 0);
            aZ[0] = __builtin_amdgcn_mfma_f32_16x16x32_bf16(f0, Brz[1][kk], aZ[0], 0, 0, 0);
            aR[1] = __builtin_amdgcn_mfma_f32_16x16x32_bf16(f1, Brz[0][kk], aR[1], 0, 0, 0);
            aZ[1] = __builtin_amdgcn_mfma_f32_16x16x32_bf16(f1, Brz[1][kk], aZ[1], 0, 0, 0);
        }
        f32x4 an[2] = {{0,0,0,0},{0,0,0,0}};
        f32x4 au[2] = {{0,0,0,0},{0,0,0,0}};
        #pragma unroll
        for (int kk = 0; kk < 4; ++kk) {
            bf16x8 am0 = *reinterpret_cast<const bf16x8*>(&A_lds[c0 * 264 + 128 + kk * 32 + kg]);
            bf16x8 ah0 = *reinterpret_cast<const bf16x8*>(&A_lds[c0 * 264 + kk * 32 + kg]);
            bf16x8 am1 = *reinterpret_cast<const bf16x8*>(&A_lds[(16 + c0) * 264 + 128 + kk * 32 + kg]);
            bf16x8 ah1 = *reinterpret_cast<const bf16x8*>(&A_lds[(16 + c0) * 264 + kk * 32 + kg]);
            an[0] = __builtin_amdgcn_mfma_f32_16x16x32_bf16(am0, Bn[kk], an[0], 0, 0, 0);
            au[0] = __builtin_amdgcn_mfma_f32_16x16x32_bf16(ah0, Bu[kk], au[0], 0, 0, 0);
            an[1] = __builtin_amdgcn_mfma_f32_16x16x32_bf16(am1, Bn[kk], an[1], 0, 0, 0);
            au[1] = __builtin_amdgcn_mfma_f32_16x16x32_bf16(ah1, Bu[kk], au[1], 0, 0, 0);
        }
        #pragma unroll
        for (int m = 0; m < 2; ++m)
            #pragma unroll
            for (int j = 0; j < 4; ++j) {
                int row = m * 16 + rj + j;
                int grow = m0 + row;
                if (grow < n) {
                    float r  = sigm(aR[m][j] + brzR);
                    float zt = sigm(aZ[m][j] + brzZ);
                    float hold = b2f(A_lds[row * 264 + colw]);
                    float nn = ftanh(an[m][j] + biN + r * (au[m][j] + bhN));
                    float hn = (1.f - zt) * nn + zt * hold;
                    ABout[(size_t)grow * 128 + colw] = f2b(hn);
                    if (WRITEH) Hf[(size_t)grow * 128 + colw] = hn;
                }
            }
        __syncthreads();
    }
}

// ---------------- fused Set2Set step: LSTM cell + online-softmax attention pool ----------------
__global__ __launch_bounds__(512) void k_s2s(const ushort* __restrict__ AB,
                                             const float* __restrict__ Wt,
                                             const float* __restrict__ bl,
                                             const int* __restrict__ gstart,
                                             const float* __restrict__ qstar,
                                             float* __restrict__ hl,
                                             float* __restrict__ cl,
                                             float* __restrict__ qout) {
    int g = blockIdx.x, tid = threadIdx.x, lane = tid & 63, wave = tid >> 6;
    __shared__ float qh[384];
    __shared__ float gbuf[512];
    __shared__ float q[128];
    __shared__ float wm[8];
    __shared__ float sw[8];
    __shared__ float rv[8][128];
    if (tid < 256) qh[tid] = qstar[(size_t)g * 256 + tid];
    else if (tid < 384) qh[tid] = hl[(size_t)g * 128 + (tid - 256)];
    __syncthreads();
    float acc = bl[tid];
    #pragma unroll 8
    for (int k = 0; k < 384; ++k)
        acc += Wt[(size_t)k * 512 + tid] * qh[k];
    gbuf[tid] = acc;
    __syncthreads();
    if (tid < 128) {
        float iv = sigm(gbuf[tid]);
        float fv = sigm(gbuf[128 + tid]);
        float gv = ftanh(gbuf[256 + tid]);
        float ov = sigm(gbuf[384 + tid]);
        float cn = fv * cl[(size_t)g * 128 + tid] + iv * gv;
        cl[(size_t)g * 128 + tid] = cn;
        float hn = ov * ftanh(cn);
        hl[(size_t)g * 128 + tid] = hn;
        q[tid] = hn;
    }
    __syncthreads();
    int s = gstart[g], e = gstart[g + 1];
    float q0 = q[2 * lane], q1 = q[2 * lane + 1];
    float mx = -1e30f, sumw = 0.f, a0 = 0.f, a1 = 0.f;
    for (int node = s + wave; node < e; node += 8) {
        unsigned u = ((const unsigned*)AB)[(size_t)node * 64 + lane];
        float v0 = b2f(u & 0xffff), v1 = b2f(u >> 16);
        float p = v0 * q0 + v1 * q1;
        #pragma unroll
        for (int off = 1; off < 64; off <<= 1) p += __shfl_xor(p, off);
        float nm = fmaxf(mx, p);
        float corr = __expf(mx - nm);
        float wgt = __expf(p - nm);
        sumw = sumw * corr + wgt;
        a0 = a0 * corr + wgt * v0;
        a1 = a1 * corr + wgt * v1;
        mx = nm;
    }
    if (lane == 0) wm[wave] = mx;
    __syncthreads();
    float gm = fmaxf(fmaxf(fmaxf(wm[0], wm[1]), fmaxf(wm[2], wm[3])),
                     fmaxf(fmaxf(wm[4], wm[5]), fmaxf(wm[6], wm[7])));
    float cw = __expf(mx - gm);
    rv[wave][2 * lane] = a0 * cw;
    rv[wave][2 * lane + 1] = a1 * cw;
    if (lane == 0) sw[wave] = sumw * cw;
    __syncthreads();
    if (tid < 128) {
        float r = 0.f, d = 1e-16f;
        #pragma unroll
        for (int wv = 0; wv < 8; ++wv) r += rv[wv][tid];
        #pragma unroll
        for (int wv = 0; wv < 8; ++wv) d += sw[wv];
        qout[(size_t)g * 256 + tid] = q[tid];
        qout[(size_t)g * 256 + 128 + tid] = r / d;
    }
}

// ---------------- launch ----------------
extern "C" void kernel_launch(void* const* d_in, const int* in_sizes, int n_in,
                              void* d_out, int out_size, void* d_ws, size_t ws_size,
                              hipStream_t stream) {
    const float* x        = (const float*)d_in[0];
    const int*   ei       = (const int*)d_in[1];
    const int*   batch    = (const int*)d_in[2];
    const float* lin0_W   = (const float*)d_in[3];
    const float* lin0_b   = (const float*)d_in[4];
    const float* gin_W1   = (const float*)d_in[5];
    const float* gin_b1   = (const float*)d_in[6];
    const float* gin_W2   = (const float*)d_in[7];
    const float* gin_b2   = (const float*)d_in[8];
    const float* gru_Wih  = (const float*)d_in[9];
    const float* gru_Whh  = (const float*)d_in[10];
    const float* gru_bih  = (const float*)d_in[11];
    const float* gru_bhh  = (const float*)d_in[12];
    const float* lstm_Wih = (const float*)d_in[13];
    const float* lstm_Whh = (const float*)d_in[14];
    const float* lstm_bih = (const float*)d_in[15];
    const float* lstm_bhh = (const float*)d_in[16];

    float* qstar_out = (float*)d_out;                         // [NG, 256]
    float* h         = (float*)d_out + (size_t)NG * 2 * DIM;  // [NN, 128] fp32 == `out`

    char* w = (char*)d_ws;
    ushort* AB0   = (ushort*)w; w += (size_t)NN * 128 * 2;   // ping (h only)
    ushort* AB1   = (ushort*)w; w += (size_t)NN * 128 * 2;   // pong (h only)
    ushort* zt    = (ushort*)w; w += (size_t)NN * 128 * 2;   // aggr out
    ushort* mt    = (ushort*)w; w += (size_t)NN * 128 * 2;   // GIN MLP out
    ushort* wlin0 = (ushort*)w; w += 16384 * 2;
    ushort* wg1   = (ushort*)w; w += 16384 * 2;
    ushort* wg2   = (ushort*)w; w += 16384 * 2;
    ushort* wihb  = (ushort*)w; w += 49152 * 2;
    ushort* whhb  = (ushort*)w; w += 49152 * 2;
    ushort* wrz   = (ushort*)w; w += 65536 * 2;
    float* brz    = (float*)w;  w += 256 * 4;
    float* wltr   = (float*)w;  w += (size_t)512 * 384 * 4;  // LSTM W transposed
    float* bl     = (float*)w;  w += 512 * 4;
    float* qstar  = (float*)w;  w += (size_t)NG * 2 * DIM * 4;  // contiguous with hl, cl
    float* hl     = (float*)w;  w += (size_t)NG * DIM * 4;
    float* cl     = (float*)w;  w += (size_t)NG * DIM * 4;
    int* deg      = (int*)w;    w += (size_t)(NN + 1) * 4;
    int* rowptr   = (int*)w;    w += (size_t)(NN + 1) * 4;
    int* bcur     = (int*)w;    w += 256 * 4;
    int* csr_src  = (int*)w;    w += (size_t)NE * 4;
    int2* pairs   = (int2*)w;   w += (size_t)NE * 8;
    int* gstart   = (int*)w;    w += (size_t)(NG + 1) * 4;
    int* part     = (int*)w;    w += (size_t)NN * 4;
    int* blksum   = (int*)w;    w += (size_t)(NBLK + 1) * 4;
    int* blkoff   = (int*)w;    w += (size_t)(NBLK + 1) * 4;

    const int* src = ei;
    const int* dst = ei + NE;

    // one mega-prep
    k_prep<<<(PREP_TOTAL + 255) / 256, 256, 0, stream>>>(
        lin0_W, gin_W1, gin_W2, gru_Wih, gru_Whh, gru_bih, gru_bhh,
        lstm_Wih, lstm_Whh, lstm_bih, lstm_bhh, batch,
        wlin0, wg1, wg2, wihb, whhb, wrz, brz, wltr, bl, deg, gstart, qstar);

    // CSR build
    k_count<<<(NE + 255) / 256, 256, 0, stream>>>(dst, deg, NE);
    k_scan_blk<<<NBLK, 256, 0, stream>>>(deg, part, blksum);
    k_scan_top<<<1, 256, 0, stream>>>(blksum, blkoff);
    k_scan_add<<<NBLK, 256, 0, stream>>>(part, blkoff, rowptr, bcur);
    k_bucket<<<(NE + 4095) / 4096, 256, 0, stream>>>(src, dst, bcur, pairs, NE);
    k_fillbkt<<<NBLK, 256, 0, stream>>>(pairs, rowptr, csr_src);

    // lin0 -> AB0
    k_lin0<<<782, 256, 0, stream>>>(x, wlin0, lin0_b, AB0, NN);

    // 3 GC layers, ping-pong AB buffers
    for (int t = 0; t < 3; ++t) {
        ushort* ABc = (t & 1) ? AB1 : AB0;
        ushort* ABn = (t & 1) ? AB0 : AB1;
        k_aggr8<<<(NN + 3) / 4, 256, 0, stream>>>(ABc, rowptr, csr_src, zt);
        k_ginmlp3<<<1024, 512, 0, stream>>>(zt, wg1, gin_b1, wg2, gin_b2, mt, NN);
        if (t < 2)
            k_gru3b<false><<<512, 512, 0, stream>>>(ABc, mt, wrz, brz,
                                                    wihb + 256 * 128, whhb + 256 * 128,
                                                    gru_bih + 256, gru_bhh + 256, h, ABn, NN);
        else
            k_gru3b<true><<<512, 512, 0, stream>>>(ABc, mt, wrz, brz,
                                                   wihb + 256 * 128, whhb + 256 * 128,
                                                   gru_bih + 256, gru_bhh + 256, h, ABn, NN);
    }
    // final bf16 h lives in AB1 (t=2 wrote ABn=AB1)
    const ushort* ABfin = AB1;

    // Set2Set (fused LSTM + attention per step)
    for (int st = 0; st < 3; ++st)
        k_s2s<<<NG, 512, 0, stream>>>(ABfin, wltr, bl, gstart, qstar, hl, cl,
                                      (st == 2) ? qstar_out : qstar);
}

// Round 17
// 407.936 us; speedup vs baseline: 1.1479x; 1.0014x over previous
//
#include <hip/hip_runtime.h>
#include <hip/hip_bf16.h>
#include <math.h>

static constexpr int NN  = 50000;   // nodes
static constexpr int NE  = 800000;  // edges
static constexpr int DIM = 128;
static constexpr int NG  = 512;     // graphs
static constexpr int NBLK = (NN + 255) / 256;  // 196 scan blocks / buckets

typedef __attribute__((ext_vector_type(8))) short bf16x8;
typedef __attribute__((ext_vector_type(4))) float f32x4;

__device__ __forceinline__ float sigm(float x) {
    return __builtin_amdgcn_rcpf(1.0f + __expf(-x));
}
__device__ __forceinline__ float ftanh(float x) {
    x = fminf(fmaxf(x, -15.f), 15.f);
    float t = __expf(2.f * x);
    return (t - 1.f) * __builtin_amdgcn_rcpf(t + 1.f);
}
__device__ __forceinline__ float b2f(ushort u) { return __uint_as_float(((unsigned)u) << 16); }
__device__ __forceinline__ ushort f2b(float f) {
    __hip_bfloat16 h = __float2bfloat16(f);
    return *reinterpret_cast<ushort*>(&h);
}
__device__ __forceinline__ bf16x8 ldb8(const ushort* p) {
    return *reinterpret_cast<const bf16x8*>(p);
}

// ---------------- mega-prep: all weight conversions + init in one kernel ----------------
__global__ __launch_bounds__(256) void k_prep(const float* __restrict__ lin0_W,
                                              const float* __restrict__ gin_W1,
                                              const float* __restrict__ gin_W2,
                                              const float* __restrict__ gru_Wih,
                                              const float* __restrict__ gru_Whh,
                                              const float* __restrict__ gru_bih,
                                              const float* __restrict__ gru_bhh,
                                              const float* __restrict__ lstm_Wih,
                                              const float* __restrict__ lstm_Whh,
                                              const float* __restrict__ lstm_bih,
                                              const float* __restrict__ lstm_bhh,
                                              const int* __restrict__ batch,
                                              ushort* __restrict__ wlin0,
                                              ushort* __restrict__ wg1,
                                              ushort* __restrict__ wg2,
                                              ushort* __restrict__ wihb,
                                              ushort* __restrict__ whhb,
                                              ushort* __restrict__ wrz,
                                              float* __restrict__ brz,
                                              float* __restrict__ wltr,
                                              float* __restrict__ bl,
                                              int* __restrict__ deg,
                                              int* __restrict__ gstart,
                                              float* __restrict__ zf) {
    const int S0 = 16384, S1 = S0 + 16384, S2 = S1 + 16384;
    const int S3 = S2 + 49152, S4 = S3 + 49152, S5 = S4 + 65536;
    const int S6 = S5 + 256, S7 = S6 + 196608, S8 = S7 + 512;
    const int S9 = S8 + (NN + 1), S10 = S9 + (NG + 1), S11 = S10 + 262144;
    int i = blockIdx.x * 256 + threadIdx.x;
    if (i < S0) { wlin0[i] = f2b(lin0_W[i]); }
    else if (i < S1) { int j = i - S0; wg1[j] = f2b(gin_W1[j]); }
    else if (i < S2) { int j = i - S1; wg2[j] = f2b(gin_W2[j]); }
    else if (i < S3) { int j = i - S2; wihb[j] = f2b(gru_Wih[j]); }
    else if (i < S4) { int j = i - S3; whhb[j] = f2b(gru_Whh[j]); }
    else if (i < S5) {
        int j = i - S4; int col = j >> 8, k = j & 255;
        int row = (col >> 7) * 128 + (col & 127);
        wrz[j] = f2b((k < 128) ? gru_Whh[row * 128 + k] : gru_Wih[row * 128 + (k - 128)]);
    }
    else if (i < S6) { int j = i - S5; brz[j] = gru_bih[j] + gru_bhh[j]; }
    else if (i < S7) {
        int j = i - S6; int k = j / 512, col = j % 512;
        wltr[j] = (k < 256) ? lstm_Wih[(size_t)col * 256 + k]
                            : lstm_Whh[(size_t)col * 128 + (k - 256)];
    }
    else if (i < S8) { int j = i - S7; bl[j] = lstm_bih[j] + lstm_bhh[j]; }
    else if (i < S9) { deg[i - S8] = 0; }
    else if (i < S10) {
        int g = i - S9;
        int lo = 0, hi = NN;
        while (lo < hi) { int mid = (lo + hi) >> 1; if (batch[mid] < g) lo = mid + 1; else hi = mid; }
        gstart[g] = lo;
    }
    else if (i < S11) { zf[i - S10] = 0.f; }
}
static constexpr int PREP_TOTAL = 16384 * 3 + 49152 * 2 + 65536 + 256 + 196608 + 512 + (NN + 1) + (NG + 1) + 262144;

__global__ void k_count(const int* __restrict__ dst, int* __restrict__ deg, int e) {
    int i = blockIdx.x * blockDim.x + threadIdx.x;
    if (i < e) atomicAdd(&deg[dst[i]], 1);
}

// ---------------- parallel 3-phase exclusive scan of deg -> rowptr (+ bucket cursors) ----------------
__global__ __launch_bounds__(256) void k_scan_blk(const int* __restrict__ deg,
                                                  int* __restrict__ part,
                                                  int* __restrict__ blksum) {
    __shared__ int s[256];
    int b = blockIdx.x, t = threadIdx.x;
    int i = b * 256 + t;
    int v = (i < NN) ? deg[i] : 0;
    s[t] = v;
    __syncthreads();
    #pragma unroll
    for (int off = 1; off < 256; off <<= 1) {
        int x = (t >= off) ? s[t - off] : 0;
        __syncthreads();
        s[t] += x;
        __syncthreads();
    }
    if (i < NN) part[i] = s[t] - v;
    if (t == 255) blksum[b] = s[255];
}
__global__ __launch_bounds__(256) void k_scan_top(const int* __restrict__ blksum,
                                                  int* __restrict__ blkoff) {
    __shared__ int s[256];
    int t = threadIdx.x;
    int v = (t < NBLK) ? blksum[t] : 0;
    s[t] = v;
    __syncthreads();
    #pragma unroll
    for (int off = 1; off < 256; off <<= 1) {
        int x = (t >= off) ? s[t - off] : 0;
        __syncthreads();
        s[t] += x;
        __syncthreads();
    }
    if (t < NBLK) blkoff[t] = s[t] - v;
    if (t == NBLK - 1) blkoff[NBLK] = s[t];
}
__global__ __launch_bounds__(256) void k_scan_add(const int* __restrict__ part,
                                                  const int* __restrict__ blkoff,
                                                  int* __restrict__ rowptr,
                                                  int* __restrict__ bcur) {
    int b = blockIdx.x, t = threadIdx.x;
    int i = b * 256 + t;
    if (i < NN) {
        int r = part[i] + blkoff[b];
        rowptr[i] = r;
        if ((i & 255) == 0) bcur[i >> 8] = r;
    }
    if (b == 0 && t == 0) rowptr[NN] = blkoff[NBLK];
}

// ---------------- bucketed CSR fill ----------------
__global__ __launch_bounds__(256) void k_bucket(const int* __restrict__ src,
                                                const int* __restrict__ dst,
                                                int* __restrict__ bcur,
                                                int2* __restrict__ pairs, int e) {
    __shared__ int lcnt[256];
    __shared__ int lbase[256];
    int tid = threadIdx.x;
    lcnt[tid] = 0;
    __syncthreads();
    int base = blockIdx.x * 4096;
    #pragma unroll
    for (int k = 0; k < 16; ++k) {
        int e0 = base + k * 256 + tid;
        if (e0 < e) atomicAdd(&lcnt[dst[e0] >> 8], 1);
    }
    __syncthreads();
    int cnt = lcnt[tid];
    if (cnt > 0) lbase[tid] = atomicAdd(&bcur[tid], cnt);
    __syncthreads();
    lcnt[tid] = 0;
    __syncthreads();
    #pragma unroll
    for (int k = 0; k < 16; ++k) {
        int e0 = base + k * 256 + tid;
        if (e0 < e) {
            int d = dst[e0];
            int b = d >> 8;
            int off = atomicAdd(&lcnt[b], 1);
            pairs[lbase[b] + off] = make_int2(src[e0], d);
        }
    }
}
__global__ __launch_bounds__(256) void k_fillbkt(const int2* __restrict__ pairs,
                                                 const int* __restrict__ rowptr,
                                                 int* __restrict__ csr) {
    __shared__ int lcur[256];
    int b = blockIdx.x, tid = threadIdx.x;
    int w0 = b << 8;
    int w1 = min(w0 + 256, NN);
    if (w0 + tid < w1) lcur[tid] = rowptr[w0 + tid];
    __syncthreads();
    int r0 = rowptr[w0], r1 = rowptr[w1];
    for (int i = r0 + tid; i < r1; i += 256) {
        int2 p = pairs[i];
        int pos = atomicAdd(&lcur[p.y - w0], 1);
        csr[pos] = p.x;
    }
}

// z[i] = h[i] + sum h[nbr]; uint2 loads, 32 lanes/node, 8 nodes/block, 8-deep MLP
__global__ __launch_bounds__(256) void k_aggr8(const ushort* __restrict__ AB,
                                               const int* __restrict__ rowptr,
                                               const int* __restrict__ csr,
                                               ushort* __restrict__ Z) {
    int node = blockIdx.x * 8 + (threadIdx.x >> 5);
    if (node >= NN) return;
    int lane = threadIdx.x & 31;
    const uint2* base = (const uint2*)AB;   // 32 uint2 (256B) per row
    uint2 u = base[(size_t)node * 32 + lane];
    float s0a = b2f(u.x & 0xffff), s0b = b2f(u.x >> 16);
    float s0c = b2f(u.y & 0xffff), s0d = b2f(u.y >> 16);
    float s1a = 0.f, s1b = 0.f, s1c = 0.f, s1d = 0.f;
    float s2a = 0.f, s2b = 0.f, s2c = 0.f, s2d = 0.f;
    float s3a = 0.f, s3b = 0.f, s3c = 0.f, s3d = 0.f;
    float s4a = 0.f, s4b = 0.f, s4c = 0.f, s4d = 0.f;
    float s5a = 0.f, s5b = 0.f, s5c = 0.f, s5d = 0.f;
    float s6a = 0.f, s6b = 0.f, s6c = 0.f, s6d = 0.f;
    float s7a = 0.f, s7b = 0.f, s7c = 0.f, s7d = 0.f;
    int p = rowptr[node], p1 = rowptr[node + 1];
    for (; p + 8 <= p1; p += 8) {
        uint2 v0 = base[(size_t)csr[p + 0] * 32 + lane];
        uint2 v1 = base[(size_t)csr[p + 1] * 32 + lane];
        uint2 v2 = base[(size_t)csr[p + 2] * 32 + lane];
        uint2 v3 = base[(size_t)csr[p + 3] * 32 + lane];
        uint2 v4 = base[(size_t)csr[p + 4] * 32 + lane];
        uint2 v5 = base[(size_t)csr[p + 5] * 32 + lane];
        uint2 v6 = base[(size_t)csr[p + 6] * 32 + lane];
        uint2 v7 = base[(size_t)csr[p + 7] * 32 + lane];
        s0a += b2f(v0.x & 0xffff); s0b += b2f(v0.x >> 16); s0c += b2f(v0.y & 0xffff); s0d += b2f(v0.y >> 16);
        s1a += b2f(v1.x & 0xffff); s1b += b2f(v1.x >> 16); s1c += b2f(v1.y & 0xffff); s1d += b2f(v1.y >> 16);
        s2a += b2f(v2.x & 0xffff); s2b += b2f(v2.x >> 16); s2c += b2f(v2.y & 0xffff); s2d += b2f(v2.y >> 16);
        s3a += b2f(v3.x & 0xffff); s3b += b2f(v3.x >> 16); s3c += b2f(v3.y & 0xffff); s3d += b2f(v3.y >> 16);
        s4a += b2f(v4.x & 0xffff); s4b += b2f(v4.x >> 16); s4c += b2f(v4.y & 0xffff); s4d += b2f(v4.y >> 16);
        s5a += b2f(v5.x & 0xffff); s5b += b2f(v5.x >> 16); s5c += b2f(v5.y & 0xffff); s5d += b2f(v5.y >> 16);
        s6a += b2f(v6.x & 0xffff); s6b += b2f(v6.x >> 16); s6c += b2f(v6.y & 0xffff); s6d += b2f(v6.y >> 16);
        s7a += b2f(v7.x & 0xffff); s7b += b2f(v7.x >> 16); s7c += b2f(v7.y & 0xffff); s7d += b2f(v7.y >> 16);
    }
    for (; p < p1; ++p) {
        uint2 v = base[(size_t)csr[p] * 32 + lane];
        s0a += b2f(v.x & 0xffff); s0b += b2f(v.x >> 16);
        s0c += b2f(v.y & 0xffff); s0d += b2f(v.y >> 16);
    }
    s0a += (s1a + s2a) + (s3a + s4a) + (s5a + s6a) + s7a;
    s0b += (s1b + s2b) + (s3b + s4b) + (s5b + s6b) + s7b;
    s0c += (s1c + s2c) + (s3c + s4c) + (s5c + s6c) + s7c;
    s0d += (s1d + s2d) + (s3d + s4d) + (s5d + s6d) + s7d;
    uint2 o;
    o.x = ((unsigned)f2b(s0b) << 16) | (unsigned)f2b(s0a);
    o.y = ((unsigned)f2b(s0d) << 16) | (unsigned)f2b(s0c);
    ((uint2*)(Z + (size_t)node * 128))[lane] = o;
}

// lin0: h = relu(x @ W^T + b), fp32 A; writes AB [NN,128] bf16
__global__ __launch_bounds__(256) void k_lin0(const float* __restrict__ X,
                                              const ushort* __restrict__ W,
                                              const float* __restrict__ bias,
                                              ushort* __restrict__ AB, int n) {
    int lane = threadIdx.x & 63, wave = threadIdx.x >> 6;
    int c0 = lane & 15, kg = (lane >> 4) * 8;
    int tb0 = wave * 32;
    bf16x8 B[2][4];
    #pragma unroll
    for (int t = 0; t < 2; ++t)
        #pragma unroll
        for (int kk = 0; kk < 4; ++kk)
            B[t][kk] = ldb8(W + (size_t)(tb0 + t * 16 + c0) * 128 + kk * 32 + kg);

    for (int m0 = blockIdx.x * 64; m0 < n; m0 += gridDim.x * 64) {
        f32x4 acc[4][2];
        #pragma unroll
        for (int m = 0; m < 4; ++m) { acc[m][0] = {0,0,0,0}; acc[m][1] = {0,0,0,0}; }
        #pragma unroll
        for (int kk = 0; kk < 4; ++kk) {
            #pragma unroll
            for (int m = 0; m < 4; ++m) {
                int ar = min(m0 + m * 16 + c0, n - 1);
                const float* a = X + (size_t)ar * 128 + kk * 32 + kg;
                float4 x0 = *reinterpret_cast<const float4*>(a);
                float4 x1 = *reinterpret_cast<const float4*>(a + 4);
                bf16x8 af;
                af[0] = (short)f2b(x0.x); af[1] = (short)f2b(x0.y);
                af[2] = (short)f2b(x0.z); af[3] = (short)f2b(x0.w);
                af[4] = (short)f2b(x1.x); af[5] = (short)f2b(x1.y);
                af[6] = (short)f2b(x1.z); af[7] = (short)f2b(x1.w);
                acc[m][0] = __builtin_amdgcn_mfma_f32_16x16x32_bf16(af, B[0][kk], acc[m][0], 0, 0, 0);
                acc[m][1] = __builtin_amdgcn_mfma_f32_16x16x32_bf16(af, B[1][kk], acc[m][1], 0, 0, 0);
            }
        }
        #pragma unroll
        for (int m = 0; m < 4; ++m) {
            int rbase = m0 + m * 16 + ((lane >> 4) << 2);
            #pragma unroll
            for (int t = 0; t < 2; ++t) {
                int col = tb0 + t * 16 + c0;
                float bv = bias[col];
                #pragma unroll
                for (int j = 0; j < 4; ++j) {
                    int row = rbase + j;
                    if (row < n) {
                        float v = fmaxf(acc[m][t][j] + bv, 0.f);
                        AB[(size_t)row * 128 + col] = f2b(v);
                    }
                }
            }
        }
    }
}

// ---------------- GIN MLP with register-prefetch pipeline ----------------
__global__ __launch_bounds__(512) void k_ginmlp3(const ushort* __restrict__ Zt,
                                                 const ushort* __restrict__ W1,
                                                 const float* __restrict__ b1,
                                                 const ushort* __restrict__ W2,
                                                 const float* __restrict__ b2,
                                                 ushort* __restrict__ mt, int n) {
    __shared__ ushort Z_lds[32 * 136];
    __shared__ ushort M_lds[32 * 136];
    int tid = threadIdx.x;
    int lane = tid & 63, wave = tid >> 6;
    int c0 = lane & 15, kg = (lane >> 4) * 8;
    int colw = wave * 16 + c0;
    int rj = (lane >> 4) << 2;
    int srow = tid >> 4, scol = (tid & 15) * 8;
    const int stride = gridDim.x * 32;

    bf16x8 B1[4], B2[4];
    #pragma unroll
    for (int kk = 0; kk < 4; ++kk) {
        B1[kk] = ldb8(W1 + (size_t)colw * 128 + kk * 32 + kg);
        B2[kk] = ldb8(W2 + (size_t)colw * 128 + kk * 32 + kg);
    }
    float bv1 = b1[colw], bv2 = b2[colw];

    int m0 = blockIdx.x * 32;
    bf16x8 pz;
    if (m0 < n) pz = ldb8(Zt + (size_t)min(m0 + srow, n - 1) * 128 + scol);
    for (; m0 < n; m0 += stride) {
        *reinterpret_cast<bf16x8*>(&Z_lds[srow * 136 + scol]) = pz;
        __syncthreads();
        int mn = m0 + stride;
        if (mn < n) pz = ldb8(Zt + (size_t)min(mn + srow, n - 1) * 128 + scol);
        {
            f32x4 a[2] = {{0,0,0,0},{0,0,0,0}};
            #pragma unroll
            for (int kk = 0; kk < 4; ++kk) {
                bf16x8 f0 = *reinterpret_cast<const bf16x8*>(&Z_lds[c0 * 136 + kk * 32 + kg]);
                bf16x8 f1 = *reinterpret_cast<const bf16x8*>(&Z_lds[(16 + c0) * 136 + kk * 32 + kg]);
                a[0] = __builtin_amdgcn_mfma_f32_16x16x32_bf16(f0, B1[kk], a[0], 0, 0, 0);
                a[1] = __builtin_amdgcn_mfma_f32_16x16x32_bf16(f1, B1[kk], a[1], 0, 0, 0);
            }
            #pragma unroll
            for (int m = 0; m < 2; ++m)
                #pragma unroll
                for (int j = 0; j < 4; ++j)
                    M_lds[(m * 16 + rj + j) * 136 + colw] = f2b(fmaxf(a[m][j] + bv1, 0.f));
        }
        __syncthreads();
        {
            f32x4 a[2] = {{0,0,0,0},{0,0,0,0}};
            #pragma unroll
            for (int kk = 0; kk < 4; ++kk) {
                bf16x8 f0 = *reinterpret_cast<const bf16x8*>(&M_lds[c0 * 136 + kk * 32 + kg]);
                bf16x8 f1 = *reinterpret_cast<const bf16x8*>(&M_lds[(16 + c0) * 136 + kk * 32 + kg]);
                a[0] = __builtin_amdgcn_mfma_f32_16x16x32_bf16(f0, B2[kk], a[0], 0, 0, 0);
                a[1] = __builtin_amdgcn_mfma_f32_16x16x32_bf16(f1, B2[kk], a[1], 0, 0, 0);
            }
            #pragma unroll
            for (int m = 0; m < 2; ++m)
                #pragma unroll
                for (int j = 0; j < 4; ++j) {
                    int grow = m0 + m * 16 + rj + j;
                    if (grow < n)
                        mt[(size_t)grow * 128 + colw] = f2b(fmaxf(a[m][j] + bv2, 0.f));
                }
        }
        __syncthreads();
    }
}

// ---------------- GRU: rz + ngate fully in-register per wave (no rz_lds, 2 barriers/tile) ----------------
template<bool WRITEH>
__global__ __launch_bounds__(512) void k_gru3b(const ushort* __restrict__ ABin,
                                               const ushort* __restrict__ mt,
                                               const ushort* __restrict__ wrz,
                                               const float* __restrict__ brz,
                                               const ushort* __restrict__ Wn,
                                               const ushort* __restrict__ Un,
                                               const float* __restrict__ bin,
                                               const float* __restrict__ bhn,
                                               float* __restrict__ Hf,
                                               ushort* __restrict__ ABout, int n) {
    __shared__ ushort A_lds[32 * 264];   // [h | m]
    int tid = threadIdx.x;
    int lane = tid & 63, wave = tid >> 6;
    int c0 = lane & 15, kg = (lane >> 4) * 8;
    int colw = wave * 16 + c0;
    int rj = (lane >> 4) << 2;
    int srow = tid >> 4, scol = (tid & 15) * 8;
    const int stride = gridDim.x * 32;

    bf16x8 Brz[2][8];
    #pragma unroll
    for (int kk = 0; kk < 8; ++kk) {
        Brz[0][kk] = ldb8(wrz + (size_t)(colw) * 256 + kk * 32 + kg);
        Brz[1][kk] = ldb8(wrz + (size_t)(128 + colw) * 256 + kk * 32 + kg);
    }
    bf16x8 Bn[4], Bu[4];
    #pragma unroll
    for (int kk = 0; kk < 4; ++kk) {
        Bn[kk] = ldb8(Wn + (size_t)colw * 128 + kk * 32 + kg);
        Bu[kk] = ldb8(Un + (size_t)colw * 128 + kk * 32 + kg);
    }
    float biN = bin[colw], bhN = bhn[colw];
    float brzR = brz[colw], brzZ = brz[128 + colw];

    int m0 = blockIdx.x * 32;
    bf16x8 ph, pm;
    if (m0 < n) {
        int gr = min(m0 + srow, n - 1);
        ph = ldb8(ABin + (size_t)gr * 128 + scol);
        pm = ldb8(mt + (size_t)gr * 128 + scol);
    }
    for (; m0 < n; m0 += stride) {
        *reinterpret_cast<bf16x8*>(&A_lds[srow * 264 + scol]) = ph;
        *reinterpret_cast<bf16x8*>(&A_lds[srow * 264 + 128 + scol]) = pm;
        __syncthreads();
        int mn = m0 + stride;
        if (mn < n) {
            int gr = min(mn + srow, n - 1);
            ph = ldb8(ABin + (size_t)gr * 128 + scol);
            pm = ldb8(mt + (size_t)gr * 128 + scol);
        }
        f32x4 aR[2] = {{0,0,0,0},{0,0,0,0}};
        f32x4 aZ[2] = {{0,0,0,0},{0,0,0,0}};
        #pragma unroll
        for (int kk = 0; kk < 8; ++kk) {
            bf16x8 f0 = *reinterpret_cast<const bf16x8*>(&A_lds[c0 * 264 + kk * 32 + kg]);
            bf16x8 f1 = *reinterpret_cast<const bf16x8*>(&A_lds[(16 + c0) * 264 + kk * 32 + kg]);
            aR[0] = __builtin_amdgcn_mfma_f32_16x16x32_bf16(f0, Brz[0][kk], aR[0], 0, 0, 0);
            aZ[0] = __builtin_amdgcn_mfma_f32_16x16x32_bf16(f0, Brz[1][kk], aZ[0], 0, 0, 0);
            aR[1] = __builtin_amdgcn_mfma_f32_16x16x32_bf16(f1, Brz[0][kk], aR[1], 0, 0, 0);
            aZ[1] = __builtin_amdgcn_mfma_f32_16x16x32_bf16(f1, Brz[1][kk], aZ[1], 0, 0, 0);
        }
        f32x4 an[2] = {{0,0,0,0},{0,0,0,0}};
        f32x4 au[2] = {{0,0,0,0},{0,0,0,0}};
        #pragma unroll
        for (int kk = 0; kk < 4; ++kk) {
            bf16x8 am0 = *reinterpret_cast<const bf16x8*>(&A_lds[c0 * 264 + 128 + kk * 32 + kg]);
            bf16x8 ah0 = *reinterpret_cast<const bf16x8*>(&A_lds[c0 * 264 + kk * 32 + kg]);
            bf16x8 am1 = *reinterpret_cast<const bf16x8*>(&A_lds[(16 + c0) * 264 + 128 + kk * 32 + kg]);
            bf16x8 ah1 = *reinterpret_cast<const bf16x8*>(&A_lds[(16 + c0) * 264 + kk * 32 + kg]);
            an[0] = __builtin_amdgcn_mfma_f32_16x16x32_bf16(am0, Bn[kk], an[0], 0, 0, 0);
            au[0] = __builtin_amdgcn_mfma_f32_16x16x32_bf16(ah0, Bu[kk], au[0], 0, 0, 0);
            an[1] = __builtin_amdgcn_mfma_f32_16x16x32_bf16(am1, Bn[kk], an[1], 0, 0, 0);
            au[1] = __builtin_amdgcn_mfma_f32_16x16x32_bf16(ah1, Bu[kk], au[1], 0, 0, 0);
        }
        #pragma unroll
        for (int m = 0; m < 2; ++m)
            #pragma unroll
            for (int j = 0; j < 4; ++j) {
                int row = m * 16 + rj + j;
                int grow = m0 + row;
                if (grow < n) {
                    float r  = sigm(aR[m][j] + brzR);
                    float zt = sigm(aZ[m][j] + brzZ);
                    float hold = b2f(A_lds[row * 264 + colw]);
                    float nn = ftanh(an[m][j] + biN + r * (au[m][j] + bhN));
                    float hn = (1.f - zt) * nn + zt * hold;
                    ABout[(size_t)grow * 128 + colw] = f2b(hn);
                    if (WRITEH) Hf[(size_t)grow * 128 + colw] = hn;
                }
            }
        __syncthreads();
    }
}

// ---------------- fused Set2Set step: LSTM cell + online-softmax attention pool ----------------
__global__ __launch_bounds__(512) void k_s2s(const ushort* __restrict__ AB,
                                             const float* __restrict__ Wt,
                                             const float* __restrict__ bl,
                                             const int* __restrict__ gstart,
                                             const float* __restrict__ qstar,
                                             float* __restrict__ hl,
                                             float* __restrict__ cl,
                                             float* __restrict__ qout) {
    int g = blockIdx.x, tid = threadIdx.x, lane = tid & 63, wave = tid >> 6;
    __shared__ float qh[384];
    __shared__ float gbuf[512];
    __shared__ float q[128];
    __shared__ float wm[8];
    __shared__ float sw[8];
    __shared__ float rv[8][128];
    if (tid < 256) qh[tid] = qstar[(size_t)g * 256 + tid];
    else if (tid < 384) qh[tid] = hl[(size_t)g * 128 + (tid - 256)];
    __syncthreads();
    float acc = bl[tid];
    #pragma unroll 8
    for (int k = 0; k < 384; ++k)
        acc += Wt[(size_t)k * 512 + tid] * qh[k];
    gbuf[tid] = acc;
    __syncthreads();
    if (tid < 128) {
        float iv = sigm(gbuf[tid]);
        float fv = sigm(gbuf[128 + tid]);
        float gv = ftanh(gbuf[256 + tid]);
        float ov = sigm(gbuf[384 + tid]);
        float cn = fv * cl[(size_t)g * 128 + tid] + iv * gv;
        cl[(size_t)g * 128 + tid] = cn;
        float hn = ov * ftanh(cn);
        hl[(size_t)g * 128 + tid] = hn;
        q[tid] = hn;
    }
    __syncthreads();
    int s = gstart[g], e = gstart[g + 1];
    float q0 = q[2 * lane], q1 = q[2 * lane + 1];
    float mx = -1e30f, sumw = 0.f, a0 = 0.f, a1 = 0.f;
    for (int node = s + wave; node < e; node += 8) {
        unsigned u = ((const unsigned*)AB)[(size_t)node * 64 + lane];
        float v0 = b2f(u & 0xffff), v1 = b2f(u >> 16);
        float p = v0 * q0 + v1 * q1;
        #pragma unroll
        for (int off = 1; off < 64; off <<= 1) p += __shfl_xor(p, off);
        float nm = fmaxf(mx, p);
        float corr = __expf(mx - nm);
        float wgt = __expf(p - nm);
        sumw = sumw * corr + wgt;
        a0 = a0 * corr + wgt * v0;
        a1 = a1 * corr + wgt * v1;
        mx = nm;
    }
    if (lane == 0) wm[wave] = mx;
    __syncthreads();
    float gm = fmaxf(fmaxf(fmaxf(wm[0], wm[1]), fmaxf(wm[2], wm[3])),
                     fmaxf(fmaxf(wm[4], wm[5]), fmaxf(wm[6], wm[7])));
    float cw = __expf(mx - gm);
    rv[wave][2 * lane] = a0 * cw;
    rv[wave][2 * lane + 1] = a1 * cw;
    if (lane == 0) sw[wave] = sumw * cw;
    __syncthreads();
    if (tid < 128) {
        float r = 0.f, d = 1e-16f;
        #pragma unroll
        for (int wv = 0; wv < 8; ++wv) r += rv[wv][tid];
        #pragma unroll
        for (int wv = 0; wv < 8; ++wv) d += sw[wv];
        qout[(size_t)g * 256 + tid] = q[tid];
        qout[(size_t)g * 256 + 128 + tid] = r / d;
    }
}

// ---------------- launch ----------------
extern "C" void kernel_launch(void* const* d_in, const int* in_sizes, int n_in,
                              void* d_out, int out_size, void* d_ws, size_t ws_size,
                              hipStream_t stream) {
    const float* x        = (const float*)d_in[0];
    const int*   ei       = (const int*)d_in[1];
    const int*   batch    = (const int*)d_in[2];
    const float* lin0_W   = (const float*)d_in[3];
    const float* lin0_b   = (const float*)d_in[4];
    const float* gin_W1   = (const float*)d_in[5];
    const float* gin_b1   = (const float*)d_in[6];
    const float* gin_W2   = (const float*)d_in[7];
    const float* gin_b2   = (const float*)d_in[8];
    const float* gru_Wih  = (const float*)d_in[9];
    const float* gru_Whh  = (const float*)d_in[10];
    const float* gru_bih  = (const float*)d_in[11];
    const float* gru_bhh  = (const float*)d_in[12];
    const float* lstm_Wih = (const float*)d_in[13];
    const float* lstm_Whh = (const float*)d_in[14];
    const float* lstm_bih = (const float*)d_in[15];
    const float* lstm_bhh = (const float*)d_in[16];

    float* qstar_out = (float*)d_out;                         // [NG, 256]
    float* h         = (float*)d_out + (size_t)NG * 2 * DIM;  // [NN, 128] fp32 == `out`

    char* w = (char*)d_ws;
    ushort* AB0   = (ushort*)w; w += (size_t)NN * 128 * 2;   // ping (h only)
    ushort* AB1   = (ushort*)w; w += (size_t)NN * 128 * 2;   // pong (h only)
    ushort* zt    = (ushort*)w; w += (size_t)NN * 128 * 2;   // aggr out
    ushort* mt    = (ushort*)w; w += (size_t)NN * 128 * 2;   // GIN MLP out
    ushort* wlin0 = (ushort*)w; w += 16384 * 2;
    ushort* wg1   = (ushort*)w; w += 16384 * 2;
    ushort* wg2   = (ushort*)w; w += 16384 * 2;
    ushort* wihb  = (ushort*)w; w += 49152 * 2;
    ushort* whhb  = (ushort*)w; w += 49152 * 2;
    ushort* wrz   = (ushort*)w; w += 65536 * 2;
    float* brz    = (float*)w;  w += 256 * 4;
    float* wltr   = (float*)w;  w += (size_t)512 * 384 * 4;  // LSTM W transposed
    float* bl     = (float*)w;  w += 512 * 4;
    float* qstar  = (float*)w;  w += (size_t)NG * 2 * DIM * 4;  // contiguous with hl, cl
    float* hl     = (float*)w;  w += (size_t)NG * DIM * 4;
    float* cl     = (float*)w;  w += (size_t)NG * DIM * 4;
    int* deg      = (int*)w;    w += (size_t)(NN + 1) * 4;
    int* rowptr   = (int*)w;    w += (size_t)(NN + 1) * 4;
    int* bcur     = (int*)w;    w += 256 * 4;
    int* csr_src  = (int*)w;    w += (size_t)NE * 4;
    int2* pairs   = (int2*)w;   w += (size_t)NE * 8;
    int* gstart   = (int*)w;    w += (size_t)(NG + 1) * 4;
    int* part     = (int*)w;    w += (size_t)NN * 4;
    int* blksum   = (int*)w;    w += (size_t)(NBLK + 1) * 4;
    int* blkoff   = (int*)w;    w += (size_t)(NBLK + 1) * 4;

    const int* src = ei;
    const int* dst = ei + NE;

    // one mega-prep
    k_prep<<<(PREP_TOTAL + 255) / 256, 256, 0, stream>>>(
        lin0_W, gin_W1, gin_W2, gru_Wih, gru_Whh, gru_bih, gru_bhh,
        lstm_Wih, lstm_Whh, lstm_bih, lstm_bhh, batch,
        wlin0, wg1, wg2, wihb, whhb, wrz, brz, wltr, bl, deg, gstart, qstar);

    // CSR build
    k_count<<<(NE + 255) / 256, 256, 0, stream>>>(dst, deg, NE);
    k_scan_blk<<<NBLK, 256, 0, stream>>>(deg, part, blksum);
    k_scan_top<<<1, 256, 0, stream>>>(blksum, blkoff);
    k_scan_add<<<NBLK, 256, 0, stream>>>(part, blkoff, rowptr, bcur);
    k_bucket<<<(NE + 4095) / 4096, 256, 0, stream>>>(src, dst, bcur, pairs, NE);
    k_fillbkt<<<NBLK, 256, 0, stream>>>(pairs, rowptr, csr_src);

    // lin0 -> AB0
    k_lin0<<<782, 256, 0, stream>>>(x, wlin0, lin0_b, AB0, NN);

    // 3 GC layers, ping-pong AB buffers
    for (int t = 0; t < 3; ++t) {
        ushort* ABc = (t & 1) ? AB1 : AB0;
        ushort* ABn = (t & 1) ? AB0 : AB1;
        k_aggr8<<<(NN + 7) / 8, 256, 0, stream>>>(ABc, rowptr, csr_src, zt);
        k_ginmlp3<<<1024, 512, 0, stream>>>(zt, wg1, gin_b1, wg2, gin_b2, mt, NN);
        if (t < 2)
            k_gru3b<false><<<512, 512, 0, stream>>>(ABc, mt, wrz, brz,
                                                    wihb + 256 * 128, whhb + 256 * 128,
                                                    gru_bih + 256, gru_bhh + 256, h, ABn, NN);
        else
            k_gru3b<true><<<512, 512, 0, stream>>>(ABc, mt, wrz, brz,
                                                   wihb + 256 * 128, whhb + 256 * 128,
                                                   gru_bih + 256, gru_bhh + 256, h, ABn, NN);
    }
    // final bf16 h lives in AB1 (t=2 wrote ABn=AB1)
    const ushort* ABfin = AB1;

    // Set2Set (fused LSTM + attention per step)
    for (int st = 0; st < 3; ++st)
        k_s2s<<<NG, 512, 0, stream>>>(ABfin, wltr, bl, gstart, qstar, hl, cl,
                                      (st == 2) ? qstar_out : qstar);
}

// Round 18
// 398.674 us; speedup vs baseline: 1.1746x; 1.0232x over previous
//
#include <hip/hip_runtime.h>
#include <hip/hip_bf16.h>
#include <math.h>

static constexpr int NN  = 50000;   // nodes
static constexpr int NE  = 800000;  // edges
static constexpr int DIM = 128;
static constexpr int NG  = 512;     // graphs
static constexpr int NBLK = (NN + 255) / 256;  // 196 scan blocks / buckets

typedef __attribute__((ext_vector_type(8))) short bf16x8;
typedef __attribute__((ext_vector_type(4))) float f32x4;
typedef __attribute__((ext_vector_type(8))) float f32x8;

__device__ __forceinline__ float sigm(float x) {
    return __builtin_amdgcn_rcpf(1.0f + __expf(-x));
}
__device__ __forceinline__ float ftanh(float x) {
    x = fminf(fmaxf(x, -15.f), 15.f);
    float t = __expf(2.f * x);
    return (t - 1.f) * __builtin_amdgcn_rcpf(t + 1.f);
}
__device__ __forceinline__ float b2f(ushort u) { return __uint_as_float(((unsigned)u) << 16); }
__device__ __forceinline__ ushort f2b(float f) {
    __hip_bfloat16 h = __float2bfloat16(f);
    return *reinterpret_cast<ushort*>(&h);
}
__device__ __forceinline__ bf16x8 ldb8(const ushort* p) {
    return *reinterpret_cast<const bf16x8*>(p);
}
__device__ __forceinline__ f32x8 acc8(f32x8 a, uint4 v) {
    a[0] += b2f(v.x & 0xffff); a[1] += b2f(v.x >> 16);
    a[2] += b2f(v.y & 0xffff); a[3] += b2f(v.y >> 16);
    a[4] += b2f(v.z & 0xffff); a[5] += b2f(v.z >> 16);
    a[6] += b2f(v.w & 0xffff); a[7] += b2f(v.w >> 16);
    return a;
}

// ---------------- mega-prep: all weight conversions + init in one kernel ----------------
__global__ __launch_bounds__(256) void k_prep(const float* __restrict__ lin0_W,
                                              const float* __restrict__ gin_W1,
                                              const float* __restrict__ gin_W2,
                                              const float* __restrict__ gru_Wih,
                                              const float* __restrict__ gru_Whh,
                                              const float* __restrict__ gru_bih,
                                              const float* __restrict__ gru_bhh,
                                              const float* __restrict__ lstm_Wih,
                                              const float* __restrict__ lstm_Whh,
                                              const float* __restrict__ lstm_bih,
                                              const float* __restrict__ lstm_bhh,
                                              const int* __restrict__ batch,
                                              ushort* __restrict__ wlin0,
                                              ushort* __restrict__ wg1,
                                              ushort* __restrict__ wg2,
                                              ushort* __restrict__ wihb,
                                              ushort* __restrict__ whhb,
                                              ushort* __restrict__ wrz,
                                              float* __restrict__ brz,
                                              float* __restrict__ wltr,
                                              float* __restrict__ bl,
                                              int* __restrict__ deg,
                                              int* __restrict__ gstart,
                                              float* __restrict__ zf) {
    const int S0 = 16384, S1 = S0 + 16384, S2 = S1 + 16384;
    const int S3 = S2 + 49152, S4 = S3 + 49152, S5 = S4 + 65536;
    const int S6 = S5 + 256, S7 = S6 + 196608, S8 = S7 + 512;
    const int S9 = S8 + (NN + 1), S10 = S9 + (NG + 1), S11 = S10 + 262144;
    int i = blockIdx.x * 256 + threadIdx.x;
    if (i < S0) { wlin0[i] = f2b(lin0_W[i]); }
    else if (i < S1) { int j = i - S0; wg1[j] = f2b(gin_W1[j]); }
    else if (i < S2) { int j = i - S1; wg2[j] = f2b(gin_W2[j]); }
    else if (i < S3) { int j = i - S2; wihb[j] = f2b(gru_Wih[j]); }
    else if (i < S4) { int j = i - S3; whhb[j] = f2b(gru_Whh[j]); }
    else if (i < S5) {
        int j = i - S4; int col = j >> 8, k = j & 255;
        int row = (col >> 7) * 128 + (col & 127);
        wrz[j] = f2b((k < 128) ? gru_Whh[row * 128 + k] : gru_Wih[row * 128 + (k - 128)]);
    }
    else if (i < S6) { int j = i - S5; brz[j] = gru_bih[j] + gru_bhh[j]; }
    else if (i < S7) {
        int j = i - S6; int k = j / 512, col = j % 512;
        wltr[j] = (k < 256) ? lstm_Wih[(size_t)col * 256 + k]
                            : lstm_Whh[(size_t)col * 128 + (k - 256)];
    }
    else if (i < S8) { int j = i - S7; bl[j] = lstm_bih[j] + lstm_bhh[j]; }
    else if (i < S9) { deg[i - S8] = 0; }
    else if (i < S10) {
        int g = i - S9;
        int lo = 0, hi = NN;
        while (lo < hi) { int mid = (lo + hi) >> 1; if (batch[mid] < g) lo = mid + 1; else hi = mid; }
        gstart[g] = lo;
    }
    else if (i < S11) { zf[i - S10] = 0.f; }
}
static constexpr int PREP_TOTAL = 16384 * 3 + 49152 * 2 + 65536 + 256 + 196608 + 512 + (NN + 1) + (NG + 1) + 262144;

__global__ void k_count(const int* __restrict__ dst, int* __restrict__ deg, int e) {
    int i = blockIdx.x * blockDim.x + threadIdx.x;
    if (i < e) atomicAdd(&deg[dst[i]], 1);
}

// ---------------- parallel 3-phase exclusive scan of deg -> rowptr (+ bucket cursors) ----------------
__global__ __launch_bounds__(256) void k_scan_blk(const int* __restrict__ deg,
                                                  int* __restrict__ part,
                                                  int* __restrict__ blksum) {
    __shared__ int s[256];
    int b = blockIdx.x, t = threadIdx.x;
    int i = b * 256 + t;
    int v = (i < NN) ? deg[i] : 0;
    s[t] = v;
    __syncthreads();
    #pragma unroll
    for (int off = 1; off < 256; off <<= 1) {
        int x = (t >= off) ? s[t - off] : 0;
        __syncthreads();
        s[t] += x;
        __syncthreads();
    }
    if (i < NN) part[i] = s[t] - v;
    if (t == 255) blksum[b] = s[255];
}
__global__ __launch_bounds__(256) void k_scan_top(const int* __restrict__ blksum,
                                                  int* __restrict__ blkoff) {
    __shared__ int s[256];
    int t = threadIdx.x;
    int v = (t < NBLK) ? blksum[t] : 0;
    s[t] = v;
    __syncthreads();
    #pragma unroll
    for (int off = 1; off < 256; off <<= 1) {
        int x = (t >= off) ? s[t - off] : 0;
        __syncthreads();
        s[t] += x;
        __syncthreads();
    }
    if (t < NBLK) blkoff[t] = s[t] - v;
    if (t == NBLK - 1) blkoff[NBLK] = s[t];
}
__global__ __launch_bounds__(256) void k_scan_add(const int* __restrict__ part,
                                                  const int* __restrict__ blkoff,
                                                  int* __restrict__ rowptr,
                                                  int* __restrict__ bcur) {
    int b = blockIdx.x, t = threadIdx.x;
    int i = b * 256 + t;
    if (i < NN) {
        int r = part[i] + blkoff[b];
        rowptr[i] = r;
        if ((i & 255) == 0) bcur[i >> 8] = r;
    }
    if (b == 0 && t == 0) rowptr[NN] = blkoff[NBLK];
}

// ---------------- bucketed CSR fill ----------------
__global__ __launch_bounds__(256) void k_bucket(const int* __restrict__ src,
                                                const int* __restrict__ dst,
                                                int* __restrict__ bcur,
                                                int2* __restrict__ pairs, int e) {
    __shared__ int lcnt[256];
    __shared__ int lbase[256];
    int tid = threadIdx.x;
    lcnt[tid] = 0;
    __syncthreads();
    int base = blockIdx.x * 4096;
    #pragma unroll
    for (int k = 0; k < 16; ++k) {
        int e0 = base + k * 256 + tid;
        if (e0 < e) atomicAdd(&lcnt[dst[e0] >> 8], 1);
    }
    __syncthreads();
    int cnt = lcnt[tid];
    if (cnt > 0) lbase[tid] = atomicAdd(&bcur[tid], cnt);
    __syncthreads();
    lcnt[tid] = 0;
    __syncthreads();
    #pragma unroll
    for (int k = 0; k < 16; ++k) {
        int e0 = base + k * 256 + tid;
        if (e0 < e) {
            int d = dst[e0];
            int b = d >> 8;
            int off = atomicAdd(&lcnt[b], 1);
            pairs[lbase[b] + off] = make_int2(src[e0], d);
        }
    }
}
__global__ __launch_bounds__(256) void k_fillbkt(const int2* __restrict__ pairs,
                                                 const int* __restrict__ rowptr,
                                                 int* __restrict__ csr) {
    __shared__ int lcur[256];
    int b = blockIdx.x, tid = threadIdx.x;
    int w0 = b << 8;
    int w1 = min(w0 + 256, NN);
    if (w0 + tid < w1) lcur[tid] = rowptr[w0 + tid];
    __syncthreads();
    int r0 = rowptr[w0], r1 = rowptr[w1];
    for (int i = r0 + tid; i < r1; i += 256) {
        int2 p = pairs[i];
        int pos = atomicAdd(&lcur[p.y - w0], 1);
        csr[pos] = p.x;
    }
}

// lin0: h = relu(x @ W^T + b), fp32 A; writes AB [NN,128] bf16
__global__ __launch_bounds__(256) void k_lin0(const float* __restrict__ X,
                                              const ushort* __restrict__ W,
                                              const float* __restrict__ bias,
                                              ushort* __restrict__ AB, int n) {
    int lane = threadIdx.x & 63, wave = threadIdx.x >> 6;
    int c0 = lane & 15, kg = (lane >> 4) * 8;
    int tb0 = wave * 32;
    bf16x8 B[2][4];
    #pragma unroll
    for (int t = 0; t < 2; ++t)
        #pragma unroll
        for (int kk = 0; kk < 4; ++kk)
            B[t][kk] = ldb8(W + (size_t)(tb0 + t * 16 + c0) * 128 + kk * 32 + kg);

    for (int m0 = blockIdx.x * 64; m0 < n; m0 += gridDim.x * 64) {
        f32x4 acc[4][2];
        #pragma unroll
        for (int m = 0; m < 4; ++m) { acc[m][0] = {0,0,0,0}; acc[m][1] = {0,0,0,0}; }
        #pragma unroll
        for (int kk = 0; kk < 4; ++kk) {
            #pragma unroll
            for (int m = 0; m < 4; ++m) {
                int ar = min(m0 + m * 16 + c0, n - 1);
                const float* a = X + (size_t)ar * 128 + kk * 32 + kg;
                float4 x0 = *reinterpret_cast<const float4*>(a);
                float4 x1 = *reinterpret_cast<const float4*>(a + 4);
                bf16x8 af;
                af[0] = (short)f2b(x0.x); af[1] = (short)f2b(x0.y);
                af[2] = (short)f2b(x0.z); af[3] = (short)f2b(x0.w);
                af[4] = (short)f2b(x1.x); af[5] = (short)f2b(x1.y);
                af[6] = (short)f2b(x1.z); af[7] = (short)f2b(x1.w);
                acc[m][0] = __builtin_amdgcn_mfma_f32_16x16x32_bf16(af, B[0][kk], acc[m][0], 0, 0, 0);
                acc[m][1] = __builtin_amdgcn_mfma_f32_16x16x32_bf16(af, B[1][kk], acc[m][1], 0, 0, 0);
            }
        }
        #pragma unroll
        for (int m = 0; m < 4; ++m) {
            int rbase = m0 + m * 16 + ((lane >> 4) << 2);
            #pragma unroll
            for (int t = 0; t < 2; ++t) {
                int col = tb0 + t * 16 + c0;
                float bv = bias[col];
                #pragma unroll
                for (int j = 0; j < 4; ++j) {
                    int row = rbase + j;
                    if (row < n) {
                        float v = fmaxf(acc[m][t][j] + bv, 0.f);
                        AB[(size_t)row * 128 + col] = f2b(v);
                    }
                }
            }
        }
    }
}

// ---------------- fused aggregation + GIN MLP ----------------
// Gather z = h_self + sum h[nbr] directly into the LDS tile, then two MFMA phases.
__global__ __launch_bounds__(512) void k_aggmlp(const ushort* __restrict__ AB,
                                                const int* __restrict__ rowptr,
                                                const int* __restrict__ csr,
                                                const ushort* __restrict__ W1,
                                                const float* __restrict__ b1,
                                                const ushort* __restrict__ W2,
                                                const float* __restrict__ b2,
                                                ushort* __restrict__ mt, int n) {
    __shared__ ushort Z_lds[32 * 136];
    __shared__ ushort M_lds[32 * 136];
    int tid = threadIdx.x;
    int lane = tid & 63, wave = tid >> 6;
    int c0 = lane & 15, kg = (lane >> 4) * 8;
    int colw = wave * 16 + c0;
    int rj = (lane >> 4) << 2;
    int grow_r = tid >> 4;            // gather row 0..31 (16 threads/row)
    int segi = tid & 15;              // 16B segment within row
    const int stride = gridDim.x * 32;

    bf16x8 B1[4], B2[4];
    #pragma unroll
    for (int kk = 0; kk < 4; ++kk) {
        B1[kk] = ldb8(W1 + (size_t)colw * 128 + kk * 32 + kg);
        B2[kk] = ldb8(W2 + (size_t)colw * 128 + kk * 32 + kg);
    }
    float bv1 = b1[colw], bv2 = b2[colw];
    const uint4* bp = (const uint4*)AB;   // 16 uint4 per row

    for (int m0 = blockIdx.x * 32; m0 < n; m0 += stride) {
        // gather this tile's z rows (registers -> LDS)
        f32x8 A0 = {0,0,0,0,0,0,0,0};
        int grow = m0 + grow_r;
        if (grow < n) {
            f32x8 A1 = {0,0,0,0,0,0,0,0}, A2 = {0,0,0,0,0,0,0,0}, A3 = {0,0,0,0,0,0,0,0};
            A0 = acc8(A0, bp[(size_t)grow * 16 + segi]);
            int p = rowptr[grow], p1 = rowptr[grow + 1];
            for (; p + 4 <= p1; p += 4) {
                uint4 v0 = bp[(size_t)csr[p + 0] * 16 + segi];
                uint4 v1 = bp[(size_t)csr[p + 1] * 16 + segi];
                uint4 v2 = bp[(size_t)csr[p + 2] * 16 + segi];
                uint4 v3 = bp[(size_t)csr[p + 3] * 16 + segi];
                A0 = acc8(A0, v0); A1 = acc8(A1, v1);
                A2 = acc8(A2, v2); A3 = acc8(A3, v3);
            }
            for (; p < p1; ++p) A0 = acc8(A0, bp[(size_t)csr[p] * 16 + segi]);
            #pragma unroll
            for (int i = 0; i < 8; ++i) A0[i] += A1[i] + A2[i] + A3[i];
        }
        bf16x8 zz;
        #pragma unroll
        for (int i = 0; i < 8; ++i) zz[i] = (short)f2b(A0[i]);
        *reinterpret_cast<bf16x8*>(&Z_lds[grow_r * 136 + segi * 8]) = zz;
        __syncthreads();
        // ph1: m1 = relu(z @ W1^T + b1) -> M_lds
        {
            f32x4 a[2] = {{0,0,0,0},{0,0,0,0}};
            #pragma unroll
            for (int kk = 0; kk < 4; ++kk) {
                bf16x8 f0 = *reinterpret_cast<const bf16x8*>(&Z_lds[c0 * 136 + kk * 32 + kg]);
                bf16x8 f1 = *reinterpret_cast<const bf16x8*>(&Z_lds[(16 + c0) * 136 + kk * 32 + kg]);
                a[0] = __builtin_amdgcn_mfma_f32_16x16x32_bf16(f0, B1[kk], a[0], 0, 0, 0);
                a[1] = __builtin_amdgcn_mfma_f32_16x16x32_bf16(f1, B1[kk], a[1], 0, 0, 0);
            }
            #pragma unroll
            for (int m = 0; m < 2; ++m)
                #pragma unroll
                for (int j = 0; j < 4; ++j)
                    M_lds[(m * 16 + rj + j) * 136 + colw] = f2b(fmaxf(a[m][j] + bv1, 0.f));
        }
        __syncthreads();
        // ph2: m = relu(m1 @ W2^T + b2) -> mt
        {
            f32x4 a[2] = {{0,0,0,0},{0,0,0,0}};
            #pragma unroll
            for (int kk = 0; kk < 4; ++kk) {
                bf16x8 f0 = *reinterpret_cast<const bf16x8*>(&M_lds[c0 * 136 + kk * 32 + kg]);
                bf16x8 f1 = *reinterpret_cast<const bf16x8*>(&M_lds[(16 + c0) * 136 + kk * 32 + kg]);
                a[0] = __builtin_amdgcn_mfma_f32_16x16x32_bf16(f0, B2[kk], a[0], 0, 0, 0);
                a[1] = __builtin_amdgcn_mfma_f32_16x16x32_bf16(f1, B2[kk], a[1], 0, 0, 0);
            }
            #pragma unroll
            for (int m = 0; m < 2; ++m)
                #pragma unroll
                for (int j = 0; j < 4; ++j) {
                    int gr2 = m0 + m * 16 + rj + j;
                    if (gr2 < n)
                        mt[(size_t)gr2 * 128 + colw] = f2b(fmaxf(a[m][j] + bv2, 0.f));
                }
        }
        __syncthreads();
    }
}

// ---------------- GRU: rz + ngate fully in-register per wave (no rz_lds, 2 barriers/tile) ----------------
template<bool WRITEH>
__global__ __launch_bounds__(512) void k_gru3b(const ushort* __restrict__ ABin,
                                               const ushort* __restrict__ mt,
                                               const ushort* __restrict__ wrz,
                                               const float* __restrict__ brz,
                                               const ushort* __restrict__ Wn,
                                               const ushort* __restrict__ Un,
                                               const float* __restrict__ bin,
                                               const float* __restrict__ bhn,
                                               float* __restrict__ Hf,
                                               ushort* __restrict__ ABout, int n) {
    __shared__ ushort A_lds[32 * 264];   // [h | m]
    int tid = threadIdx.x;
    int lane = tid & 63, wave = tid >> 6;
    int c0 = lane & 15, kg = (lane >> 4) * 8;
    int colw = wave * 16 + c0;
    int rj = (lane >> 4) << 2;
    int srow = tid >> 4, scol = (tid & 15) * 8;
    const int stride = gridDim.x * 32;

    bf16x8 Brz[2][8];
    #pragma unroll
    for (int kk = 0; kk < 8; ++kk) {
        Brz[0][kk] = ldb8(wrz + (size_t)(colw) * 256 + kk * 32 + kg);
        Brz[1][kk] = ldb8(wrz + (size_t)(128 + colw) * 256 + kk * 32 + kg);
    }
    bf16x8 Bn[4], Bu[4];
    #pragma unroll
    for (int kk = 0; kk < 4; ++kk) {
        Bn[kk] = ldb8(Wn + (size_t)colw * 128 + kk * 32 + kg);
        Bu[kk] = ldb8(Un + (size_t)colw * 128 + kk * 32 + kg);
    }
    float biN = bin[colw], bhN = bhn[colw];
    float brzR = brz[colw], brzZ = brz[128 + colw];

    int m0 = blockIdx.x * 32;
    bf16x8 ph, pm;
    if (m0 < n) {
        int gr = min(m0 + srow, n - 1);
        ph = ldb8(ABin + (size_t)gr * 128 + scol);
        pm = ldb8(mt + (size_t)gr * 128 + scol);
    }
    for (; m0 < n; m0 += stride) {
        *reinterpret_cast<bf16x8*>(&A_lds[srow * 264 + scol]) = ph;
        *reinterpret_cast<bf16x8*>(&A_lds[srow * 264 + 128 + scol]) = pm;
        __syncthreads();
        int mn = m0 + stride;
        if (mn < n) {
            int gr = min(mn + srow, n - 1);
            ph = ldb8(ABin + (size_t)gr * 128 + scol);
            pm = ldb8(mt + (size_t)gr * 128 + scol);
        }
        f32x4 aR[2] = {{0,0,0,0},{0,0,0,0}};
        f32x4 aZ[2] = {{0,0,0,0},{0,0,0,0}};
        #pragma unroll
        for (int kk = 0; kk < 8; ++kk) {
            bf16x8 f0 = *reinterpret_cast<const bf16x8*>(&A_lds[c0 * 264 + kk * 32 + kg]);
            bf16x8 f1 = *reinterpret_cast<const bf16x8*>(&A_lds[(16 + c0) * 264 + kk * 32 + kg]);
            aR[0] = __builtin_amdgcn_mfma_f32_16x16x32_bf16(f0, Brz[0][kk], aR[0], 0, 0, 0);
            aZ[0] = __builtin_amdgcn_mfma_f32_16x16x32_bf16(f0, Brz[1][kk], aZ[0], 0, 0, 0);
            aR[1] = __builtin_amdgcn_mfma_f32_16x16x32_bf16(f1, Brz[0][kk], aR[1], 0, 0, 0);
            aZ[1] = __builtin_amdgcn_mfma_f32_16x16x32_bf16(f1, Brz[1][kk], aZ[1], 0, 0, 0);
        }
        f32x4 an[2] = {{0,0,0,0},{0,0,0,0}};
        f32x4 au[2] = {{0,0,0,0},{0,0,0,0}};
        #pragma unroll
        for (int kk = 0; kk < 4; ++kk) {
            bf16x8 am0 = *reinterpret_cast<const bf16x8*>(&A_lds[c0 * 264 + 128 + kk * 32 + kg]);
            bf16x8 ah0 = *reinterpret_cast<const bf16x8*>(&A_lds[c0 * 264 + kk * 32 + kg]);
            bf16x8 am1 = *reinterpret_cast<const bf16x8*>(&A_lds[(16 + c0) * 264 + 128 + kk * 32 + kg]);
            bf16x8 ah1 = *reinterpret_cast<const bf16x8*>(&A_lds[(16 + c0) * 264 + kk * 32 + kg]);
            an[0] = __builtin_amdgcn_mfma_f32_16x16x32_bf16(am0, Bn[kk], an[0], 0, 0, 0);
            au[0] = __builtin_amdgcn_mfma_f32_16x16x32_bf16(ah0, Bu[kk], au[0], 0, 0, 0);
            an[1] = __builtin_amdgcn_mfma_f32_16x16x32_bf16(am1, Bn[kk], an[1], 0, 0, 0);
            au[1] = __builtin_amdgcn_mfma_f32_16x16x32_bf16(ah1, Bu[kk], au[1], 0, 0, 0);
        }
        #pragma unroll
        for (int m = 0; m < 2; ++m)
            #pragma unroll
            for (int j = 0; j < 4; ++j) {
                int row = m * 16 + rj + j;
                int grow = m0 + row;
                if (grow < n) {
                    float r  = sigm(aR[m][j] + brzR);
                    float zt = sigm(aZ[m][j] + brzZ);
                    float hold = b2f(A_lds[row * 264 + colw]);
                    float nn = ftanh(an[m][j] + biN + r * (au[m][j] + bhN));
                    float hn = (1.f - zt) * nn + zt * hold;
                    ABout[(size_t)grow * 128 + colw] = f2b(hn);
                    if (WRITEH) Hf[(size_t)grow * 128 + colw] = hn;
                }
            }
        __syncthreads();
    }
}

// ---------------- fused Set2Set step: LSTM cell + online-softmax attention pool ----------------
__global__ __launch_bounds__(512) void k_s2s(const ushort* __restrict__ AB,
                                             const float* __restrict__ Wt,
                                             const float* __restrict__ bl,
                                             const int* __restrict__ gstart,
                                             const float* __restrict__ qstar,
                                             float* __restrict__ hl,
                                             float* __restrict__ cl,
                                             float* __restrict__ qout) {
    int g = blockIdx.x, tid = threadIdx.x, lane = tid & 63, wave = tid >> 6;
    __shared__ float qh[384];
    __shared__ float gbuf[512];
    __shared__ float q[128];
    __shared__ float wm[8];
    __shared__ float sw[8];
    __shared__ float rv[8][128];
    if (tid < 256) qh[tid] = qstar[(size_t)g * 256 + tid];
    else if (tid < 384) qh[tid] = hl[(size_t)g * 128 + (tid - 256)];
    __syncthreads();
    float acc = bl[tid];
    #pragma unroll 8
    for (int k = 0; k < 384; ++k)
        acc += Wt[(size_t)k * 512 + tid] * qh[k];
    gbuf[tid] = acc;
    __syncthreads();
    if (tid < 128) {
        float iv = sigm(gbuf[tid]);
        float fv = sigm(gbuf[128 + tid]);
        float gv = ftanh(gbuf[256 + tid]);
        float ov = sigm(gbuf[384 + tid]);
        float cn = fv * cl[(size_t)g * 128 + tid] + iv * gv;
        cl[(size_t)g * 128 + tid] = cn;
        float hn = ov * ftanh(cn);
        hl[(size_t)g * 128 + tid] = hn;
        q[tid] = hn;
    }
    __syncthreads();
    int s = gstart[g], e = gstart[g + 1];
    float q0 = q[2 * lane], q1 = q[2 * lane + 1];
    float mx = -1e30f, sumw = 0.f, a0 = 0.f, a1 = 0.f;
    for (int node = s + wave; node < e; node += 8) {
        unsigned u = ((const unsigned*)AB)[(size_t)node * 64 + lane];
        float v0 = b2f(u & 0xffff), v1 = b2f(u >> 16);
        float p = v0 * q0 + v1 * q1;
        #pragma unroll
        for (int off = 1; off < 64; off <<= 1) p += __shfl_xor(p, off);
        float nm = fmaxf(mx, p);
        float corr = __expf(mx - nm);
        float wgt = __expf(p - nm);
        sumw = sumw * corr + wgt;
        a0 = a0 * corr + wgt * v0;
        a1 = a1 * corr + wgt * v1;
        mx = nm;
    }
    if (lane == 0) wm[wave] = mx;
    __syncthreads();
    float gm = fmaxf(fmaxf(fmaxf(wm[0], wm[1]), fmaxf(wm[2], wm[3])),
                     fmaxf(fmaxf(wm[4], wm[5]), fmaxf(wm[6], wm[7])));
    float cw = __expf(mx - gm);
    rv[wave][2 * lane] = a0 * cw;
    rv[wave][2 * lane + 1] = a1 * cw;
    if (lane == 0) sw[wave] = sumw * cw;
    __syncthreads();
    if (tid < 128) {
        float r = 0.f, d = 1e-16f;
        #pragma unroll
        for (int wv = 0; wv < 8; ++wv) r += rv[wv][tid];
        #pragma unroll
        for (int wv = 0; wv < 8; ++wv) d += sw[wv];
        qout[(size_t)g * 256 + tid] = q[tid];
        qout[(size_t)g * 256 + 128 + tid] = r / d;
    }
}

// ---------------- launch ----------------
extern "C" void kernel_launch(void* const* d_in, const int* in_sizes, int n_in,
                              void* d_out, int out_size, void* d_ws, size_t ws_size,
                              hipStream_t stream) {
    const float* x        = (const float*)d_in[0];
    const int*   ei       = (const int*)d_in[1];
    const int*   batch    = (const int*)d_in[2];
    const float* lin0_W   = (const float*)d_in[3];
    const float* lin0_b   = (const float*)d_in[4];
    const float* gin_W1   = (const float*)d_in[5];
    const float* gin_b1   = (const float*)d_in[6];
    const float* gin_W2   = (const float*)d_in[7];
    const float* gin_b2   = (const float*)d_in[8];
    const float* gru_Wih  = (const float*)d_in[9];
    const float* gru_Whh  = (const float*)d_in[10];
    const float* gru_bih  = (const float*)d_in[11];
    const float* gru_bhh  = (const float*)d_in[12];
    const float* lstm_Wih = (const float*)d_in[13];
    const float* lstm_Whh = (const float*)d_in[14];
    const float* lstm_bih = (const float*)d_in[15];
    const float* lstm_bhh = (const float*)d_in[16];

    float* qstar_out = (float*)d_out;                         // [NG, 256]
    float* h         = (float*)d_out + (size_t)NG * 2 * DIM;  // [NN, 128] fp32 == `out`

    char* w = (char*)d_ws;
    ushort* AB0   = (ushort*)w; w += (size_t)NN * 128 * 2;   // ping (h only)
    ushort* AB1   = (ushort*)w; w += (size_t)NN * 128 * 2;   // pong (h only)
    ushort* mt    = (ushort*)w; w += (size_t)NN * 128 * 2;   // GIN MLP out
    ushort* wlin0 = (ushort*)w; w += 16384 * 2;
    ushort* wg1   = (ushort*)w; w += 16384 * 2;
    ushort* wg2   = (ushort*)w; w += 16384 * 2;
    ushort* wihb  = (ushort*)w; w += 49152 * 2;
    ushort* whhb  = (ushort*)w; w += 49152 * 2;
    ushort* wrz   = (ushort*)w; w += 65536 * 2;
    float* brz    = (float*)w;  w += 256 * 4;
    float* wltr   = (float*)w;  w += (size_t)512 * 384 * 4;  // LSTM W transposed
    float* bl     = (float*)w;  w += 512 * 4;
    float* qstar  = (float*)w;  w += (size_t)NG * 2 * DIM * 4;  // contiguous with hl, cl
    float* hl     = (float*)w;  w += (size_t)NG * DIM * 4;
    float* cl     = (float*)w;  w += (size_t)NG * DIM * 4;
    int* deg      = (int*)w;    w += (size_t)(NN + 1) * 4;
    int* rowptr   = (int*)w;    w += (size_t)(NN + 1) * 4;
    int* bcur     = (int*)w;    w += 256 * 4;
    int* csr_src  = (int*)w;    w += (size_t)NE * 4;
    int2* pairs   = (int2*)w;   w += (size_t)NE * 8;
    int* gstart   = (int*)w;    w += (size_t)(NG + 1) * 4;
    int* part     = (int*)w;    w += (size_t)NN * 4;
    int* blksum   = (int*)w;    w += (size_t)(NBLK + 1) * 4;
    int* blkoff   = (int*)w;    w += (size_t)(NBLK + 1) * 4;

    const int* src = ei;
    const int* dst = ei + NE;

    // one mega-prep
    k_prep<<<(PREP_TOTAL + 255) / 256, 256, 0, stream>>>(
        lin0_W, gin_W1, gin_W2, gru_Wih, gru_Whh, gru_bih, gru_bhh,
        lstm_Wih, lstm_Whh, lstm_bih, lstm_bhh, batch,
        wlin0, wg1, wg2, wihb, whhb, wrz, brz, wltr, bl, deg, gstart, qstar);

    // CSR build
    k_count<<<(NE + 255) / 256, 256, 0, stream>>>(dst, deg, NE);
    k_scan_blk<<<NBLK, 256, 0, stream>>>(deg, part, blksum);
    k_scan_top<<<1, 256, 0, stream>>>(blksum, blkoff);
    k_scan_add<<<NBLK, 256, 0, stream>>>(part, blkoff, rowptr, bcur);
    k_bucket<<<(NE + 4095) / 4096, 256, 0, stream>>>(src, dst, bcur, pairs, NE);
    k_fillbkt<<<NBLK, 256, 0, stream>>>(pairs, rowptr, csr_src);

    // lin0 -> AB0
    k_lin0<<<782, 256, 0, stream>>>(x, wlin0, lin0_b, AB0, NN);

    // 3 GC layers, ping-pong AB buffers (gather fused into the MLP kernel)
    for (int t = 0; t < 3; ++t) {
        ushort* ABc = (t & 1) ? AB1 : AB0;
        ushort* ABn = (t & 1) ? AB0 : AB1;
        k_aggmlp<<<1024, 512, 0, stream>>>(ABc, rowptr, csr_src,
                                           wg1, gin_b1, wg2, gin_b2, mt, NN);
        if (t < 2)
            k_gru3b<false><<<512, 512, 0, stream>>>(ABc, mt, wrz, brz,
                                                    wihb + 256 * 128, whhb + 256 * 128,
                                                    gru_bih + 256, gru_bhh + 256, h, ABn, NN);
        else
            k_gru3b<true><<<512, 512, 0, stream>>>(ABc, mt, wrz, brz,
                                                   wihb + 256 * 128, whhb + 256 * 128,
                                                   gru_bih + 256, gru_bhh + 256, h, ABn, NN);
    }
    // final bf16 h lives in AB1 (t=2 wrote ABn=AB1)
    const ushort* ABfin = AB1;

    // Set2Set (fused LSTM + attention per step)
    for (int st = 0; st < 3; ++st)
        k_s2s<<<NG, 512, 0, stream>>>(ABfin, wltr, bl, gstart, qstar, hl, cl,
                                      (st == 2) ? qstar_out : qstar);
}

// Round 19
// 361.416 us; speedup vs baseline: 1.2957x; 1.1031x over previous
//
#include <hip/hip_runtime.h>
#include <hip/hip_bf16.h>
#include <math.h>

static constexpr int NN  = 50000;   // nodes
static constexpr int NE  = 800000;  // edges
static constexpr int DIM = 128;
static constexpr int NG  = 512;     // graphs
static constexpr int NBLK = (NN + 255) / 256;  // 196 buckets

typedef __attribute__((ext_vector_type(8))) short bf16x8;
typedef __attribute__((ext_vector_type(4))) float f32x4;
typedef __attribute__((ext_vector_type(8))) float f32x8;

__device__ __forceinline__ float sigm(float x) {
    return __builtin_amdgcn_rcpf(1.0f + __expf(-x));
}
__device__ __forceinline__ float ftanh(float x) {
    x = fminf(fmaxf(x, -15.f), 15.f);
    float t = __expf(2.f * x);
    return (t - 1.f) * __builtin_amdgcn_rcpf(t + 1.f);
}
__device__ __forceinline__ float b2f(ushort u) { return __uint_as_float(((unsigned)u) << 16); }
__device__ __forceinline__ ushort f2b(float f) {
    __hip_bfloat16 h = __float2bfloat16(f);
    return *reinterpret_cast<ushort*>(&h);
}
__device__ __forceinline__ bf16x8 ldb8(const ushort* p) {
    return *reinterpret_cast<const bf16x8*>(p);
}
__device__ __forceinline__ f32x8 acc8(f32x8 a, uint4 v) {
    a[0] += b2f(v.x & 0xffff); a[1] += b2f(v.x >> 16);
    a[2] += b2f(v.y & 0xffff); a[3] += b2f(v.y >> 16);
    a[4] += b2f(v.z & 0xffff); a[5] += b2f(v.z >> 16);
    a[6] += b2f(v.w & 0xffff); a[7] += b2f(v.w >> 16);
    return a;
}

// ---------------- mega-prep: weight conversions + init (no deg anymore) ----------------
__global__ __launch_bounds__(256) void k_prep(const float* __restrict__ lin0_W,
                                              const float* __restrict__ gin_W1,
                                              const float* __restrict__ gin_W2,
                                              const float* __restrict__ gru_Wih,
                                              const float* __restrict__ gru_Whh,
                                              const float* __restrict__ gru_bih,
                                              const float* __restrict__ gru_bhh,
                                              const float* __restrict__ lstm_Wih,
                                              const float* __restrict__ lstm_Whh,
                                              const float* __restrict__ lstm_bih,
                                              const float* __restrict__ lstm_bhh,
                                              const int* __restrict__ batch,
                                              ushort* __restrict__ wlin0,
                                              ushort* __restrict__ wg1,
                                              ushort* __restrict__ wg2,
                                              ushort* __restrict__ wihb,
                                              ushort* __restrict__ whhb,
                                              ushort* __restrict__ wrz,
                                              float* __restrict__ brz,
                                              float* __restrict__ wltr,
                                              float* __restrict__ bl,
                                              int* __restrict__ gstart,
                                              float* __restrict__ zf,
                                              int* __restrict__ bcnt) {
    const int S0 = 16384, S1 = S0 + 16384, S2 = S1 + 16384;
    const int S3 = S2 + 49152, S4 = S3 + 49152, S5 = S4 + 65536;
    const int S6 = S5 + 256, S7 = S6 + 196608, S8 = S7 + 512;
    const int S9 = S8 + (NG + 1), S10 = S9 + 262144, S11 = S10 + 256;
    int i = blockIdx.x * 256 + threadIdx.x;
    if (i < S0) { wlin0[i] = f2b(lin0_W[i]); }
    else if (i < S1) { int j = i - S0; wg1[j] = f2b(gin_W1[j]); }
    else if (i < S2) { int j = i - S1; wg2[j] = f2b(gin_W2[j]); }
    else if (i < S3) { int j = i - S2; wihb[j] = f2b(gru_Wih[j]); }
    else if (i < S4) { int j = i - S3; whhb[j] = f2b(gru_Whh[j]); }
    else if (i < S5) {
        int j = i - S4; int col = j >> 8, k = j & 255;
        int row = (col >> 7) * 128 + (col & 127);
        wrz[j] = f2b((k < 128) ? gru_Whh[row * 128 + k] : gru_Wih[row * 128 + (k - 128)]);
    }
    else if (i < S6) { int j = i - S5; brz[j] = gru_bih[j] + gru_bhh[j]; }
    else if (i < S7) {
        int j = i - S6; int k = j / 512, col = j % 512;
        wltr[j] = (k < 256) ? lstm_Wih[(size_t)col * 256 + k]
                            : lstm_Whh[(size_t)col * 128 + (k - 256)];
    }
    else if (i < S8) { int j = i - S7; bl[j] = lstm_bih[j] + lstm_bhh[j]; }
    else if (i < S9) {
        int g = i - S8;
        int lo = 0, hi = NN;
        while (lo < hi) { int mid = (lo + hi) >> 1; if (batch[mid] < g) lo = mid + 1; else hi = mid; }
        gstart[g] = lo;
    }
    else if (i < S10) { zf[i - S9] = 0.f; }
    else if (i < S11) { bcnt[i - S10] = 0; }
}
static constexpr int PREP_TOTAL = 16384 * 3 + 49152 * 2 + 65536 + 256 + 196608 + 512 + (NG + 1) + 262144 + 256;

// ---------------- bucket counts (LDS histogram; 256x196 global atomics only) ----------------
__global__ __launch_bounds__(256) void k_bcount(const int* __restrict__ dst,
                                                int* __restrict__ bcnt, int e) {
    __shared__ int l[256];
    int tid = threadIdx.x;
    l[tid] = 0;
    __syncthreads();
    int base = blockIdx.x * 4096;
    #pragma unroll
    for (int k = 0; k < 16; ++k) {
        int e0 = base + k * 256 + tid;
        if (e0 < e) atomicAdd(&l[dst[e0] >> 8], 1);
    }
    __syncthreads();
    if (l[tid] > 0) atomicAdd(&bcnt[tid], l[tid]);
}

// exclusive scan of 256 bucket counts -> bbase[0..256], seed bcur
__global__ __launch_bounds__(256) void k_btop(const int* __restrict__ bcnt,
                                              int* __restrict__ bbase,
                                              int* __restrict__ bcur) {
    __shared__ int s[256];
    int t = threadIdx.x;
    int v = bcnt[t];
    s[t] = v;
    __syncthreads();
    #pragma unroll
    for (int off = 1; off < 256; off <<= 1) {
        int x = (t >= off) ? s[t - off] : 0;
        __syncthreads();
        s[t] += x;
        __syncthreads();
    }
    int ex = s[t] - v;
    bbase[t] = ex;
    bcur[t] = ex;
    if (t == 255) bbase[256] = s[255];
}

// ---------------- bucket pass (pairs placement) + fused lin0 ----------------
__global__ __launch_bounds__(256) void k_bucket_lin0(const int* __restrict__ src,
                                                     const int* __restrict__ dst,
                                                     int* __restrict__ bcur,
                                                     int2* __restrict__ pairs, int e,
                                                     const float* __restrict__ X,
                                                     const ushort* __restrict__ W,
                                                     const float* __restrict__ bias,
                                                     ushort* __restrict__ AB, int n) {
    if (blockIdx.x < (unsigned)NBLK) {
        // ---- bucket part ----
        __shared__ int lcnt[256];
        __shared__ int lbase[256];
        int tid = threadIdx.x;
        lcnt[tid] = 0;
        __syncthreads();
        int base = blockIdx.x * 4096;
        #pragma unroll
        for (int k = 0; k < 16; ++k) {
            int e0 = base + k * 256 + tid;
            if (e0 < e) atomicAdd(&lcnt[dst[e0] >> 8], 1);
        }
        __syncthreads();
        int cnt = lcnt[tid];
        if (cnt > 0) lbase[tid] = atomicAdd(&bcur[tid], cnt);
        __syncthreads();
        lcnt[tid] = 0;
        __syncthreads();
        #pragma unroll
        for (int k = 0; k < 16; ++k) {
            int e0 = base + k * 256 + tid;
            if (e0 < e) {
                int d = dst[e0];
                int b = d >> 8;
                int off = atomicAdd(&lcnt[b], 1);
                pairs[lbase[b] + off] = make_int2(src[e0], d);
            }
        }
        return;
    }
    // ---- lin0 part ----
    int bid = blockIdx.x - NBLK;
    int nlb = gridDim.x - NBLK;
    int lane = threadIdx.x & 63, wave = threadIdx.x >> 6;
    int c0 = lane & 15, kg = (lane >> 4) * 8;
    int tb0 = wave * 32;
    bf16x8 B[2][4];
    #pragma unroll
    for (int t = 0; t < 2; ++t)
        #pragma unroll
        for (int kk = 0; kk < 4; ++kk)
            B[t][kk] = ldb8(W + (size_t)(tb0 + t * 16 + c0) * 128 + kk * 32 + kg);

    for (int m0 = bid * 64; m0 < n; m0 += nlb * 64) {
        f32x4 acc[4][2];
        #pragma unroll
        for (int m = 0; m < 4; ++m) { acc[m][0] = {0,0,0,0}; acc[m][1] = {0,0,0,0}; }
        #pragma unroll
        for (int kk = 0; kk < 4; ++kk) {
            #pragma unroll
            for (int m = 0; m < 4; ++m) {
                int ar = min(m0 + m * 16 + c0, n - 1);
                const float* a = X + (size_t)ar * 128 + kk * 32 + kg;
                float4 x0 = *reinterpret_cast<const float4*>(a);
                float4 x1 = *reinterpret_cast<const float4*>(a + 4);
                bf16x8 af;
                af[0] = (short)f2b(x0.x); af[1] = (short)f2b(x0.y);
                af[2] = (short)f2b(x0.z); af[3] = (short)f2b(x0.w);
                af[4] = (short)f2b(x1.x); af[5] = (short)f2b(x1.y);
                af[6] = (short)f2b(x1.z); af[7] = (short)f2b(x1.w);
                acc[m][0] = __builtin_amdgcn_mfma_f32_16x16x32_bf16(af, B[0][kk], acc[m][0], 0, 0, 0);
                acc[m][1] = __builtin_amdgcn_mfma_f32_16x16x32_bf16(af, B[1][kk], acc[m][1], 0, 0, 0);
            }
        }
        #pragma unroll
        for (int m = 0; m < 4; ++m) {
            int rbase = m0 + m * 16 + ((lane >> 4) << 2);
            #pragma unroll
            for (int t = 0; t < 2; ++t) {
                int col = tb0 + t * 16 + c0;
                float bv = bias[col];
                #pragma unroll
                for (int j = 0; j < 4; ++j) {
                    int row = rbase + j;
                    if (row < n) {
                        float v = fmaxf(acc[m][t][j] + bv, 0.f);
                        AB[(size_t)row * 128 + col] = f2b(v);
                    }
                }
            }
        }
    }
}

// ---------------- fill: per-node offsets from bucket pairs + rowptr + csr scatter ----------------
__global__ __launch_bounds__(256) void k_fillbkt2(const int2* __restrict__ pairs,
                                                  const int* __restrict__ bbase,
                                                  int* __restrict__ rowptr,
                                                  int* __restrict__ csr) {
    __shared__ int lcnt[256];
    __shared__ int s[256];
    __shared__ int lcur[256];
    int b = blockIdx.x, tid = threadIdx.x;
    int w0 = b << 8;
    int r0 = bbase[b], r1 = bbase[b + 1];
    lcnt[tid] = 0;
    __syncthreads();
    for (int i = r0 + tid; i < r1; i += 256)
        atomicAdd(&lcnt[pairs[i].y - w0], 1);
    __syncthreads();
    int v = lcnt[tid];
    s[tid] = v;
    __syncthreads();
    #pragma unroll
    for (int off = 1; off < 256; off <<= 1) {
        int x = (tid >= off) ? s[tid - off] : 0;
        __syncthreads();
        s[tid] += x;
        __syncthreads();
    }
    int ex = r0 + s[tid] - v;   // global CSR offset of node w0+tid
    lcur[tid] = ex;
    if (w0 + tid < NN) rowptr[w0 + tid] = ex;
    if (b == 0 && tid == 0) rowptr[NN] = NE;
    __syncthreads();
    for (int i = r0 + tid; i < r1; i += 256) {
        int2 p = pairs[i];
        int pos = atomicAdd(&lcur[p.y - w0], 1);
        csr[pos] = p.x;
    }
}

// ---------------- fused aggregation + GIN MLP ----------------
__global__ __launch_bounds__(512) void k_aggmlp(const ushort* __restrict__ AB,
                                                const int* __restrict__ rowptr,
                                                const int* __restrict__ csr,
                                                const ushort* __restrict__ W1,
                                                const float* __restrict__ b1,
                                                const ushort* __restrict__ W2,
                                                const float* __restrict__ b2,
                                                ushort* __restrict__ mt, int n) {
    __shared__ ushort Z_lds[32 * 136];
    __shared__ ushort M_lds[32 * 136];
    int tid = threadIdx.x;
    int lane = tid & 63, wave = tid >> 6;
    int c0 = lane & 15, kg = (lane >> 4) * 8;
    int colw = wave * 16 + c0;
    int rj = (lane >> 4) << 2;
    int grow_r = tid >> 4;
    int segi = tid & 15;
    const int stride = gridDim.x * 32;

    bf16x8 B1[4], B2[4];
    #pragma unroll
    for (int kk = 0; kk < 4; ++kk) {
        B1[kk] = ldb8(W1 + (size_t)colw * 128 + kk * 32 + kg);
        B2[kk] = ldb8(W2 + (size_t)colw * 128 + kk * 32 + kg);
    }
    float bv1 = b1[colw], bv2 = b2[colw];
    const uint4* bp = (const uint4*)AB;

    for (int m0 = blockIdx.x * 32; m0 < n; m0 += stride) {
        f32x8 A0 = {0,0,0,0,0,0,0,0};
        int grow = m0 + grow_r;
        if (grow < n) {
            f32x8 A1 = {0,0,0,0,0,0,0,0}, A2 = {0,0,0,0,0,0,0,0}, A3 = {0,0,0,0,0,0,0,0};
            A0 = acc8(A0, bp[(size_t)grow * 16 + segi]);
            int p = rowptr[grow], p1 = rowptr[grow + 1];
            for (; p + 4 <= p1; p += 4) {
                uint4 v0 = bp[(size_t)csr[p + 0] * 16 + segi];
                uint4 v1 = bp[(size_t)csr[p + 1] * 16 + segi];
                uint4 v2 = bp[(size_t)csr[p + 2] * 16 + segi];
                uint4 v3 = bp[(size_t)csr[p + 3] * 16 + segi];
                A0 = acc8(A0, v0); A1 = acc8(A1, v1);
                A2 = acc8(A2, v2); A3 = acc8(A3, v3);
            }
            for (; p < p1; ++p) A0 = acc8(A0, bp[(size_t)csr[p] * 16 + segi]);
            #pragma unroll
            for (int i = 0; i < 8; ++i) A0[i] += A1[i] + A2[i] + A3[i];
        }
        bf16x8 zz;
        #pragma unroll
        for (int i = 0; i < 8; ++i) zz[i] = (short)f2b(A0[i]);
        *reinterpret_cast<bf16x8*>(&Z_lds[grow_r * 136 + segi * 8]) = zz;
        __syncthreads();
        {
            f32x4 a[2] = {{0,0,0,0},{0,0,0,0}};
            #pragma unroll
            for (int kk = 0; kk < 4; ++kk) {
                bf16x8 f0 = *reinterpret_cast<const bf16x8*>(&Z_lds[c0 * 136 + kk * 32 + kg]);
                bf16x8 f1 = *reinterpret_cast<const bf16x8*>(&Z_lds[(16 + c0) * 136 + kk * 32 + kg]);
                a[0] = __builtin_amdgcn_mfma_f32_16x16x32_bf16(f0, B1[kk], a[0], 0, 0, 0);
                a[1] = __builtin_amdgcn_mfma_f32_16x16x32_bf16(f1, B1[kk], a[1], 0, 0, 0);
            }
            #pragma unroll
            for (int m = 0; m < 2; ++m)
                #pragma unroll
                for (int j = 0; j < 4; ++j)
                    M_lds[(m * 16 + rj + j) * 136 + colw] = f2b(fmaxf(a[m][j] + bv1, 0.f));
        }
        __syncthreads();
        {
            f32x4 a[2] = {{0,0,0,0},{0,0,0,0}};
            #pragma unroll
            for (int kk = 0; kk < 4; ++kk) {
                bf16x8 f0 = *reinterpret_cast<const bf16x8*>(&M_lds[c0 * 136 + kk * 32 + kg]);
                bf16x8 f1 = *reinterpret_cast<const bf16x8*>(&M_lds[(16 + c0) * 136 + kk * 32 + kg]);
                a[0] = __builtin_amdgcn_mfma_f32_16x16x32_bf16(f0, B2[kk], a[0], 0, 0, 0);
                a[1] = __builtin_amdgcn_mfma_f32_16x16x32_bf16(f1, B2[kk], a[1], 0, 0, 0);
            }
            #pragma unroll
            for (int m = 0; m < 2; ++m)
                #pragma unroll
                for (int j = 0; j < 4; ++j) {
                    int gr2 = m0 + m * 16 + rj + j;
                    if (gr2 < n)
                        mt[(size_t)gr2 * 128 + colw] = f2b(fmaxf(a[m][j] + bv2, 0.f));
                }
        }
        __syncthreads();
    }
}

// ---------------- GRU: rz + ngate fully in-register per wave ----------------
template<bool WRITEH>
__global__ __launch_bounds__(512) void k_gru3b(const ushort* __restrict__ ABin,
                                               const ushort* __restrict__ mt,
                                               const ushort* __restrict__ wrz,
                                               const float* __restrict__ brz,
                                               const ushort* __restrict__ Wn,
                                               const ushort* __restrict__ Un,
                                               const float* __restrict__ bin,
                                               const float* __restrict__ bhn,
                                               float* __restrict__ Hf,
                                               ushort* __restrict__ ABout, int n) {
    __shared__ ushort A_lds[32 * 264];   // [h | m]
    int tid = threadIdx.x;
    int lane = tid & 63, wave = tid >> 6;
    int c0 = lane & 15, kg = (lane >> 4) * 8;
    int colw = wave * 16 + c0;
    int rj = (lane >> 4) << 2;
    int srow = tid >> 4, scol = (tid & 15) * 8;
    const int stride = gridDim.x * 32;

    bf16x8 Brz[2][8];
    #pragma unroll
    for (int kk = 0; kk < 8; ++kk) {
        Brz[0][kk] = ldb8(wrz + (size_t)(colw) * 256 + kk * 32 + kg);
        Brz[1][kk] = ldb8(wrz + (size_t)(128 + colw) * 256 + kk * 32 + kg);
    }
    bf16x8 Bn[4], Bu[4];
    #pragma unroll
    for (int kk = 0; kk < 4; ++kk) {
        Bn[kk] = ldb8(Wn + (size_t)colw * 128 + kk * 32 + kg);
        Bu[kk] = ldb8(Un + (size_t)colw * 128 + kk * 32 + kg);
    }
    float biN = bin[colw], bhN = bhn[colw];
    float brzR = brz[colw], brzZ = brz[128 + colw];

    int m0 = blockIdx.x * 32;
    bf16x8 ph, pm;
    if (m0 < n) {
        int gr = min(m0 + srow, n - 1);
        ph = ldb8(ABin + (size_t)gr * 128 + scol);
        pm = ldb8(mt + (size_t)gr * 128 + scol);
    }
    for (; m0 < n; m0 += stride) {
        *reinterpret_cast<bf16x8*>(&A_lds[srow * 264 + scol]) = ph;
        *reinterpret_cast<bf16x8*>(&A_lds[srow * 264 + 128 + scol]) = pm;
        __syncthreads();
        int mn = m0 + stride;
        if (mn < n) {
            int gr = min(mn + srow, n - 1);
            ph = ldb8(ABin + (size_t)gr * 128 + scol);
            pm = ldb8(mt + (size_t)gr * 128 + scol);
        }
        f32x4 aR[2] = {{0,0,0,0},{0,0,0,0}};
        f32x4 aZ[2] = {{0,0,0,0},{0,0,0,0}};
        #pragma unroll
        for (int kk = 0; kk < 8; ++kk) {
            bf16x8 f0 = *reinterpret_cast<const bf16x8*>(&A_lds[c0 * 264 + kk * 32 + kg]);
            bf16x8 f1 = *reinterpret_cast<const bf16x8*>(&A_lds[(16 + c0) * 264 + kk * 32 + kg]);
            aR[0] = __builtin_amdgcn_mfma_f32_16x16x32_bf16(f0, Brz[0][kk], aR[0], 0, 0, 0);
            aZ[0] = __builtin_amdgcn_mfma_f32_16x16x32_bf16(f0, Brz[1][kk], aZ[0], 0, 0, 0);
            aR[1] = __builtin_amdgcn_mfma_f32_16x16x32_bf16(f1, Brz[0][kk], aR[1], 0, 0, 0);
            aZ[1] = __builtin_amdgcn_mfma_f32_16x16x32_bf16(f1, Brz[1][kk], aZ[1], 0, 0, 0);
        }
        f32x4 an[2] = {{0,0,0,0},{0,0,0,0}};
        f32x4 au[2] = {{0,0,0,0},{0,0,0,0}};
        #pragma unroll
        for (int kk = 0; kk < 4; ++kk) {
            bf16x8 am0 = *reinterpret_cast<const bf16x8*>(&A_lds[c0 * 264 + 128 + kk * 32 + kg]);
            bf16x8 ah0 = *reinterpret_cast<const bf16x8*>(&A_lds[c0 * 264 + kk * 32 + kg]);
            bf16x8 am1 = *reinterpret_cast<const bf16x8*>(&A_lds[(16 + c0) * 264 + 128 + kk * 32 + kg]);
            bf16x8 ah1 = *reinterpret_cast<const bf16x8*>(&A_lds[(16 + c0) * 264 + kk * 32 + kg]);
            an[0] = __builtin_amdgcn_mfma_f32_16x16x32_bf16(am0, Bn[kk], an[0], 0, 0, 0);
            au[0] = __builtin_amdgcn_mfma_f32_16x16x32_bf16(ah0, Bu[kk], au[0], 0, 0, 0);
            an[1] = __builtin_amdgcn_mfma_f32_16x16x32_bf16(am1, Bn[kk], an[1], 0, 0, 0);
            au[1] = __builtin_amdgcn_mfma_f32_16x16x32_bf16(ah1, Bu[kk], au[1], 0, 0, 0);
        }
        #pragma unroll
        for (int m = 0; m < 2; ++m)
            #pragma unroll
            for (int j = 0; j < 4; ++j) {
                int row = m * 16 + rj + j;
                int grow = m0 + row;
                if (grow < n) {
                    float r  = sigm(aR[m][j] + brzR);
                    float zt = sigm(aZ[m][j] + brzZ);
                    float hold = b2f(A_lds[row * 264 + colw]);
                    float nn = ftanh(an[m][j] + biN + r * (au[m][j] + bhN));
                    float hn = (1.f - zt) * nn + zt * hold;
                    ABout[(size_t)grow * 128 + colw] = f2b(hn);
                    if (WRITEH) Hf[(size_t)grow * 128 + colw] = hn;
                }
            }
        __syncthreads();
    }
}

// ---------------- fused Set2Set step: LSTM cell + online-softmax attention pool ----------------
__global__ __launch_bounds__(512) void k_s2s(const ushort* __restrict__ AB,
                                             const float* __restrict__ Wt,
                                             const float* __restrict__ bl,
                                             const int* __restrict__ gstart,
                                             const float* __restrict__ qstar,
                                             float* __restrict__ hl,
                                             float* __restrict__ cl,
                                             float* __restrict__ qout) {
    int g = blockIdx.x, tid = threadIdx.x, lane = tid & 63, wave = tid >> 6;
    __shared__ float qh[384];
    __shared__ float gbuf[512];
    __shared__ float q[128];
    __shared__ float wm[8];
    __shared__ float sw[8];
    __shared__ float rv[8][128];
    if (tid < 256) qh[tid] = qstar[(size_t)g * 256 + tid];
    else if (tid < 384) qh[tid] = hl[(size_t)g * 128 + (tid - 256)];
    __syncthreads();
    float acc = bl[tid];
    #pragma unroll 8
    for (int k = 0; k < 384; ++k)
        acc += Wt[(size_t)k * 512 + tid] * qh[k];
    gbuf[tid] = acc;
    __syncthreads();
    if (tid < 128) {
        float iv = sigm(gbuf[tid]);
        float fv = sigm(gbuf[128 + tid]);
        float gv = ftanh(gbuf[256 + tid]);
        float ov = sigm(gbuf[384 + tid]);
        float cn = fv * cl[(size_t)g * 128 + tid] + iv * gv;
        cl[(size_t)g * 128 + tid] = cn;
        float hn = ov * ftanh(cn);
        hl[(size_t)g * 128 + tid] = hn;
        q[tid] = hn;
    }
    __syncthreads();
    int s = gstart[g], e = gstart[g + 1];
    float q0 = q[2 * lane], q1 = q[2 * lane + 1];
    float mx = -1e30f, sumw = 0.f, a0 = 0.f, a1 = 0.f;
    for (int node = s + wave; node < e; node += 8) {
        unsigned u = ((const unsigned*)AB)[(size_t)node * 64 + lane];
        float v0 = b2f(u & 0xffff), v1 = b2f(u >> 16);
        float p = v0 * q0 + v1 * q1;
        #pragma unroll
        for (int off = 1; off < 64; off <<= 1) p += __shfl_xor(p, off);
        float nm = fmaxf(mx, p);
        float corr = __expf(mx - nm);
        float wgt = __expf(p - nm);
        sumw = sumw * corr + wgt;
        a0 = a0 * corr + wgt * v0;
        a1 = a1 * corr + wgt * v1;
        mx = nm;
    }
    if (lane == 0) wm[wave] = mx;
    __syncthreads();
    float gm = fmaxf(fmaxf(fmaxf(wm[0], wm[1]), fmaxf(wm[2], wm[3])),
                     fmaxf(fmaxf(wm[4], wm[5]), fmaxf(wm[6], wm[7])));
    float cw = __expf(mx - gm);
    rv[wave][2 * lane] = a0 * cw;
    rv[wave][2 * lane + 1] = a1 * cw;
    if (lane == 0) sw[wave] = sumw * cw;
    __syncthreads();
    if (tid < 128) {
        float r = 0.f, d = 1e-16f;
        #pragma unroll
        for (int wv = 0; wv < 8; ++wv) r += rv[wv][tid];
        #pragma unroll
        for (int wv = 0; wv < 8; ++wv) d += sw[wv];
        qout[(size_t)g * 256 + tid] = q[tid];
        qout[(size_t)g * 256 + 128 + tid] = r / d;
    }
}

// ---------------- launch ----------------
extern "C" void kernel_launch(void* const* d_in, const int* in_sizes, int n_in,
                              void* d_out, int out_size, void* d_ws, size_t ws_size,
                              hipStream_t stream) {
    const float* x        = (const float*)d_in[0];
    const int*   ei       = (const int*)d_in[1];
    const int*   batch    = (const int*)d_in[2];
    const float* lin0_W   = (const float*)d_in[3];
    const float* lin0_b   = (const float*)d_in[4];
    const float* gin_W1   = (const float*)d_in[5];
    const float* gin_b1   = (const float*)d_in[6];
    const float* gin_W2   = (const float*)d_in[7];
    const float* gin_b2   = (const float*)d_in[8];
    const float* gru_Wih  = (const float*)d_in[9];
    const float* gru_Whh  = (const float*)d_in[10];
    const float* gru_bih  = (const float*)d_in[11];
    const float* gru_bhh  = (const float*)d_in[12];
    const float* lstm_Wih = (const float*)d_in[13];
    const float* lstm_Whh = (const float*)d_in[14];
    const float* lstm_bih = (const float*)d_in[15];
    const float* lstm_bhh = (const float*)d_in[16];

    float* qstar_out = (float*)d_out;                         // [NG, 256]
    float* h         = (float*)d_out + (size_t)NG * 2 * DIM;  // [NN, 128] fp32 == `out`

    char* w = (char*)d_ws;
    ushort* AB0   = (ushort*)w; w += (size_t)NN * 128 * 2;   // ping (h only)
    ushort* AB1   = (ushort*)w; w += (size_t)NN * 128 * 2;   // pong (h only)
    ushort* mt    = (ushort*)w; w += (size_t)NN * 128 * 2;   // GIN MLP out
    ushort* wlin0 = (ushort*)w; w += 16384 * 2;
    ushort* wg1   = (ushort*)w; w += 16384 * 2;
    ushort* wg2   = (ushort*)w; w += 16384 * 2;
    ushort* wihb  = (ushort*)w; w += 49152 * 2;
    ushort* whhb  = (ushort*)w; w += 49152 * 2;
    ushort* wrz   = (ushort*)w; w += 65536 * 2;
    float* brz    = (float*)w;  w += 256 * 4;
    float* wltr   = (float*)w;  w += (size_t)512 * 384 * 4;  // LSTM W transposed
    float* bl     = (float*)w;  w += 512 * 4;
    float* qstar  = (float*)w;  w += (size_t)NG * 2 * DIM * 4;  // contiguous with hl, cl
    float* hl     = (float*)w;  w += (size_t)NG * DIM * 4;
    float* cl     = (float*)w;  w += (size_t)NG * DIM * 4;
    int* rowptr   = (int*)w;    w += (size_t)(NN + 1) * 4;
    int* bcnt     = (int*)w;    w += 256 * 4;
    int* bbase    = (int*)w;    w += 257 * 4;
    int* bcur     = (int*)w;    w += 256 * 4;
    int* csr_src  = (int*)w;    w += (size_t)NE * 4;
    int2* pairs   = (int2*)w;   w += (size_t)NE * 8;
    int* gstart   = (int*)w;    w += (size_t)(NG + 1) * 4;

    const int* src = ei;
    const int* dst = ei + NE;

    // one mega-prep (weights, biases, transposes, gstart, state-zero, bcnt-zero)
    k_prep<<<(PREP_TOTAL + 255) / 256, 256, 0, stream>>>(
        lin0_W, gin_W1, gin_W2, gru_Wih, gru_Whh, gru_bih, gru_bhh,
        lstm_Wih, lstm_Whh, lstm_bih, lstm_bhh, batch,
        wlin0, wg1, wg2, wihb, whhb, wrz, brz, wltr, bl, gstart, qstar, bcnt);

    // CSR build (degree-free) + fused lin0
    k_bcount<<<(NE + 4095) / 4096, 256, 0, stream>>>(dst, bcnt, NE);
    k_btop<<<1, 256, 0, stream>>>(bcnt, bbase, bcur);
    k_bucket_lin0<<<NBLK + 782, 256, 0, stream>>>(src, dst, bcur, pairs, NE,
                                                  x, wlin0, lin0_b, AB0, NN);
    k_fillbkt2<<<NBLK, 256, 0, stream>>>(pairs, bbase, rowptr, csr_src);

    // 3 GC layers, ping-pong AB buffers (gather fused into the MLP kernel)
    for (int t = 0; t < 3; ++t) {
        ushort* ABc = (t & 1) ? AB1 : AB0;
        ushort* ABn = (t & 1) ? AB0 : AB1;
        k_aggmlp<<<1024, 512, 0, stream>>>(ABc, rowptr, csr_src,
                                           wg1, gin_b1, wg2, gin_b2, mt, NN);
        if (t < 2)
            k_gru3b<false><<<512, 512, 0, stream>>>(ABc, mt, wrz, brz,
                                                    wihb + 256 * 128, whhb + 256 * 128,
                                                    gru_bih + 256, gru_bhh + 256, h, ABn, NN);
        else
            k_gru3b<true><<<512, 512, 0, stream>>>(ABc, mt, wrz, brz,
                                                   wihb + 256 * 128, whhb + 256 * 128,
                                                   gru_bih + 256, gru_bhh + 256, h, ABn, NN);
    }
    // final bf16 h lives in AB1 (t=2 wrote ABn=AB1)
    const ushort* ABfin = AB1;

    // Set2Set (fused LSTM + attention per step)
    for (int st = 0; st < 3; ++st)
        k_s2s<<<NG, 512, 0, stream>>>(ABfin, wltr, bl, gstart, qstar, hl, cl,
                                      (st == 2) ? qstar_out : qstar);
}

// Round 20
// 354.254 us; speedup vs baseline: 1.3219x; 1.0202x over previous
//
#include <hip/hip_runtime.h>
#include <hip/hip_bf16.h>
#include <math.h>

static constexpr int NN  = 50000;   // nodes
static constexpr int NE  = 800000;  // edges
static constexpr int DIM = 128;
static constexpr int NG  = 512;     // graphs
static constexpr int NBLK = (NN + 255) / 256;  // 196 buckets

typedef __attribute__((ext_vector_type(8))) short bf16x8;
typedef __attribute__((ext_vector_type(4))) float f32x4;
typedef __attribute__((ext_vector_type(8))) float f32x8;

__device__ __forceinline__ float sigm(float x) {
    return __builtin_amdgcn_rcpf(1.0f + __expf(-x));
}
__device__ __forceinline__ float ftanh(float x) {
    x = fminf(fmaxf(x, -15.f), 15.f);
    float t = __expf(2.f * x);
    return (t - 1.f) * __builtin_amdgcn_rcpf(t + 1.f);
}
__device__ __forceinline__ float b2f(ushort u) { return __uint_as_float(((unsigned)u) << 16); }
__device__ __forceinline__ ushort f2b(float f) {
    __hip_bfloat16 h = __float2bfloat16(f);
    return *reinterpret_cast<ushort*>(&h);
}
__device__ __forceinline__ bf16x8 ldb8(const ushort* p) {
    return *reinterpret_cast<const bf16x8*>(p);
}
__device__ __forceinline__ f32x8 acc8(f32x8 a, uint4 v) {
    a[0] += b2f(v.x & 0xffff); a[1] += b2f(v.x >> 16);
    a[2] += b2f(v.y & 0xffff); a[3] += b2f(v.y >> 16);
    a[4] += b2f(v.z & 0xffff); a[5] += b2f(v.z >> 16);
    a[6] += b2f(v.w & 0xffff); a[7] += b2f(v.w >> 16);
    return a;
}

// ---------------- mega-prep: weight conversions + init ----------------
__global__ __launch_bounds__(256) void k_prep(const float* __restrict__ lin0_W,
                                              const float* __restrict__ gin_W1,
                                              const float* __restrict__ gin_W2,
                                              const float* __restrict__ gru_Wih,
                                              const float* __restrict__ gru_Whh,
                                              const float* __restrict__ gru_bih,
                                              const float* __restrict__ gru_bhh,
                                              const float* __restrict__ lstm_Wih,
                                              const float* __restrict__ lstm_Whh,
                                              const float* __restrict__ lstm_bih,
                                              const float* __restrict__ lstm_bhh,
                                              const int* __restrict__ batch,
                                              ushort* __restrict__ wlin0,
                                              ushort* __restrict__ wg1,
                                              ushort* __restrict__ wg2,
                                              ushort* __restrict__ wihb,
                                              ushort* __restrict__ whhb,
                                              ushort* __restrict__ wrz,
                                              float* __restrict__ brz,
                                              float* __restrict__ wltr,
                                              float* __restrict__ bl,
                                              int* __restrict__ gstart,
                                              int* __restrict__ bcnt) {
    const int S0 = 16384, S1 = S0 + 16384, S2 = S1 + 16384;
    const int S3 = S2 + 49152, S4 = S3 + 49152, S5 = S4 + 65536;
    const int S6 = S5 + 256, S7 = S6 + 196608, S8 = S7 + 512;
    const int S9 = S8 + (NG + 1), S10 = S9 + 256;
    int i = blockIdx.x * 256 + threadIdx.x;
    if (i < S0) { wlin0[i] = f2b(lin0_W[i]); }
    else if (i < S1) { int j = i - S0; wg1[j] = f2b(gin_W1[j]); }
    else if (i < S2) { int j = i - S1; wg2[j] = f2b(gin_W2[j]); }
    else if (i < S3) { int j = i - S2; wihb[j] = f2b(gru_Wih[j]); }
    else if (i < S4) { int j = i - S3; whhb[j] = f2b(gru_Whh[j]); }
    else if (i < S5) {
        int j = i - S4; int col = j >> 8, k = j & 255;
        int row = (col >> 7) * 128 + (col & 127);
        wrz[j] = f2b((k < 128) ? gru_Whh[row * 128 + k] : gru_Wih[row * 128 + (k - 128)]);
    }
    else if (i < S6) { int j = i - S5; brz[j] = gru_bih[j] + gru_bhh[j]; }
    else if (i < S7) {
        int j = i - S6; int k = j / 512, col = j % 512;
        wltr[j] = (k < 256) ? lstm_Wih[(size_t)col * 256 + k]
                            : lstm_Whh[(size_t)col * 128 + (k - 256)];
    }
    else if (i < S8) { int j = i - S7; bl[j] = lstm_bih[j] + lstm_bhh[j]; }
    else if (i < S9) {
        int g = i - S8;
        int lo = 0, hi = NN;
        while (lo < hi) { int mid = (lo + hi) >> 1; if (batch[mid] < g) lo = mid + 1; else hi = mid; }
        gstart[g] = lo;
    }
    else if (i < S10) { bcnt[i - S9] = 0; }
}
static constexpr int PREP_TOTAL = 16384 * 3 + 49152 * 2 + 65536 + 256 + 196608 + 512 + (NG + 1) + 256;

// ---------------- bucket counts ----------------
__global__ __launch_bounds__(256) void k_bcount(const int* __restrict__ dst,
                                                int* __restrict__ bcnt, int e) {
    __shared__ int l[256];
    int tid = threadIdx.x;
    l[tid] = 0;
    __syncthreads();
    int base = blockIdx.x * 4096;
    #pragma unroll
    for (int k = 0; k < 16; ++k) {
        int e0 = base + k * 256 + tid;
        if (e0 < e) atomicAdd(&l[dst[e0] >> 8], 1);
    }
    __syncthreads();
    if (l[tid] > 0) atomicAdd(&bcnt[tid], l[tid]);
}

__global__ __launch_bounds__(256) void k_btop(const int* __restrict__ bcnt,
                                              int* __restrict__ bbase,
                                              int* __restrict__ bcur) {
    __shared__ int s[256];
    int t = threadIdx.x;
    int v = bcnt[t];
    s[t] = v;
    __syncthreads();
    #pragma unroll
    for (int off = 1; off < 256; off <<= 1) {
        int x = (t >= off) ? s[t - off] : 0;
        __syncthreads();
        s[t] += x;
        __syncthreads();
    }
    int ex = s[t] - v;
    bbase[t] = ex;
    bcur[t] = ex;
    if (t == 255) bbase[256] = s[255];
}

// ---------------- bucket pass + fused lin0 ----------------
__global__ __launch_bounds__(256) void k_bucket_lin0(const int* __restrict__ src,
                                                     const int* __restrict__ dst,
                                                     int* __restrict__ bcur,
                                                     int2* __restrict__ pairs, int e,
                                                     const float* __restrict__ X,
                                                     const ushort* __restrict__ W,
                                                     const float* __restrict__ bias,
                                                     ushort* __restrict__ AB, int n) {
    if (blockIdx.x < (unsigned)NBLK) {
        __shared__ int lcnt[256];
        __shared__ int lbase[256];
        int tid = threadIdx.x;
        lcnt[tid] = 0;
        __syncthreads();
        int base = blockIdx.x * 4096;
        #pragma unroll
        for (int k = 0; k < 16; ++k) {
            int e0 = base + k * 256 + tid;
            if (e0 < e) atomicAdd(&lcnt[dst[e0] >> 8], 1);
        }
        __syncthreads();
        int cnt = lcnt[tid];
        if (cnt > 0) lbase[tid] = atomicAdd(&bcur[tid], cnt);
        __syncthreads();
        lcnt[tid] = 0;
        __syncthreads();
        #pragma unroll
        for (int k = 0; k < 16; ++k) {
            int e0 = base + k * 256 + tid;
            if (e0 < e) {
                int d = dst[e0];
                int b = d >> 8;
                int off = atomicAdd(&lcnt[b], 1);
                pairs[lbase[b] + off] = make_int2(src[e0], d);
            }
        }
        return;
    }
    int bid = blockIdx.x - NBLK;
    int nlb = gridDim.x - NBLK;
    int lane = threadIdx.x & 63, wave = threadIdx.x >> 6;
    int c0 = lane & 15, kg = (lane >> 4) * 8;
    int tb0 = wave * 32;
    bf16x8 B[2][4];
    #pragma unroll
    for (int t = 0; t < 2; ++t)
        #pragma unroll
        for (int kk = 0; kk < 4; ++kk)
            B[t][kk] = ldb8(W + (size_t)(tb0 + t * 16 + c0) * 128 + kk * 32 + kg);

    for (int m0 = bid * 64; m0 < n; m0 += nlb * 64) {
        f32x4 acc[4][2];
        #pragma unroll
        for (int m = 0; m < 4; ++m) { acc[m][0] = {0,0,0,0}; acc[m][1] = {0,0,0,0}; }
        #pragma unroll
        for (int kk = 0; kk < 4; ++kk) {
            #pragma unroll
            for (int m = 0; m < 4; ++m) {
                int ar = min(m0 + m * 16 + c0, n - 1);
                const float* a = X + (size_t)ar * 128 + kk * 32 + kg;
                float4 x0 = *reinterpret_cast<const float4*>(a);
                float4 x1 = *reinterpret_cast<const float4*>(a + 4);
                bf16x8 af;
                af[0] = (short)f2b(x0.x); af[1] = (short)f2b(x0.y);
                af[2] = (short)f2b(x0.z); af[3] = (short)f2b(x0.w);
                af[4] = (short)f2b(x1.x); af[5] = (short)f2b(x1.y);
                af[6] = (short)f2b(x1.z); af[7] = (short)f2b(x1.w);
                acc[m][0] = __builtin_amdgcn_mfma_f32_16x16x32_bf16(af, B[0][kk], acc[m][0], 0, 0, 0);
                acc[m][1] = __builtin_amdgcn_mfma_f32_16x16x32_bf16(af, B[1][kk], acc[m][1], 0, 0, 0);
            }
        }
        #pragma unroll
        for (int m = 0; m < 4; ++m) {
            int rbase = m0 + m * 16 + ((lane >> 4) << 2);
            #pragma unroll
            for (int t = 0; t < 2; ++t) {
                int col = tb0 + t * 16 + c0;
                float bv = bias[col];
                #pragma unroll
                for (int j = 0; j < 4; ++j) {
                    int row = rbase + j;
                    if (row < n) {
                        float v = fmaxf(acc[m][t][j] + bv, 0.f);
                        AB[(size_t)row * 128 + col] = f2b(v);
                    }
                }
            }
        }
    }
}

// ---------------- fill: per-node offsets + rowptr + csr scatter ----------------
__global__ __launch_bounds__(256) void k_fillbkt2(const int2* __restrict__ pairs,
                                                  const int* __restrict__ bbase,
                                                  int* __restrict__ rowptr,
                                                  int* __restrict__ csr) {
    __shared__ int lcnt[256];
    __shared__ int s[256];
    __shared__ int lcur[256];
    int b = blockIdx.x, tid = threadIdx.x;
    int w0 = b << 8;
    int r0 = bbase[b], r1 = bbase[b + 1];
    lcnt[tid] = 0;
    __syncthreads();
    for (int i = r0 + tid; i < r1; i += 256)
        atomicAdd(&lcnt[pairs[i].y - w0], 1);
    __syncthreads();
    int v = lcnt[tid];
    s[tid] = v;
    __syncthreads();
    #pragma unroll
    for (int off = 1; off < 256; off <<= 1) {
        int x = (tid >= off) ? s[tid - off] : 0;
        __syncthreads();
        s[tid] += x;
        __syncthreads();
    }
    int ex = r0 + s[tid] - v;
    lcur[tid] = ex;
    if (w0 + tid < NN) rowptr[w0 + tid] = ex;
    if (b == 0 && tid == 0) rowptr[NN] = NE;
    __syncthreads();
    for (int i = r0 + tid; i < r1; i += 256) {
        int2 p = pairs[i];
        int pos = atomicAdd(&lcur[p.y - w0], 1);
        csr[pos] = p.x;
    }
}

// ---------------- fused aggregation + GIN MLP ----------------
__global__ __launch_bounds__(512) void k_aggmlp(const ushort* __restrict__ AB,
                                                const int* __restrict__ rowptr,
                                                const int* __restrict__ csr,
                                                const ushort* __restrict__ W1,
                                                const float* __restrict__ b1,
                                                const ushort* __restrict__ W2,
                                                const float* __restrict__ b2,
                                                ushort* __restrict__ mt, int n) {
    __shared__ ushort Z_lds[32 * 136];
    __shared__ ushort M_lds[32 * 136];
    int tid = threadIdx.x;
    int lane = tid & 63, wave = tid >> 6;
    int c0 = lane & 15, kg = (lane >> 4) * 8;
    int colw = wave * 16 + c0;
    int rj = (lane >> 4) << 2;
    int grow_r = tid >> 4;
    int segi = tid & 15;
    const int stride = gridDim.x * 32;

    bf16x8 B1[4], B2[4];
    #pragma unroll
    for (int kk = 0; kk < 4; ++kk) {
        B1[kk] = ldb8(W1 + (size_t)colw * 128 + kk * 32 + kg);
        B2[kk] = ldb8(W2 + (size_t)colw * 128 + kk * 32 + kg);
    }
    float bv1 = b1[colw], bv2 = b2[colw];
    const uint4* bp = (const uint4*)AB;

    for (int m0 = blockIdx.x * 32; m0 < n; m0 += stride) {
        f32x8 A0 = {0,0,0,0,0,0,0,0};
        int grow = m0 + grow_r;
        if (grow < n) {
            f32x8 A1 = {0,0,0,0,0,0,0,0}, A2 = {0,0,0,0,0,0,0,0}, A3 = {0,0,0,0,0,0,0,0};
            A0 = acc8(A0, bp[(size_t)grow * 16 + segi]);
            int p = rowptr[grow], p1 = rowptr[grow + 1];
            for (; p + 4 <= p1; p += 4) {
                uint4 v0 = bp[(size_t)csr[p + 0] * 16 + segi];
                uint4 v1 = bp[(size_t)csr[p + 1] * 16 + segi];
                uint4 v2 = bp[(size_t)csr[p + 2] * 16 + segi];
                uint4 v3 = bp[(size_t)csr[p + 3] * 16 + segi];
                A0 = acc8(A0, v0); A1 = acc8(A1, v1);
                A2 = acc8(A2, v2); A3 = acc8(A3, v3);
            }
            for (; p < p1; ++p) A0 = acc8(A0, bp[(size_t)csr[p] * 16 + segi]);
            #pragma unroll
            for (int i = 0; i < 8; ++i) A0[i] += A1[i] + A2[i] + A3[i];
        }
        bf16x8 zz;
        #pragma unroll
        for (int i = 0; i < 8; ++i) zz[i] = (short)f2b(A0[i]);
        *reinterpret_cast<bf16x8*>(&Z_lds[grow_r * 136 + segi * 8]) = zz;
        __syncthreads();
        {
            f32x4 a[2] = {{0,0,0,0},{0,0,0,0}};
            #pragma unroll
            for (int kk = 0; kk < 4; ++kk) {
                bf16x8 f0 = *reinterpret_cast<const bf16x8*>(&Z_lds[c0 * 136 + kk * 32 + kg]);
                bf16x8 f1 = *reinterpret_cast<const bf16x8*>(&Z_lds[(16 + c0) * 136 + kk * 32 + kg]);
                a[0] = __builtin_amdgcn_mfma_f32_16x16x32_bf16(f0, B1[kk], a[0], 0, 0, 0);
                a[1] = __builtin_amdgcn_mfma_f32_16x16x32_bf16(f1, B1[kk], a[1], 0, 0, 0);
            }
            #pragma unroll
            for (int m = 0; m < 2; ++m)
                #pragma unroll
                for (int j = 0; j < 4; ++j)
                    M_lds[(m * 16 + rj + j) * 136 + colw] = f2b(fmaxf(a[m][j] + bv1, 0.f));
        }
        __syncthreads();
        {
            f32x4 a[2] = {{0,0,0,0},{0,0,0,0}};
            #pragma unroll
            for (int kk = 0; kk < 4; ++kk) {
                bf16x8 f0 = *reinterpret_cast<const bf16x8*>(&M_lds[c0 * 136 + kk * 32 + kg]);
                bf16x8 f1 = *reinterpret_cast<const bf16x8*>(&M_lds[(16 + c0) * 136 + kk * 32 + kg]);
                a[0] = __builtin_amdgcn_mfma_f32_16x16x32_bf16(f0, B2[kk], a[0], 0, 0, 0);
                a[1] = __builtin_amdgcn_mfma_f32_16x16x32_bf16(f1, B2[kk], a[1], 0, 0, 0);
            }
            #pragma unroll
            for (int m = 0; m < 2; ++m)
                #pragma unroll
                for (int j = 0; j < 4; ++j) {
                    int gr2 = m0 + m * 16 + rj + j;
                    if (gr2 < n)
                        mt[(size_t)gr2 * 128 + colw] = f2b(fmaxf(a[m][j] + bv2, 0.f));
                }
        }
        __syncthreads();
    }
}

// ---------------- GRU: rz + ngate fully in-register per wave ----------------
template<bool WRITEH>
__global__ __launch_bounds__(512) void k_gru3b(const ushort* __restrict__ ABin,
                                               const ushort* __restrict__ mt,
                                               const ushort* __restrict__ wrz,
                                               const float* __restrict__ brz,
                                               const ushort* __restrict__ Wn,
                                               const ushort* __restrict__ Un,
                                               const float* __restrict__ bin,
                                               const float* __restrict__ bhn,
                                               float* __restrict__ Hf,
                                               ushort* __restrict__ ABout, int n) {
    __shared__ ushort A_lds[32 * 264];   // [h | m]
    int tid = threadIdx.x;
    int lane = tid & 63, wave = tid >> 6;
    int c0 = lane & 15, kg = (lane >> 4) * 8;
    int colw = wave * 16 + c0;
    int rj = (lane >> 4) << 2;
    int srow = tid >> 4, scol = (tid & 15) * 8;
    const int stride = gridDim.x * 32;

    bf16x8 Brz[2][8];
    #pragma unroll
    for (int kk = 0; kk < 8; ++kk) {
        Brz[0][kk] = ldb8(wrz + (size_t)(colw) * 256 + kk * 32 + kg);
        Brz[1][kk] = ldb8(wrz + (size_t)(128 + colw) * 256 + kk * 32 + kg);
    }
    bf16x8 Bn[4], Bu[4];
    #pragma unroll
    for (int kk = 0; kk < 4; ++kk) {
        Bn[kk] = ldb8(Wn + (size_t)colw * 128 + kk * 32 + kg);
        Bu[kk] = ldb8(Un + (size_t)colw * 128 + kk * 32 + kg);
    }
    float biN = bin[colw], bhN = bhn[colw];
    float brzR = brz[colw], brzZ = brz[128 + colw];

    int m0 = blockIdx.x * 32;
    bf16x8 ph, pm;
    if (m0 < n) {
        int gr = min(m0 + srow, n - 1);
        ph = ldb8(ABin + (size_t)gr * 128 + scol);
        pm = ldb8(mt + (size_t)gr * 128 + scol);
    }
    for (; m0 < n; m0 += stride) {
        *reinterpret_cast<bf16x8*>(&A_lds[srow * 264 + scol]) = ph;
        *reinterpret_cast<bf16x8*>(&A_lds[srow * 264 + 128 + scol]) = pm;
        __syncthreads();
        int mn = m0 + stride;
        if (mn < n) {
            int gr = min(mn + srow, n - 1);
            ph = ldb8(ABin + (size_t)gr * 128 + scol);
            pm = ldb8(mt + (size_t)gr * 128 + scol);
        }
        f32x4 aR[2] = {{0,0,0,0},{0,0,0,0}};
        f32x4 aZ[2] = {{0,0,0,0},{0,0,0,0}};
        #pragma unroll
        for (int kk = 0; kk < 8; ++kk) {
            bf16x8 f0 = *reinterpret_cast<const bf16x8*>(&A_lds[c0 * 264 + kk * 32 + kg]);
            bf16x8 f1 = *reinterpret_cast<const bf16x8*>(&A_lds[(16 + c0) * 264 + kk * 32 + kg]);
            aR[0] = __builtin_amdgcn_mfma_f32_16x16x32_bf16(f0, Brz[0][kk], aR[0], 0, 0, 0);
            aZ[0] = __builtin_amdgcn_mfma_f32_16x16x32_bf16(f0, Brz[1][kk], aZ[0], 0, 0, 0);
            aR[1] = __builtin_amdgcn_mfma_f32_16x16x32_bf16(f1, Brz[0][kk], aR[1], 0, 0, 0);
            aZ[1] = __builtin_amdgcn_mfma_f32_16x16x32_bf16(f1, Brz[1][kk], aZ[1], 0, 0, 0);
        }
        f32x4 an[2] = {{0,0,0,0},{0,0,0,0}};
        f32x4 au[2] = {{0,0,0,0},{0,0,0,0}};
        #pragma unroll
        for (int kk = 0; kk < 4; ++kk) {
            bf16x8 am0 = *reinterpret_cast<const bf16x8*>(&A_lds[c0 * 264 + 128 + kk * 32 + kg]);
            bf16x8 ah0 = *reinterpret_cast<const bf16x8*>(&A_lds[c0 * 264 + kk * 32 + kg]);
            bf16x8 am1 = *reinterpret_cast<const bf16x8*>(&A_lds[(16 + c0) * 264 + 128 + kk * 32 + kg]);
            bf16x8 ah1 = *reinterpret_cast<const bf16x8*>(&A_lds[(16 + c0) * 264 + kk * 32 + kg]);
            an[0] = __builtin_amdgcn_mfma_f32_16x16x32_bf16(am0, Bn[kk], an[0], 0, 0, 0);
            au[0] = __builtin_amdgcn_mfma_f32_16x16x32_bf16(ah0, Bu[kk], au[0], 0, 0, 0);
            an[1] = __builtin_amdgcn_mfma_f32_16x16x32_bf16(am1, Bn[kk], an[1], 0, 0, 0);
            au[1] = __builtin_amdgcn_mfma_f32_16x16x32_bf16(ah1, Bu[kk], au[1], 0, 0, 0);
        }
        #pragma unroll
        for (int m = 0; m < 2; ++m)
            #pragma unroll
            for (int j = 0; j < 4; ++j) {
                int row = m * 16 + rj + j;
                int grow = m0 + row;
                if (grow < n) {
                    float r  = sigm(aR[m][j] + brzR);
                    float zt = sigm(aZ[m][j] + brzZ);
                    float hold = b2f(A_lds[row * 264 + colw]);
                    float nn = ftanh(an[m][j] + biN + r * (au[m][j] + bhN));
                    float hn = (1.f - zt) * nn + zt * hold;
                    ABout[(size_t)grow * 128 + colw] = f2b(hn);
                    if (WRITEH) Hf[(size_t)grow * 128 + colw] = hn;
                }
            }
        __syncthreads();
    }
}

// ---------------- Set2Set: all 3 steps in ONE kernel, state in LDS ----------------
__global__ __launch_bounds__(512) void k_s2s3(const ushort* __restrict__ AB,
                                              const float* __restrict__ Wt,
                                              const float* __restrict__ bl,
                                              const int* __restrict__ gstart,
                                              float* __restrict__ qout) {
    int g = blockIdx.x, tid = threadIdx.x, lane = tid & 63, wave = tid >> 6;
    __shared__ float qh[384];     // [q_star(256) | hl(128)]
    __shared__ float cl_s[128];
    __shared__ float gbuf[512];
    __shared__ float q[128];
    __shared__ float wm[8];
    __shared__ float sw[8];
    __shared__ float rv[8][128];
    if (tid < 384) qh[tid] = 0.f;
    if (tid < 128) cl_s[tid] = 0.f;
    int s = gstart[g], e = gstart[g + 1];

    for (int st = 0; st < 3; ++st) {
        __syncthreads();   // qh/cl ready
        float acc = bl[tid];
        #pragma unroll 8
        for (int k = 0; k < 384; ++k)
            acc += Wt[(size_t)k * 512 + tid] * qh[k];
        gbuf[tid] = acc;
        __syncthreads();
        if (tid < 128) {
            float iv = sigm(gbuf[tid]);
            float fv = sigm(gbuf[128 + tid]);
            float gv = ftanh(gbuf[256 + tid]);
            float ov = sigm(gbuf[384 + tid]);
            float cn = fv * cl_s[tid] + iv * gv;
            cl_s[tid] = cn;
            float hn = ov * ftanh(cn);
            q[tid] = hn;
            qh[256 + tid] = hn;
        }
        __syncthreads();
        float q0 = q[2 * lane], q1 = q[2 * lane + 1];
        float mx = -1e30f, sumw = 0.f, a0 = 0.f, a1 = 0.f;
        for (int node = s + wave; node < e; node += 8) {
            unsigned u = ((const unsigned*)AB)[(size_t)node * 64 + lane];
            float v0 = b2f(u & 0xffff), v1 = b2f(u >> 16);
            float p = v0 * q0 + v1 * q1;
            #pragma unroll
            for (int off = 1; off < 64; off <<= 1) p += __shfl_xor(p, off);
            float nm = fmaxf(mx, p);
            float corr = __expf(mx - nm);
            float wgt = __expf(p - nm);
            sumw = sumw * corr + wgt;
            a0 = a0 * corr + wgt * v0;
            a1 = a1 * corr + wgt * v1;
            mx = nm;
        }
        if (lane == 0) wm[wave] = mx;
        __syncthreads();
        float gm = fmaxf(fmaxf(fmaxf(wm[0], wm[1]), fmaxf(wm[2], wm[3])),
                         fmaxf(fmaxf(wm[4], wm[5]), fmaxf(wm[6], wm[7])));
        float cw = __expf(mx - gm);
        rv[wave][2 * lane] = a0 * cw;
        rv[wave][2 * lane + 1] = a1 * cw;
        if (lane == 0) sw[wave] = sumw * cw;
        __syncthreads();
        if (tid < 128) {
            float r = 0.f, d = 1e-16f;
            #pragma unroll
            for (int wv = 0; wv < 8; ++wv) r += rv[wv][tid];
            #pragma unroll
            for (int wv = 0; wv < 8; ++wv) d += sw[wv];
            if (st == 2) {
                qout[(size_t)g * 256 + tid] = q[tid];
                qout[(size_t)g * 256 + 128 + tid] = r / d;
            } else {
                qh[tid] = q[tid];
                qh[128 + tid] = r / d;
            }
        }
    }
}

// ---------------- launch ----------------
extern "C" void kernel_launch(void* const* d_in, const int* in_sizes, int n_in,
                              void* d_out, int out_size, void* d_ws, size_t ws_size,
                              hipStream_t stream) {
    const float* x        = (const float*)d_in[0];
    const int*   ei       = (const int*)d_in[1];
    const int*   batch    = (const int*)d_in[2];
    const float* lin0_W   = (const float*)d_in[3];
    const float* lin0_b   = (const float*)d_in[4];
    const float* gin_W1   = (const float*)d_in[5];
    const float* gin_b1   = (const float*)d_in[6];
    const float* gin_W2   = (const float*)d_in[7];
    const float* gin_b2   = (const float*)d_in[8];
    const float* gru_Wih  = (const float*)d_in[9];
    const float* gru_Whh  = (const float*)d_in[10];
    const float* gru_bih  = (const float*)d_in[11];
    const float* gru_bhh  = (const float*)d_in[12];
    const float* lstm_Wih = (const float*)d_in[13];
    const float* lstm_Whh = (const float*)d_in[14];
    const float* lstm_bih = (const float*)d_in[15];
    const float* lstm_bhh = (const float*)d_in[16];

    float* qstar_out = (float*)d_out;                         // [NG, 256]
    float* h         = (float*)d_out + (size_t)NG * 2 * DIM;  // [NN, 128] fp32 == `out`

    char* w = (char*)d_ws;
    ushort* AB0   = (ushort*)w; w += (size_t)NN * 128 * 2;   // ping (h only)
    ushort* AB1   = (ushort*)w; w += (size_t)NN * 128 * 2;   // pong (h only)
    ushort* mt    = (ushort*)w; w += (size_t)NN * 128 * 2;   // GIN MLP out
    ushort* wlin0 = (ushort*)w; w += 16384 * 2;
    ushort* wg1   = (ushort*)w; w += 16384 * 2;
    ushort* wg2   = (ushort*)w; w += 16384 * 2;
    ushort* wihb  = (ushort*)w; w += 49152 * 2;
    ushort* whhb  = (ushort*)w; w += 49152 * 2;
    ushort* wrz   = (ushort*)w; w += 65536 * 2;
    float* brz    = (float*)w;  w += 256 * 4;
    float* wltr   = (float*)w;  w += (size_t)512 * 384 * 4;  // LSTM W transposed
    float* bl     = (float*)w;  w += 512 * 4;
    int* rowptr   = (int*)w;    w += (size_t)(NN + 1) * 4;
    int* bcnt     = (int*)w;    w += 256 * 4;
    int* bbase    = (int*)w;    w += 257 * 4;
    int* bcur     = (int*)w;    w += 256 * 4;
    int* csr_src  = (int*)w;    w += (size_t)NE * 4;
    int2* pairs   = (int2*)w;   w += (size_t)NE * 8;
    int* gstart   = (int*)w;    w += (size_t)(NG + 1) * 4;

    const int* src = ei;
    const int* dst = ei + NE;

    // one mega-prep (weights, biases, transposes, gstart, bcnt-zero)
    k_prep<<<(PREP_TOTAL + 255) / 256, 256, 0, stream>>>(
        lin0_W, gin_W1, gin_W2, gru_Wih, gru_Whh, gru_bih, gru_bhh,
        lstm_Wih, lstm_Whh, lstm_bih, lstm_bhh, batch,
        wlin0, wg1, wg2, wihb, whhb, wrz, brz, wltr, bl, gstart, bcnt);

    // CSR build (degree-free) + fused lin0
    k_bcount<<<(NE + 4095) / 4096, 256, 0, stream>>>(dst, bcnt, NE);
    k_btop<<<1, 256, 0, stream>>>(bcnt, bbase, bcur);
    k_bucket_lin0<<<NBLK + 782, 256, 0, stream>>>(src, dst, bcur, pairs, NE,
                                                  x, wlin0, lin0_b, AB0, NN);
    k_fillbkt2<<<NBLK, 256, 0, stream>>>(pairs, bbase, rowptr, csr_src);

    // 3 GC layers, ping-pong AB buffers (gather fused into the MLP kernel)
    for (int t = 0; t < 3; ++t) {
        ushort* ABc = (t & 1) ? AB1 : AB0;
        ushort* ABn = (t & 1) ? AB0 : AB1;
        k_aggmlp<<<1024, 512, 0, stream>>>(ABc, rowptr, csr_src,
                                           wg1, gin_b1, wg2, gin_b2, mt, NN);
        if (t < 2)
            k_gru3b<false><<<512, 512, 0, stream>>>(ABc, mt, wrz, brz,
                                                    wihb + 256 * 128, whhb + 256 * 128,
                                                    gru_bih + 256, gru_bhh + 256, h, ABn, NN);
        else
            k_gru3b<true><<<512, 512, 0, stream>>>(ABc, mt, wrz, brz,
                                                   wihb + 256 * 128, whhb + 256 * 128,
                                                   gru_bih + 256, gru_bhh + 256, h, ABn, NN);
    }
    // final bf16 h lives in AB1 (t=2 wrote ABn=AB1)
    const ushort* ABfin = AB1;

    // Set2Set: one launch, 3 steps internal
    k_s2s3<<<NG, 512, 0, stream>>>(ABfin, wltr, bl, gstart, qstar_out);
}

// Round 21
// 338.074 us; speedup vs baseline: 1.3851x; 1.0479x over previous
//
#include <hip/hip_runtime.h>
#include <hip/hip_bf16.h>
#include <math.h>

static constexpr int NN  = 50000;   // nodes
static constexpr int NE  = 800000;  // edges
static constexpr int DIM = 128;
static constexpr int NG  = 512;     // graphs
static constexpr int NBLK = (NN + 255) / 256;  // 196 buckets

typedef __attribute__((ext_vector_type(8))) short bf16x8;
typedef __attribute__((ext_vector_type(4))) float f32x4;
typedef __attribute__((ext_vector_type(8))) float f32x8;

__device__ __forceinline__ float sigm(float x) {
    return __builtin_amdgcn_rcpf(1.0f + __expf(-x));
}
__device__ __forceinline__ float ftanh(float x) {
    x = fminf(fmaxf(x, -15.f), 15.f);
    float t = __expf(2.f * x);
    return (t - 1.f) * __builtin_amdgcn_rcpf(t + 1.f);
}
__device__ __forceinline__ float b2f(ushort u) { return __uint_as_float(((unsigned)u) << 16); }
__device__ __forceinline__ ushort f2b(float f) {
    __hip_bfloat16 h = __float2bfloat16(f);
    return *reinterpret_cast<ushort*>(&h);
}
__device__ __forceinline__ bf16x8 ldb8(const ushort* p) {
    return *reinterpret_cast<const bf16x8*>(p);
}
__device__ __forceinline__ f32x8 acc8(f32x8 a, uint4 v) {
    a[0] += b2f(v.x & 0xffff); a[1] += b2f(v.x >> 16);
    a[2] += b2f(v.y & 0xffff); a[3] += b2f(v.y >> 16);
    a[4] += b2f(v.z & 0xffff); a[5] += b2f(v.z >> 16);
    a[6] += b2f(v.w & 0xffff); a[7] += b2f(v.w >> 16);
    return a;
}

// ---------------- mega-prep: weight conversions + init ----------------
// wltr now bf16-PAIR packed: wp[pk*512+col] = bf16(W[2pk][col]) | bf16(W[2pk+1][col])<<16
__global__ __launch_bounds__(256) void k_prep(const float* __restrict__ lin0_W,
                                              const float* __restrict__ gin_W1,
                                              const float* __restrict__ gin_W2,
                                              const float* __restrict__ gru_Wih,
                                              const float* __restrict__ gru_Whh,
                                              const float* __restrict__ gru_bih,
                                              const float* __restrict__ gru_bhh,
                                              const float* __restrict__ lstm_Wih,
                                              const float* __restrict__ lstm_Whh,
                                              const float* __restrict__ lstm_bih,
                                              const float* __restrict__ lstm_bhh,
                                              const int* __restrict__ batch,
                                              ushort* __restrict__ wlin0,
                                              ushort* __restrict__ wg1,
                                              ushort* __restrict__ wg2,
                                              ushort* __restrict__ wihb,
                                              ushort* __restrict__ whhb,
                                              ushort* __restrict__ wrz,
                                              float* __restrict__ brz,
                                              unsigned* __restrict__ wp,
                                              float* __restrict__ bl,
                                              int* __restrict__ gstart,
                                              int* __restrict__ bcnt) {
    const int S0 = 16384, S1 = S0 + 16384, S2 = S1 + 16384;
    const int S3 = S2 + 49152, S4 = S3 + 49152, S5 = S4 + 65536;
    const int S6 = S5 + 256, S7 = S6 + 98304, S8 = S7 + 512;
    const int S9 = S8 + (NG + 1), S10 = S9 + 256;
    int i = blockIdx.x * 256 + threadIdx.x;
    if (i < S0) { wlin0[i] = f2b(lin0_W[i]); }
    else if (i < S1) { int j = i - S0; wg1[j] = f2b(gin_W1[j]); }
    else if (i < S2) { int j = i - S1; wg2[j] = f2b(gin_W2[j]); }
    else if (i < S3) { int j = i - S2; wihb[j] = f2b(gru_Wih[j]); }
    else if (i < S4) { int j = i - S3; whhb[j] = f2b(gru_Whh[j]); }
    else if (i < S5) {
        int j = i - S4; int col = j >> 8, k = j & 255;
        int row = (col >> 7) * 128 + (col & 127);
        wrz[j] = f2b((k < 128) ? gru_Whh[row * 128 + k] : gru_Wih[row * 128 + (k - 128)]);
    }
    else if (i < S6) { int j = i - S5; brz[j] = gru_bih[j] + gru_bhh[j]; }
    else if (i < S7) {
        int j = i - S6; int pk = j / 512, col = j % 512;
        int k0 = 2 * pk, k1 = 2 * pk + 1;
        float v0 = (k0 < 256) ? lstm_Wih[(size_t)col * 256 + k0]
                              : lstm_Whh[(size_t)col * 128 + (k0 - 256)];
        float v1 = (k1 < 256) ? lstm_Wih[(size_t)col * 256 + k1]
                              : lstm_Whh[(size_t)col * 128 + (k1 - 256)];
        wp[j] = ((unsigned)f2b(v1) << 16) | (unsigned)f2b(v0);
    }
    else if (i < S8) { int j = i - S7; bl[j] = lstm_bih[j] + lstm_bhh[j]; }
    else if (i < S9) {
        int g = i - S8;
        int lo = 0, hi = NN;
        while (lo < hi) { int mid = (lo + hi) >> 1; if (batch[mid] < g) lo = mid + 1; else hi = mid; }
        gstart[g] = lo;
    }
    else if (i < S10) { bcnt[i - S9] = 0; }
}
static constexpr int PREP_TOTAL = 16384 * 3 + 49152 * 2 + 65536 + 256 + 98304 + 512 + (NG + 1) + 256;

// ---------------- bucket counts ----------------
__global__ __launch_bounds__(256) void k_bcount(const int* __restrict__ dst,
                                                int* __restrict__ bcnt, int e) {
    __shared__ int l[256];
    int tid = threadIdx.x;
    l[tid] = 0;
    __syncthreads();
    int base = blockIdx.x * 4096;
    #pragma unroll
    for (int k = 0; k < 16; ++k) {
        int e0 = base + k * 256 + tid;
        if (e0 < e) atomicAdd(&l[dst[e0] >> 8], 1);
    }
    __syncthreads();
    if (l[tid] > 0) atomicAdd(&bcnt[tid], l[tid]);
}

__global__ __launch_bounds__(256) void k_btop(const int* __restrict__ bcnt,
                                              int* __restrict__ bbase,
                                              int* __restrict__ bcur) {
    __shared__ int s[256];
    int t = threadIdx.x;
    int v = bcnt[t];
    s[t] = v;
    __syncthreads();
    #pragma unroll
    for (int off = 1; off < 256; off <<= 1) {
        int x = (t >= off) ? s[t - off] : 0;
        __syncthreads();
        s[t] += x;
        __syncthreads();
    }
    int ex = s[t] - v;
    bbase[t] = ex;
    bcur[t] = ex;
    if (t == 255) bbase[256] = s[255];
}

// ---------------- bucket pass + fused lin0 ----------------
__global__ __launch_bounds__(256) void k_bucket_lin0(const int* __restrict__ src,
                                                     const int* __restrict__ dst,
                                                     int* __restrict__ bcur,
                                                     int2* __restrict__ pairs, int e,
                                                     const float* __restrict__ X,
                                                     const ushort* __restrict__ W,
                                                     const float* __restrict__ bias,
                                                     ushort* __restrict__ AB, int n) {
    if (blockIdx.x < (unsigned)NBLK) {
        __shared__ int lcnt[256];
        __shared__ int lbase[256];
        int tid = threadIdx.x;
        lcnt[tid] = 0;
        __syncthreads();
        int base = blockIdx.x * 4096;
        #pragma unroll
        for (int k = 0; k < 16; ++k) {
            int e0 = base + k * 256 + tid;
            if (e0 < e) atomicAdd(&lcnt[dst[e0] >> 8], 1);
        }
        __syncthreads();
        int cnt = lcnt[tid];
        if (cnt > 0) lbase[tid] = atomicAdd(&bcur[tid], cnt);
        __syncthreads();
        lcnt[tid] = 0;
        __syncthreads();
        #pragma unroll
        for (int k = 0; k < 16; ++k) {
            int e0 = base + k * 256 + tid;
            if (e0 < e) {
                int d = dst[e0];
                int b = d >> 8;
                int off = atomicAdd(&lcnt[b], 1);
                pairs[lbase[b] + off] = make_int2(src[e0], d);
            }
        }
        return;
    }
    int bid = blockIdx.x - NBLK;
    int nlb = gridDim.x - NBLK;
    int lane = threadIdx.x & 63, wave = threadIdx.x >> 6;
    int c0 = lane & 15, kg = (lane >> 4) * 8;
    int tb0 = wave * 32;
    bf16x8 B[2][4];
    #pragma unroll
    for (int t = 0; t < 2; ++t)
        #pragma unroll
        for (int kk = 0; kk < 4; ++kk)
            B[t][kk] = ldb8(W + (size_t)(tb0 + t * 16 + c0) * 128 + kk * 32 + kg);

    for (int m0 = bid * 64; m0 < n; m0 += nlb * 64) {
        f32x4 acc[4][2];
        #pragma unroll
        for (int m = 0; m < 4; ++m) { acc[m][0] = {0,0,0,0}; acc[m][1] = {0,0,0,0}; }
        #pragma unroll
        for (int kk = 0; kk < 4; ++kk) {
            #pragma unroll
            for (int m = 0; m < 4; ++m) {
                int ar = min(m0 + m * 16 + c0, n - 1);
                const float* a = X + (size_t)ar * 128 + kk * 32 + kg;
                float4 x0 = *reinterpret_cast<const float4*>(a);
                float4 x1 = *reinterpret_cast<const float4*>(a + 4);
                bf16x8 af;
                af[0] = (short)f2b(x0.x); af[1] = (short)f2b(x0.y);
                af[2] = (short)f2b(x0.z); af[3] = (short)f2b(x0.w);
                af[4] = (short)f2b(x1.x); af[5] = (short)f2b(x1.y);
                af[6] = (short)f2b(x1.z); af[7] = (short)f2b(x1.w);
                acc[m][0] = __builtin_amdgcn_mfma_f32_16x16x32_bf16(af, B[0][kk], acc[m][0], 0, 0, 0);
                acc[m][1] = __builtin_amdgcn_mfma_f32_16x16x32_bf16(af, B[1][kk], acc[m][1], 0, 0, 0);
            }
        }
        #pragma unroll
        for (int m = 0; m < 4; ++m) {
            int rbase = m0 + m * 16 + ((lane >> 4) << 2);
            #pragma unroll
            for (int t = 0; t < 2; ++t) {
                int col = tb0 + t * 16 + c0;
                float bv = bias[col];
                #pragma unroll
                for (int j = 0; j < 4; ++j) {
                    int row = rbase + j;
                    if (row < n) {
                        float v = fmaxf(acc[m][t][j] + bv, 0.f);
                        AB[(size_t)row * 128 + col] = f2b(v);
                    }
                }
            }
        }
    }
}

// ---------------- fill: per-node offsets + rowptr + csr scatter ----------------
__global__ __launch_bounds__(256) void k_fillbkt2(const int2* __restrict__ pairs,
                                                  const int* __restrict__ bbase,
                                                  int* __restrict__ rowptr,
                                                  int* __restrict__ csr) {
    __shared__ int lcnt[256];
    __shared__ int s[256];
    __shared__ int lcur[256];
    int b = blockIdx.x, tid = threadIdx.x;
    int w0 = b << 8;
    int r0 = bbase[b], r1 = bbase[b + 1];
    lcnt[tid] = 0;
    __syncthreads();
    for (int i = r0 + tid; i < r1; i += 256)
        atomicAdd(&lcnt[pairs[i].y - w0], 1);
    __syncthreads();
    int v = lcnt[tid];
    s[tid] = v;
    __syncthreads();
    #pragma unroll
    for (int off = 1; off < 256; off <<= 1) {
        int x = (tid >= off) ? s[tid - off] : 0;
        __syncthreads();
        s[tid] += x;
        __syncthreads();
    }
    int ex = r0 + s[tid] - v;
    lcur[tid] = ex;
    if (w0 + tid < NN) rowptr[w0 + tid] = ex;
    if (b == 0 && tid == 0) rowptr[NN] = NE;
    __syncthreads();
    for (int i = r0 + tid; i < r1; i += 256) {
        int2 p = pairs[i];
        int pos = atomicAdd(&lcur[p.y - w0], 1);
        csr[pos] = p.x;
    }
}

// ---------------- fused aggregation + GIN MLP ----------------
__global__ __launch_bounds__(512) void k_aggmlp(const ushort* __restrict__ AB,
                                                const int* __restrict__ rowptr,
                                                const int* __restrict__ csr,
                                                const ushort* __restrict__ W1,
                                                const float* __restrict__ b1,
                                                const ushort* __restrict__ W2,
                                                const float* __restrict__ b2,
                                                ushort* __restrict__ mt, int n) {
    __shared__ ushort Z_lds[32 * 136];
    __shared__ ushort M_lds[32 * 136];
    int tid = threadIdx.x;
    int lane = tid & 63, wave = tid >> 6;
    int c0 = lane & 15, kg = (lane >> 4) * 8;
    int colw = wave * 16 + c0;
    int rj = (lane >> 4) << 2;
    int grow_r = tid >> 4;
    int segi = tid & 15;
    const int stride = gridDim.x * 32;

    bf16x8 B1[4], B2[4];
    #pragma unroll
    for (int kk = 0; kk < 4; ++kk) {
        B1[kk] = ldb8(W1 + (size_t)colw * 128 + kk * 32 + kg);
        B2[kk] = ldb8(W2 + (size_t)colw * 128 + kk * 32 + kg);
    }
    float bv1 = b1[colw], bv2 = b2[colw];
    const uint4* bp = (const uint4*)AB;

    for (int m0 = blockIdx.x * 32; m0 < n; m0 += stride) {
        f32x8 A0 = {0,0,0,0,0,0,0,0};
        int grow = m0 + grow_r;
        if (grow < n) {
            f32x8 A1 = {0,0,0,0,0,0,0,0}, A2 = {0,0,0,0,0,0,0,0}, A3 = {0,0,0,0,0,0,0,0};
            A0 = acc8(A0, bp[(size_t)grow * 16 + segi]);
            int p = rowptr[grow], p1 = rowptr[grow + 1];
            for (; p + 4 <= p1; p += 4) {
                uint4 v0 = bp[(size_t)csr[p + 0] * 16 + segi];
                uint4 v1 = bp[(size_t)csr[p + 1] * 16 + segi];
                uint4 v2 = bp[(size_t)csr[p + 2] * 16 + segi];
                uint4 v3 = bp[(size_t)csr[p + 3] * 16 + segi];
                A0 = acc8(A0, v0); A1 = acc8(A1, v1);
                A2 = acc8(A2, v2); A3 = acc8(A3, v3);
            }
            for (; p < p1; ++p) A0 = acc8(A0, bp[(size_t)csr[p] * 16 + segi]);
            #pragma unroll
            for (int i = 0; i < 8; ++i) A0[i] += A1[i] + A2[i] + A3[i];
        }
        bf16x8 zz;
        #pragma unroll
        for (int i = 0; i < 8; ++i) zz[i] = (short)f2b(A0[i]);
        *reinterpret_cast<bf16x8*>(&Z_lds[grow_r * 136 + segi * 8]) = zz;
        __syncthreads();
        {
            f32x4 a[2] = {{0,0,0,0},{0,0,0,0}};
            #pragma unroll
            for (int kk = 0; kk < 4; ++kk) {
                bf16x8 f0 = *reinterpret_cast<const bf16x8*>(&Z_lds[c0 * 136 + kk * 32 + kg]);
                bf16x8 f1 = *reinterpret_cast<const bf16x8*>(&Z_lds[(16 + c0) * 136 + kk * 32 + kg]);
                a[0] = __builtin_amdgcn_mfma_f32_16x16x32_bf16(f0, B1[kk], a[0], 0, 0, 0);
                a[1] = __builtin_amdgcn_mfma_f32_16x16x32_bf16(f1, B1[kk], a[1], 0, 0, 0);
            }
            #pragma unroll
            for (int m = 0; m < 2; ++m)
                #pragma unroll
                for (int j = 0; j < 4; ++j)
                    M_lds[(m * 16 + rj + j) * 136 + colw] = f2b(fmaxf(a[m][j] + bv1, 0.f));
        }
        __syncthreads();
        {
            f32x4 a[2] = {{0,0,0,0},{0,0,0,0}};
            #pragma unroll
            for (int kk = 0; kk < 4; ++kk) {
                bf16x8 f0 = *reinterpret_cast<const bf16x8*>(&M_lds[c0 * 136 + kk * 32 + kg]);
                bf16x8 f1 = *reinterpret_cast<const bf16x8*>(&M_lds[(16 + c0) * 136 + kk * 32 + kg]);
                a[0] = __builtin_amdgcn_mfma_f32_16x16x32_bf16(f0, B2[kk], a[0], 0, 0, 0);
                a[1] = __builtin_amdgcn_mfma_f32_16x16x32_bf16(f1, B2[kk], a[1], 0, 0, 0);
            }
            #pragma unroll
            for (int m = 0; m < 2; ++m)
                #pragma unroll
                for (int j = 0; j < 4; ++j) {
                    int gr2 = m0 + m * 16 + rj + j;
                    if (gr2 < n)
                        mt[(size_t)gr2 * 128 + colw] = f2b(fmaxf(a[m][j] + bv2, 0.f));
                }
        }
        __syncthreads();
    }
}

// ---------------- GRU: rz + ngate fully in-register per wave ----------------
template<bool WRITEH>
__global__ __launch_bounds__(512) void k_gru3b(const ushort* __restrict__ ABin,
                                               const ushort* __restrict__ mt,
                                               const ushort* __restrict__ wrz,
                                               const float* __restrict__ brz,
                                               const ushort* __restrict__ Wn,
                                               const ushort* __restrict__ Un,
                                               const float* __restrict__ bin,
                                               const float* __restrict__ bhn,
                                               float* __restrict__ Hf,
                                               ushort* __restrict__ ABout, int n) {
    __shared__ ushort A_lds[32 * 264];   // [h | m]
    int tid = threadIdx.x;
    int lane = tid & 63, wave = tid >> 6;
    int c0 = lane & 15, kg = (lane >> 4) * 8;
    int colw = wave * 16 + c0;
    int rj = (lane >> 4) << 2;
    int srow = tid >> 4, scol = (tid & 15) * 8;
    const int stride = gridDim.x * 32;

    bf16x8 Brz[2][8];
    #pragma unroll
    for (int kk = 0; kk < 8; ++kk) {
        Brz[0][kk] = ldb8(wrz + (size_t)(colw) * 256 + kk * 32 + kg);
        Brz[1][kk] = ldb8(wrz + (size_t)(128 + colw) * 256 + kk * 32 + kg);
    }
    bf16x8 Bn[4], Bu[4];
    #pragma unroll
    for (int kk = 0; kk < 4; ++kk) {
        Bn[kk] = ldb8(Wn + (size_t)colw * 128 + kk * 32 + kg);
        Bu[kk] = ldb8(Un + (size_t)colw * 128 + kk * 32 + kg);
    }
    float biN = bin[colw], bhN = bhn[colw];
    float brzR = brz[colw], brzZ = brz[128 + colw];

    int m0 = blockIdx.x * 32;
    bf16x8 ph, pm;
    if (m0 < n) {
        int gr = min(m0 + srow, n - 1);
        ph = ldb8(ABin + (size_t)gr * 128 + scol);
        pm = ldb8(mt + (size_t)gr * 128 + scol);
    }
    for (; m0 < n; m0 += stride) {
        *reinterpret_cast<bf16x8*>(&A_lds[srow * 264 + scol]) = ph;
        *reinterpret_cast<bf16x8*>(&A_lds[srow * 264 + 128 + scol]) = pm;
        __syncthreads();
        int mn = m0 + stride;
        if (mn < n) {
            int gr = min(mn + srow, n - 1);
            ph = ldb8(ABin + (size_t)gr * 128 + scol);
            pm = ldb8(mt + (size_t)gr * 128 + scol);
        }
        f32x4 aR[2] = {{0,0,0,0},{0,0,0,0}};
        f32x4 aZ[2] = {{0,0,0,0},{0,0,0,0}};
        #pragma unroll
        for (int kk = 0; kk < 8; ++kk) {
            bf16x8 f0 = *reinterpret_cast<const bf16x8*>(&A_lds[c0 * 264 + kk * 32 + kg]);
            bf16x8 f1 = *reinterpret_cast<const bf16x8*>(&A_lds[(16 + c0) * 264 + kk * 32 + kg]);
            aR[0] = __builtin_amdgcn_mfma_f32_16x16x32_bf16(f0, Brz[0][kk], aR[0], 0, 0, 0);
            aZ[0] = __builtin_amdgcn_mfma_f32_16x16x32_bf16(f0, Brz[1][kk], aZ[0], 0, 0, 0);
            aR[1] = __builtin_amdgcn_mfma_f32_16x16x32_bf16(f1, Brz[0][kk], aR[1], 0, 0, 0);
            aZ[1] = __builtin_amdgcn_mfma_f32_16x16x32_bf16(f1, Brz[1][kk], aZ[1], 0, 0, 0);
        }
        f32x4 an[2] = {{0,0,0,0},{0,0,0,0}};
        f32x4 au[2] = {{0,0,0,0},{0,0,0,0}};
        #pragma unroll
        for (int kk = 0; kk < 4; ++kk) {
            bf16x8 am0 = *reinterpret_cast<const bf16x8*>(&A_lds[c0 * 264 + 128 + kk * 32 + kg]);
            bf16x8 ah0 = *reinterpret_cast<const bf16x8*>(&A_lds[c0 * 264 + kk * 32 + kg]);
            bf16x8 am1 = *reinterpret_cast<const bf16x8*>(&A_lds[(16 + c0) * 264 + 128 + kk * 32 + kg]);
            bf16x8 ah1 = *reinterpret_cast<const bf16x8*>(&A_lds[(16 + c0) * 264 + kk * 32 + kg]);
            an[0] = __builtin_amdgcn_mfma_f32_16x16x32_bf16(am0, Bn[kk], an[0], 0, 0, 0);
            au[0] = __builtin_amdgcn_mfma_f32_16x16x32_bf16(ah0, Bu[kk], au[0], 0, 0, 0);
            an[1] = __builtin_amdgcn_mfma_f32_16x16x32_bf16(am1, Bn[kk], an[1], 0, 0, 0);
            au[1] = __builtin_amdgcn_mfma_f32_16x16x32_bf16(ah1, Bu[kk], au[1], 0, 0, 0);
        }
        #pragma unroll
        for (int m = 0; m < 2; ++m)
            #pragma unroll
            for (int j = 0; j < 4; ++j) {
                int row = m * 16 + rj + j;
                int grow = m0 + row;
                if (grow < n) {
                    float r  = sigm(aR[m][j] + brzR);
                    float zt = sigm(aZ[m][j] + brzZ);
                    float hold = b2f(A_lds[row * 264 + colw]);
                    float nn = ftanh(an[m][j] + biN + r * (au[m][j] + bhN));
                    float hn = (1.f - zt) * nn + zt * hold;
                    ABout[(size_t)grow * 128 + colw] = f2b(hn);
                    if (WRITEH) Hf[(size_t)grow * 128 + colw] = hn;
                }
            }
        __syncthreads();
    }
}

// ---------------- Set2Set: all 3 steps in ONE kernel, state in LDS, bf16-packed weights ----------------
__global__ __launch_bounds__(512) void k_s2s3(const ushort* __restrict__ AB,
                                              const unsigned* __restrict__ Wp,
                                              const float* __restrict__ bl,
                                              const int* __restrict__ gstart,
                                              float* __restrict__ qout) {
    int g = blockIdx.x, tid = threadIdx.x, lane = tid & 63, wave = tid >> 6;
    __shared__ float qh[384];     // [q_star(256) | hl(128)]
    __shared__ float cl_s[128];
    __shared__ float gbuf[512];
    __shared__ float q[128];
    __shared__ float wm[8];
    __shared__ float sw[8];
    __shared__ float rv[8][128];
    if (tid < 384) qh[tid] = 0.f;
    if (tid < 128) cl_s[tid] = 0.f;
    int s = gstart[g], e = gstart[g + 1];

    for (int st = 0; st < 3; ++st) {
        __syncthreads();
        float acc = bl[tid];
        #pragma unroll 8
        for (int pk = 0; pk < 192; ++pk) {
            unsigned u = Wp[pk * 512 + tid];
            acc += b2f(u & 0xffff) * qh[2 * pk] + b2f(u >> 16) * qh[2 * pk + 1];
        }
        gbuf[tid] = acc;
        __syncthreads();
        if (tid < 128) {
            float iv = sigm(gbuf[tid]);
            float fv = sigm(gbuf[128 + tid]);
            float gv = ftanh(gbuf[256 + tid]);
            float ov = sigm(gbuf[384 + tid]);
            float cn = fv * cl_s[tid] + iv * gv;
            cl_s[tid] = cn;
            float hn = ov * ftanh(cn);
            q[tid] = hn;
            qh[256 + tid] = hn;
        }
        __syncthreads();
        float q0 = q[2 * lane], q1 = q[2 * lane + 1];
        float mx = -1e30f, sumw = 0.f, a0 = 0.f, a1 = 0.f;
        for (int node = s + wave; node < e; node += 8) {
            unsigned u = ((const unsigned*)AB)[(size_t)node * 64 + lane];
            float v0 = b2f(u & 0xffff), v1 = b2f(u >> 16);
            float p = v0 * q0 + v1 * q1;
            #pragma unroll
            for (int off = 1; off < 64; off <<= 1) p += __shfl_xor(p, off);
            float nm = fmaxf(mx, p);
            float corr = __expf(mx - nm);
            float wgt = __expf(p - nm);
            sumw = sumw * corr + wgt;
            a0 = a0 * corr + wgt * v0;
            a1 = a1 * corr + wgt * v1;
            mx = nm;
        }
        if (lane == 0) wm[wave] = mx;
        __syncthreads();
        float gm = fmaxf(fmaxf(fmaxf(wm[0], wm[1]), fmaxf(wm[2], wm[3])),
                         fmaxf(fmaxf(wm[4], wm[5]), fmaxf(wm[6], wm[7])));
        float cw = __expf(mx - gm);
        rv[wave][2 * lane] = a0 * cw;
        rv[wave][2 * lane + 1] = a1 * cw;
        if (lane == 0) sw[wave] = sumw * cw;
        __syncthreads();
        if (tid < 128) {
            float r = 0.f, d = 1e-16f;
            #pragma unroll
            for (int wv = 0; wv < 8; ++wv) r += rv[wv][tid];
            #pragma unroll
            for (int wv = 0; wv < 8; ++wv) d += sw[wv];
            if (st == 2) {
                qout[(size_t)g * 256 + tid] = q[tid];
                qout[(size_t)g * 256 + 128 + tid] = r / d;
            } else {
                qh[tid] = q[tid];
                qh[128 + tid] = r / d;
            }
        }
    }
}

// ---------------- launch ----------------
extern "C" void kernel_launch(void* const* d_in, const int* in_sizes, int n_in,
                              void* d_out, int out_size, void* d_ws, size_t ws_size,
                              hipStream_t stream) {
    const float* x        = (const float*)d_in[0];
    const int*   ei       = (const int*)d_in[1];
    const int*   batch    = (const int*)d_in[2];
    const float* lin0_W   = (const float*)d_in[3];
    const float* lin0_b   = (const float*)d_in[4];
    const float* gin_W1   = (const float*)d_in[5];
    const float* gin_b1   = (const float*)d_in[6];
    const float* gin_W2   = (const float*)d_in[7];
    const float* gin_b2   = (const float*)d_in[8];
    const float* gru_Wih  = (const float*)d_in[9];
    const float* gru_Whh  = (const float*)d_in[10];
    const float* gru_bih  = (const float*)d_in[11];
    const float* gru_bhh  = (const float*)d_in[12];
    const float* lstm_Wih = (const float*)d_in[13];
    const float* lstm_Whh = (const float*)d_in[14];
    const float* lstm_bih = (const float*)d_in[15];
    const float* lstm_bhh = (const float*)d_in[16];

    float* qstar_out = (float*)d_out;                         // [NG, 256]
    float* h         = (float*)d_out + (size_t)NG * 2 * DIM;  // [NN, 128] fp32 == `out`

    char* w = (char*)d_ws;
    ushort* AB0   = (ushort*)w; w += (size_t)NN * 128 * 2;   // ping (h only)
    ushort* AB1   = (ushort*)w; w += (size_t)NN * 128 * 2;   // pong (h only)
    ushort* mt    = (ushort*)w; w += (size_t)NN * 128 * 2;   // GIN MLP out
    ushort* wlin0 = (ushort*)w; w += 16384 * 2;
    ushort* wg1   = (ushort*)w; w += 16384 * 2;
    ushort* wg2   = (ushort*)w; w += 16384 * 2;
    ushort* wihb  = (ushort*)w; w += 49152 * 2;
    ushort* whhb  = (ushort*)w; w += 49152 * 2;
    ushort* wrz   = (ushort*)w; w += 65536 * 2;
    float* brz    = (float*)w;  w += 256 * 4;
    unsigned* wp  = (unsigned*)w; w += (size_t)98304 * 4;    // LSTM W bf16-pair packed
    float* bl     = (float*)w;  w += 512 * 4;
    int* rowptr   = (int*)w;    w += (size_t)(NN + 1) * 4;
    int* bcnt     = (int*)w;    w += 256 * 4;
    int* bbase    = (int*)w;    w += 257 * 4;
    int* bcur     = (int*)w;    w += 256 * 4;
    int* csr_src  = (int*)w;    w += (size_t)NE * 4;
    int2* pairs   = (int2*)w;   w += (size_t)NE * 8;
    int* gstart   = (int*)w;    w += (size_t)(NG + 1) * 4;

    const int* src = ei;
    const int* dst = ei + NE;

    // one mega-prep
    k_prep<<<(PREP_TOTAL + 255) / 256, 256, 0, stream>>>(
        lin0_W, gin_W1, gin_W2, gru_Wih, gru_Whh, gru_bih, gru_bhh,
        lstm_Wih, lstm_Whh, lstm_bih, lstm_bhh, batch,
        wlin0, wg1, wg2, wihb, whhb, wrz, brz, wp, bl, gstart, bcnt);

    // CSR build (degree-free) + fused lin0
    k_bcount<<<(NE + 4095) / 4096, 256, 0, stream>>>(dst, bcnt, NE);
    k_btop<<<1, 256, 0, stream>>>(bcnt, bbase, bcur);
    k_bucket_lin0<<<NBLK + 782, 256, 0, stream>>>(src, dst, bcur, pairs, NE,
                                                  x, wlin0, lin0_b, AB0, NN);
    k_fillbkt2<<<NBLK, 256, 0, stream>>>(pairs, bbase, rowptr, csr_src);

    // 3 GC layers, ping-pong AB buffers
    for (int t = 0; t < 3; ++t) {
        ushort* ABc = (t & 1) ? AB1 : AB0;
        ushort* ABn = (t & 1) ? AB0 : AB1;
        k_aggmlp<<<1024, 512, 0, stream>>>(ABc, rowptr, csr_src,
                                           wg1, gin_b1, wg2, gin_b2, mt, NN);
        if (t < 2)
            k_gru3b<false><<<512, 512, 0, stream>>>(ABc, mt, wrz, brz,
                                                    wihb + 256 * 128, whhb + 256 * 128,
                                                    gru_bih + 256, gru_bhh + 256, h, ABn, NN);
        else
            k_gru3b<true><<<512, 512, 0, stream>>>(ABc, mt, wrz, brz,
                                                   wihb + 256 * 128, whhb + 256 * 128,
                                                   gru_bih + 256, gru_bhh + 256, h, ABn, NN);
    }
    // final bf16 h lives in AB1 (t=2 wrote ABn=AB1)
    const ushort* ABfin = AB1;

    // Set2Set: one launch, 3 steps internal
    k_s2s3<<<NG, 512, 0, stream>>>(ABfin, wp, bl, gstart, qstar_out);
}